// Round 1
// baseline (703.385 us; speedup 1.0000x reference)
//
#include <hip/hip_runtime.h>
#include <hip/hip_bf16.h>

#define B_ 8
#define T_ 1024
#define D_ 256
#define H_ 8
#define KD_ 256
#define HK_ 2048
#define FF_ 1024
#define WIN_ 64
#define BT_ 8192

using bf16 = __hip_bfloat16;
typedef float f32x4 __attribute__((ext_vector_type(4)));
typedef short s16x8 __attribute__((ext_vector_type(8)));

__device__ inline float b2f(bf16 h) { return __bfloat162float(h); }
__device__ inline short f2bs(float x) { bf16 h = __float2bfloat16(x); return __builtin_bit_cast(short, h); }
__device__ inline unsigned short fbits(float x) { bf16 h = __float2bfloat16(x); return __builtin_bit_cast(unsigned short, h); }

// ---------------- elementwise f32 -> bf16 ----------------
__global__ __launch_bounds__(256) void f32_to_bf16_vec(const float* __restrict__ in, bf16* __restrict__ out, int n) {
    int i = (blockIdx.x * 256 + threadIdx.x) * 4;
    if (i + 3 < n) {
        float4 v = *(const float4*)(in + i);
        ushort4 o;
        o.x = fbits(v.x); o.y = fbits(v.y); o.z = fbits(v.z); o.w = fbits(v.w);
        *(ushort4*)(out + i) = o;
    }
}

// ---------------- transpose f32[R][C] -> bf16[C][R] ----------------
__global__ void transpose_to_bf16(const float* __restrict__ in, bf16* __restrict__ out, int R, int C) {
    __shared__ float tile[32][33];
    int cb = blockIdx.x * 32, rb = blockIdx.y * 32;
    for (int k = 0; k < 4; k++) {
        int r = threadIdx.y + k * 8;
        tile[r][threadIdx.x] = in[(size_t)(rb + r) * C + cb + threadIdx.x];
    }
    __syncthreads();
    for (int k = 0; k < 4; k++) {
        int r = threadIdx.y + k * 8;
        out[(size_t)(cb + r) * R + rb + threadIdx.x] = __float2bfloat16(tile[threadIdx.x][r]);
    }
}

// ---------------- generic bf16 GEMM: C[M][N] = A[M][K] * Bt[N][K]^T + bias ----------------
// MODE 0: store f32; MODE 1: store bf16; MODE 2: store bf16 with relu
template <int MODE>
__global__ __launch_bounds__(256) void gemm_bt(const bf16* __restrict__ A, const bf16* __restrict__ Bt,
                                               const float* __restrict__ bias, void* __restrict__ C,
                                               int M, int N, int K) {
    __shared__ bf16 As[64][40];
    __shared__ bf16 Bs[64][40];
    const int tid = threadIdx.x;
    const int m0 = blockIdx.y * 64, n0 = blockIdx.x * 64;
    const int w = tid >> 6, l = tid & 63;
    const int wm = (w >> 1) * 32, wn = (w & 1) * 32;
    const int lrow = tid >> 2, lk = (tid & 3) * 8;
    f32x4 acc[2][2] = {};
    for (int k0 = 0; k0 < K; k0 += 32) {
        __syncthreads();
        *(uint4*)&As[lrow][lk] = *(const uint4*)&A[(size_t)(m0 + lrow) * K + k0 + lk];
        *(uint4*)&Bs[lrow][lk] = *(const uint4*)&Bt[(size_t)(n0 + lrow) * K + k0 + lk];
        __syncthreads();
        s16x8 a[2], b[2];
        for (int mf = 0; mf < 2; mf++) a[mf] = *(const s16x8*)&As[wm + mf * 16 + (l & 15)][(l >> 4) * 8];
        for (int nf = 0; nf < 2; nf++) b[nf] = *(const s16x8*)&Bs[wn + nf * 16 + (l & 15)][(l >> 4) * 8];
        for (int mf = 0; mf < 2; mf++)
            for (int nf = 0; nf < 2; nf++)
                acc[mf][nf] = __builtin_amdgcn_mfma_f32_16x16x32_bf16(a[mf], b[nf], acc[mf][nf], 0, 0, 0);
    }
    for (int mf = 0; mf < 2; mf++)
        for (int nf = 0; nf < 2; nf++)
            for (int r = 0; r < 4; r++) {
                int row = m0 + wm + mf * 16 + (l >> 4) * 4 + r;
                int col = n0 + wn + nf * 16 + (l & 15);
                float v = acc[mf][nf][r] + (bias ? bias[col] : 0.f);
                if (MODE == 0)
                    ((float*)C)[(size_t)row * N + col] = v;
                else {
                    if (MODE == 2) v = fmaxf(v, 0.f);
                    ((bf16*)C)[(size_t)row * N + col] = __float2bfloat16(v);
                }
            }
}

// ---------------- local windowed attention ----------------
// grid: (T/64, B*H). Q,K,V,O: [B*T][HK] bf16, head slice h*KD.
__global__ __launch_bounds__(256) void local_attn(const bf16* __restrict__ Q, const bf16* __restrict__ K,
                                                  const bf16* __restrict__ V, bf16* __restrict__ O) {
    __shared__ bf16 Qs[64][264];
    __shared__ float Ss[64][132];
    __shared__ bf16 KV[256 * 72];  // phase1: Ks[64][264]; phase2: VT[256][72]
    const int tid = threadIdx.x, l = tid & 63, w = tid >> 6;
    const int qt = blockIdx.x, bh = blockIdx.y;
    const int b = bh >> 3, h = bh & 7;
    const int qs = qt * 64;
    const size_t base = (size_t)b * T_ * HK_ + h * KD_;

    {   // load Q tile
        int row = tid >> 2;
        for (int c = 0; c < 8; c++) {
            int col = ((tid & 3) + 4 * c) * 8;
            *(uint4*)&Qs[row][col] = *(const uint4*)&Q[base + (size_t)(qs + row) * HK_ + col];
        }
    }
    bf16(*Ks)[264] = (bf16(*)[264])KV;
    for (int kb = 0; kb < 2; kb++) {
        __syncthreads();
        {
            int row = tid >> 2;
            int tk = qs - 64 + kb * 64 + row;
            for (int c = 0; c < 8; c++) {
                int col = ((tid & 3) + 4 * c) * 8;
                uint4 val = {0, 0, 0, 0};
                if (tk >= 0) val = *(const uint4*)&K[base + (size_t)tk * HK_ + col];
                *(uint4*)&Ks[row][col] = val;
            }
        }
        __syncthreads();
        const int r0 = w * 16;
        for (int nf = 0; nf < 4; nf++) {
            f32x4 acc = {};
            for (int ks = 0; ks < 8; ks++) {
                s16x8 a = *(const s16x8*)&Qs[r0 + (l & 15)][ks * 32 + (l >> 4) * 8];
                s16x8 bb = *(const s16x8*)&Ks[nf * 16 + (l & 15)][ks * 32 + (l >> 4) * 8];
                acc = __builtin_amdgcn_mfma_f32_16x16x32_bf16(a, bb, acc, 0, 0, 0);
            }
            for (int r = 0; r < 4; r++) {
                int srow = r0 + (l >> 4) * 4 + r;
                int scol = nf * 16 + (l & 15);
                int i = qs + srow, j = qs - 64 + kb * 64 + scol;
                bool valid = (j >= 0) && (j <= i) && (j > i - WIN_);
                Ss[srow][kb * 64 + scol] = valid ? acc[r] * (1.f / 16.f) : -1e9f;
            }
        }
    }
    __syncthreads();
    {   // softmax: wave w handles rows w*16 + (l>>2); 4 lanes/row, 32 cols each
        int row = w * 16 + (l >> 2);
        int c0 = (l & 3) * 32;
        float m = -1e30f;
        for (int c = 0; c < 32; c++) m = fmaxf(m, Ss[row][c0 + c]);
        m = fmaxf(m, __shfl_xor(m, 1, 64));
        m = fmaxf(m, __shfl_xor(m, 2, 64));
        float s = 0.f;
        for (int c = 0; c < 32; c++) {
            float e = __expf(Ss[row][c0 + c] - m);
            Ss[row][c0 + c] = e;
            s += e;
        }
        s += __shfl_xor(s, 1, 64);
        s += __shfl_xor(s, 2, 64);
        float inv = 1.f / s;
        for (int c = 0; c < 32; c++) Ss[row][c0 + c] *= inv;
    }
    bf16(*VT)[72] = (bf16(*)[72])KV;
    f32x4 oacc[16] = {};
    for (int kb = 0; kb < 2; kb++) {
        __syncthreads();
        {
            int row = tid >> 2;
            int tk = qs - 64 + kb * 64 + row;
            for (int c = 0; c < 8; c++) {
                int col = ((tid & 3) + 4 * c) * 8;
                if (tk >= 0) {
                    bf16 tmp[8];
                    *(uint4*)tmp = *(const uint4*)&V[base + (size_t)tk * HK_ + col];
                    for (int e = 0; e < 8; e++) VT[col + e][row] = tmp[e];
                } else {
                    bf16 z = __float2bfloat16(0.f);
                    for (int e = 0; e < 8; e++) VT[col + e][row] = z;
                }
            }
        }
        __syncthreads();
        const int r0 = w * 16;
        for (int ks = 0; ks < 2; ks++) {
            s16x8 a;
            {
                const float* p = &Ss[r0 + (l & 15)][kb * 64 + ks * 32 + (l >> 4) * 8];
                for (int e = 0; e < 8; e++) a[e] = f2bs(p[e]);
            }
            for (int nf = 0; nf < 16; nf++) {
                s16x8 bb = *(const s16x8*)&VT[nf * 16 + (l & 15)][ks * 32 + (l >> 4) * 8];
                oacc[nf] = __builtin_amdgcn_mfma_f32_16x16x32_bf16(a, bb, oacc[nf], 0, 0, 0);
            }
        }
    }
    for (int nf = 0; nf < 16; nf++)
        for (int r = 0; r < 4; r++) {
            int row = w * 16 + (l >> 4) * 4 + r;
            int col = nf * 16 + (l & 15);
            O[base + (size_t)(qs + row) * HK_ + col] = __float2bfloat16(oacc[nf][r]);
        }
}

// ---------------- global path: g2 attention scores/PV per (b,h) ----------------
// og[b][h][i][kd] = softmax_t(qg_i . gK_t / 16) . gV
__global__ __launch_bounds__(256) void g2_qk(const float* __restrict__ x, const bf16* __restrict__ gwq_t,
                                             const float* __restrict__ gbq, const bf16* __restrict__ gK,
                                             const bf16* __restrict__ gV, float* __restrict__ og) {
    __shared__ float qg[2][256];
    __shared__ float sc[2][1024];
    __shared__ float red[256];
    int bh = blockIdx.x;
    int b = bh >> 3, h = bh & 7;
    int tid = threadIdx.x;
    for (int i = 0; i < 2; i++) {
        float acc = gbq[h * KD_ + tid];
        const float* xr = &x[((size_t)b * T_ + (T_ - 2 + i)) * D_];
        const bf16* wr = &gwq_t[(size_t)(h * KD_ + tid) * D_];
        for (int dd = 0; dd < D_; dd++) acc += xr[dd] * b2f(wr[dd]);
        qg[i][tid] = acc;
    }
    __syncthreads();
    float tot[2];
    for (int i = 0; i < 2; i++) {
        float lm = -1e30f;
        for (int c = 0; c < 4; c++) {
            int t = tid + 256 * c;
            const bf16* kr = &gK[((size_t)b * T_ + t) * HK_ + h * KD_];
            float acc = 0.f;
            for (int dd = 0; dd < D_; dd++) acc += qg[i][dd] * b2f(kr[dd]);
            acc *= (1.f / 16.f);
            sc[i][t] = acc;
            lm = fmaxf(lm, acc);
        }
        red[tid] = lm;
        __syncthreads();
        for (int s = 128; s >= 1; s >>= 1) {
            if (tid < s) red[tid] = fmaxf(red[tid], red[tid + s]);
            __syncthreads();
        }
        float bm = red[0];
        __syncthreads();
        float ls = 0.f;
        for (int c = 0; c < 4; c++) {
            int t = tid + 256 * c;
            float e = __expf(sc[i][t] - bm);
            sc[i][t] = e;
            ls += e;
        }
        red[tid] = ls;
        __syncthreads();
        for (int s = 128; s >= 1; s >>= 1) {
            if (tid < s) red[tid] += red[tid + s];
            __syncthreads();
        }
        tot[i] = red[0];
        __syncthreads();
    }
    for (int i = 0; i < 2; i++) {
        float acc = 0.f;
        for (int t = 0; t < 1024; t++) acc += sc[i][t] * b2f(gV[((size_t)b * T_ + t) * HK_ + h * KD_ + tid]);
        og[((size_t)bh * 2 + i) * KD_ + tid] = acc / tot[i];
    }
}

// g2 = og @ gWo + gbo; then K2 = g2 @ gWk + gbk, V2 = g2 @ gWv + gbv (bf16)
__global__ __launch_bounds__(256) void g2_out(const float* __restrict__ og, const bf16* __restrict__ gwo_t,
                                              const float* __restrict__ gbo, const bf16* __restrict__ gwk_t,
                                              const float* __restrict__ gbk, const bf16* __restrict__ gwv_t,
                                              const float* __restrict__ gbv, bf16* __restrict__ K2,
                                              bf16* __restrict__ V2) {
    __shared__ float g2s[2][256];
    int b = blockIdx.x, tid = threadIdx.x;
    for (int i = 0; i < 2; i++) {
        float acc = gbo[tid];
        const bf16* wr = &gwo_t[(size_t)tid * HK_];
        const float* ogb = &og[(size_t)b * H_ * 2 * KD_];
        for (int h = 0; h < H_; h++) {
            const float* o = &ogb[(h * 2 + i) * KD_];
            const bf16* wrh = &wr[h * KD_];
            for (int kd = 0; kd < KD_; kd++) acc += o[kd] * b2f(wrh[kd]);
        }
        g2s[i][tid] = acc;
    }
    __syncthreads();
    for (int i = 0; i < 2; i++)
        for (int c = 0; c < 8; c++) {
            int hk = tid + 256 * c;
            float ak = gbk[hk], av = gbv[hk];
            const bf16* wk = &gwk_t[(size_t)hk * D_];
            const bf16* wv = &gwv_t[(size_t)hk * D_];
            for (int d = 0; d < D_; d++) {
                float g = g2s[i][d];
                ak += g * b2f(wk[d]);
                av += g * b2f(wv[d]);
            }
            K2[((size_t)b * 2 + i) * HK_ + hk] = __float2bfloat16(ak);
            V2[((size_t)b * 2 + i) * HK_ + hk] = __float2bfloat16(av);
        }
}

// gx attention: each block = one (b,t); 8 heads x 32 lanes; softmax over 2 keys
__global__ __launch_bounds__(256) void gx_attn(const bf16* __restrict__ gQ, const bf16* __restrict__ K2,
                                               const bf16* __restrict__ V2, bf16* __restrict__ O) {
    int bt = blockIdx.x;
    int b = bt >> 10;
    int tid = threadIdx.x;
    int h = tid >> 5, ln = tid & 31;
    size_t qoff = (size_t)bt * HK_ + h * KD_;
    size_t koff = (size_t)(b * 2) * HK_ + h * KD_;
    float s0 = 0.f, s1 = 0.f;
    for (int c = 0; c < 8; c++) {
        int d = ln + 32 * c;
        float q = b2f(gQ[qoff + d]);
        s0 += q * b2f(K2[koff + d]);
        s1 += q * b2f(K2[koff + HK_ + d]);
    }
    for (int m = 16; m >= 1; m >>= 1) {
        s0 += __shfl_xor(s0, m, 64);
        s1 += __shfl_xor(s1, m, 64);
    }
    s0 *= (1.f / 16.f);
    s1 *= (1.f / 16.f);
    float mx = fmaxf(s0, s1);
    float e0 = __expf(s0 - mx), e1 = __expf(s1 - mx);
    float inv = 1.f / (e0 + e1);
    float p0 = e0 * inv, p1 = e1 * inv;
    for (int c = 0; c < 8; c++) {
        int d = ln + 32 * c;
        float v = p0 * b2f(V2[koff + d]) + p1 * b2f(V2[koff + HK_ + d]);
        O[qoff + d] = __float2bfloat16(v);
    }
}

// ---------------- LayerNorm over D=256, block per row ----------------
__global__ __launch_bounds__(256) void ln_kernel(const float* __restrict__ a, const float* __restrict__ b2,
                                                 const float* __restrict__ c, const float* __restrict__ g,
                                                 const float* __restrict__ bia, float* __restrict__ outf,
                                                 bf16* __restrict__ outb) {
    __shared__ float red[8];
    int row = blockIdx.x, d = threadIdx.x;
    size_t idx = (size_t)row * D_ + d;
    float v = a[idx] + b2[idx] + (c ? c[idx] : 0.f);
    float s = v;
    for (int m = 32; m >= 1; m >>= 1) s += __shfl_xor(s, m, 64);
    int wid = threadIdx.x >> 6;
    if ((threadIdx.x & 63) == 0) red[wid] = s;
    __syncthreads();
    float mean = (red[0] + red[1] + red[2] + red[3]) * (1.f / 256.f);
    __syncthreads();
    float dv = v - mean;
    float q = dv * dv;
    for (int m = 32; m >= 1; m >>= 1) q += __shfl_xor(q, m, 64);
    if ((threadIdx.x & 63) == 0) red[wid] = q;
    __syncthreads();
    float var = (red[0] + red[1] + red[2] + red[3]) * (1.f / 256.f);
    float o = dv * rsqrtf(var + 1e-6f) * g[d] + bia[d];
    if (outf) outf[idx] = o;
    if (outb) outb[idx] = __float2bfloat16(o);
}

extern "C" void kernel_launch(void* const* d_in, const int* in_sizes, int n_in, void* d_out, int out_size,
                              void* d_ws, size_t ws_size, hipStream_t stream) {
    const float* x = (const float*)d_in[0];
    const float* lWq = (const float*)d_in[1];  const float* lbq = (const float*)d_in[2];
    const float* lWk = (const float*)d_in[3];  const float* lbk = (const float*)d_in[4];
    const float* lWv = (const float*)d_in[5];  const float* lbv = (const float*)d_in[6];
    const float* lWo = (const float*)d_in[7];  const float* lbo = (const float*)d_in[8];
    const float* gWq = (const float*)d_in[9];  const float* gbq = (const float*)d_in[10];
    const float* gWk = (const float*)d_in[11]; const float* gbk = (const float*)d_in[12];
    const float* gWv = (const float*)d_in[13]; const float* gbv = (const float*)d_in[14];
    const float* gWo = (const float*)d_in[15]; const float* gbo = (const float*)d_in[16];
    const float* fW1 = (const float*)d_in[17]; const float* fb1 = (const float*)d_in[18];
    const float* fW2 = (const float*)d_in[19]; const float* fb2 = (const float*)d_in[20];
    const float* ln1g = (const float*)d_in[21]; const float* ln1b = (const float*)d_in[22];
    const float* ln2g = (const float*)d_in[23]; const float* ln2b = (const float*)d_in[24];

    char* ws = (char*)d_ws;
    size_t off = 0;
    auto alloc = [&](size_t bytes) -> char* {
        char* p = ws + off;
        off = (off + bytes + 255) & ~(size_t)255;
        return p;
    };
    bf16* xb = (bf16*)alloc((size_t)BT_ * D_ * 2);
    bf16* wq_t = (bf16*)alloc((size_t)HK_ * D_ * 2);
    bf16* wk_t = (bf16*)alloc((size_t)HK_ * D_ * 2);
    bf16* wv_t = (bf16*)alloc((size_t)HK_ * D_ * 2);
    bf16* wo_t = (bf16*)alloc((size_t)D_ * HK_ * 2);
    bf16* gwq_t = (bf16*)alloc((size_t)HK_ * D_ * 2);
    bf16* gwk_t = (bf16*)alloc((size_t)HK_ * D_ * 2);
    bf16* gwv_t = (bf16*)alloc((size_t)HK_ * D_ * 2);
    bf16* gwo_t = (bf16*)alloc((size_t)D_ * HK_ * 2);
    bf16* fw1_t = (bf16*)alloc((size_t)FF_ * D_ * 2);
    bf16* fw2_t = (bf16*)alloc((size_t)D_ * FF_ * 2);
    bf16* Qb = (bf16*)alloc((size_t)BT_ * HK_ * 2);
    bf16* Kb = (bf16*)alloc((size_t)BT_ * HK_ * 2);
    bf16* Vb = (bf16*)alloc((size_t)BT_ * HK_ * 2);
    bf16* Ob = (bf16*)alloc((size_t)BT_ * HK_ * 2);
    float* attnA = (float*)alloc((size_t)BT_ * D_ * 4);
    float* attnB = (float*)alloc((size_t)BT_ * D_ * 4);
    float* out1 = (float*)alloc((size_t)BT_ * D_ * 4);
    float* og = (float*)alloc((size_t)B_ * H_ * 2 * KD_ * 4);
    bf16* K2 = (bf16*)alloc((size_t)B_ * 2 * HK_ * 2);
    bf16* V2 = (bf16*)alloc((size_t)B_ * 2 * HK_ * 2);
    // aliases (lifetimes verified against launch order):
    bf16* hid = Qb;           // FFN hidden, after gQ last read (gx_attn)
    bf16* out1b = Kb;         // after gK last read (g2_qk)
    float* ffn = (float*)Vb;  // after gV last read (g2_qk)

    // 1. convert + transposes
    f32_to_bf16_vec<<<(BT_ * D_) / 1024, 256, 0, stream>>>(x, xb, BT_ * D_);
    dim3 tb(32, 8);
    transpose_to_bf16<<<dim3(HK_ / 32, D_ / 32), tb, 0, stream>>>(lWq, wq_t, D_, HK_);
    transpose_to_bf16<<<dim3(HK_ / 32, D_ / 32), tb, 0, stream>>>(lWk, wk_t, D_, HK_);
    transpose_to_bf16<<<dim3(HK_ / 32, D_ / 32), tb, 0, stream>>>(lWv, wv_t, D_, HK_);
    transpose_to_bf16<<<dim3(D_ / 32, HK_ / 32), tb, 0, stream>>>(lWo, wo_t, HK_, D_);
    transpose_to_bf16<<<dim3(HK_ / 32, D_ / 32), tb, 0, stream>>>(gWq, gwq_t, D_, HK_);
    transpose_to_bf16<<<dim3(HK_ / 32, D_ / 32), tb, 0, stream>>>(gWk, gwk_t, D_, HK_);
    transpose_to_bf16<<<dim3(HK_ / 32, D_ / 32), tb, 0, stream>>>(gWv, gwv_t, D_, HK_);
    transpose_to_bf16<<<dim3(D_ / 32, HK_ / 32), tb, 0, stream>>>(gWo, gwo_t, HK_, D_);
    transpose_to_bf16<<<dim3(FF_ / 32, D_ / 32), tb, 0, stream>>>(fW1, fw1_t, D_, FF_);
    transpose_to_bf16<<<dim3(D_ / 32, FF_ / 32), tb, 0, stream>>>(fW2, fw2_t, FF_, D_);

    // 2. local attention path
    gemm_bt<1><<<dim3(HK_ / 64, BT_ / 64), 256, 0, stream>>>(xb, wq_t, lbq, Qb, BT_, HK_, D_);
    gemm_bt<1><<<dim3(HK_ / 64, BT_ / 64), 256, 0, stream>>>(xb, wk_t, lbk, Kb, BT_, HK_, D_);
    gemm_bt<1><<<dim3(HK_ / 64, BT_ / 64), 256, 0, stream>>>(xb, wv_t, lbv, Vb, BT_, HK_, D_);
    local_attn<<<dim3(T_ / 64, B_ * H_), 256, 0, stream>>>(Qb, Kb, Vb, Ob);
    gemm_bt<0><<<dim3(D_ / 64, BT_ / 64), 256, 0, stream>>>(Ob, wo_t, lbo, attnA, BT_, D_, HK_);

    // 3. global path
    gemm_bt<1><<<dim3(HK_ / 64, BT_ / 64), 256, 0, stream>>>(xb, gwk_t, gbk, Kb, BT_, HK_, D_);
    gemm_bt<1><<<dim3(HK_ / 64, BT_ / 64), 256, 0, stream>>>(xb, gwv_t, gbv, Vb, BT_, HK_, D_);
    g2_qk<<<B_ * H_, 256, 0, stream>>>(x, gwq_t, gbq, Kb, Vb, og);
    g2_out<<<B_, 256, 0, stream>>>(og, gwo_t, gbo, gwk_t, gbk, gwv_t, gbv, K2, V2);
    gemm_bt<1><<<dim3(HK_ / 64, BT_ / 64), 256, 0, stream>>>(xb, gwq_t, gbq, Qb, BT_, HK_, D_);
    gx_attn<<<BT_, 256, 0, stream>>>(Qb, K2, V2, Ob);
    gemm_bt<0><<<dim3(D_ / 64, BT_ / 64), 256, 0, stream>>>(Ob, gwo_t, gbo, attnB, BT_, D_, HK_);

    // 4. LN1 + FFN + LN2
    ln_kernel<<<BT_, 256, 0, stream>>>(x, attnA, attnB, ln1g, ln1b, out1, out1b);
    gemm_bt<2><<<dim3(FF_ / 64, BT_ / 64), 256, 0, stream>>>(out1b, fw1_t, fb1, hid, BT_, FF_, D_);
    gemm_bt<0><<<dim3(D_ / 64, BT_ / 64), 256, 0, stream>>>(hid, fw2_t, fb2, ffn, BT_, D_, FF_);
    ln_kernel<<<BT_, 256, 0, stream>>>(out1, ffn, nullptr, ln2g, ln2b, (float*)d_out, nullptr);
}

// Round 2
// 470.542 us; speedup vs baseline: 1.4948x; 1.4948x over previous
//
#include <hip/hip_runtime.h>
#include <hip/hip_bf16.h>

#define B_ 8
#define T_ 1024
#define D_ 256
#define H_ 8
#define KD_ 256
#define HK_ 2048
#define FF_ 1024
#define WIN_ 64
#define BT_ 8192

using bf16 = __hip_bfloat16;
typedef float f32x4 __attribute__((ext_vector_type(4)));
typedef short s16x8 __attribute__((ext_vector_type(8)));

__device__ inline float b2f(bf16 h) { return __bfloat162float(h); }
__device__ inline float bs2f(short s) {
    unsigned int u = ((unsigned int)(unsigned short)s) << 16;
    return __builtin_bit_cast(float, u);
}
__device__ inline short f2bs(float x) { bf16 h = __float2bfloat16(x); return __builtin_bit_cast(short, h); }
__device__ inline unsigned short fbits(float x) { bf16 h = __float2bfloat16(x); return __builtin_bit_cast(unsigned short, h); }

// async global->LDS, 16B per lane; lds base must be wave-uniform, lane l lands at base + l*16
__device__ __forceinline__ void stage16(const void* g, void* l) {
    __builtin_amdgcn_global_load_lds((const __attribute__((address_space(1))) void*)g,
                                     (__attribute__((address_space(3))) void*)l, 16, 0, 0);
}

// ---------------- elementwise f32 -> bf16 ----------------
__global__ __launch_bounds__(256) void f32_to_bf16_vec(const float* __restrict__ in, bf16* __restrict__ out, int n) {
    int i = (blockIdx.x * 256 + threadIdx.x) * 4;
    if (i + 3 < n) {
        float4 v = *(const float4*)(in + i);
        ushort4 o;
        o.x = fbits(v.x); o.y = fbits(v.y); o.z = fbits(v.z); o.w = fbits(v.w);
        *(ushort4*)(out + i) = o;
    }
}

// ---------------- fused weight transposes: in f32[R][C] -> out bf16[C][R] ----------------
struct TJob { const float* in; bf16* out; int R; int C; int tile_start; };
struct TJobs { TJob j[10]; int total; };

__global__ void transpose_all(TJobs js) {
    __shared__ float tile[32][33];
    int bid = blockIdx.x;
    int ji = 0;
    while (ji < 9 && bid >= js.j[ji + 1].tile_start) ji++;
    TJob jb = js.j[ji];
    int t = bid - jb.tile_start;
    int tiles_x = jb.C / 32;
    int cb = (t % tiles_x) * 32, rb = (t / tiles_x) * 32;
    for (int k = 0; k < 4; k++) {
        int r = threadIdx.y + k * 8;
        tile[r][threadIdx.x] = jb.in[(size_t)(rb + r) * jb.C + cb + threadIdx.x];
    }
    __syncthreads();
    for (int k = 0; k < 4; k++) {
        int r = threadIdx.y + k * 8;
        jb.out[(size_t)(cb + r) * jb.R + rb + threadIdx.x] = __float2bfloat16(tile[threadIdx.x][r]);
    }
}

// ---------------- m97-structure GEMM: C[M][N] = A[M][K] * Bt[N][K]^T + bias ----------------
// 128x128 tile, BK=64, 4 waves (2x2), 4x4 16x16x32 frags per wave, global_load_lds staging.
// MODE 0: f32 out; MODE 1: bf16 out; MODE 2: bf16 relu out
template <int MODE>
__global__ __launch_bounds__(256) void gemm128(const bf16* __restrict__ A, const bf16* __restrict__ Bt,
                                               const float* __restrict__ bias, void* __restrict__ C,
                                               int M, int N, int K) {
    __shared__ bf16 As[128 * 64];
    __shared__ bf16 Bs[128 * 64];
    const int tid = threadIdx.x;
    const int w = tid >> 6, l = tid & 63;
    const int m0 = blockIdx.y * 128, n0 = blockIdx.x * 128;
    const int wm = (w >> 1) * 64, wn = (w & 1) * 64;
    const int srow = w * 8 + (l >> 3);   // + j*32
    const int scol = (l & 7) * 8;        // element within BK
    const int ldsOff = w * 512;          // + j*2048 elements (lane offset implicit)
    f32x4 acc[4][4] = {};
    for (int k0 = 0; k0 < K; k0 += 64) {
#pragma unroll
        for (int j = 0; j < 4; j++) {
            stage16(A + (size_t)(m0 + j * 32 + srow) * K + k0 + scol, &As[ldsOff + j * 2048]);
            stage16(Bt + (size_t)(n0 + j * 32 + srow) * K + k0 + scol, &Bs[ldsOff + j * 2048]);
        }
        __syncthreads();
#pragma unroll
        for (int ks = 0; ks < 2; ks++) {
            s16x8 a[4], b[4];
#pragma unroll
            for (int mf = 0; mf < 4; mf++) a[mf] = *(const s16x8*)&As[(wm + mf * 16 + (l & 15)) * 64 + ks * 32 + (l >> 4) * 8];
#pragma unroll
            for (int nf = 0; nf < 4; nf++) b[nf] = *(const s16x8*)&Bs[(wn + nf * 16 + (l & 15)) * 64 + ks * 32 + (l >> 4) * 8];
#pragma unroll
            for (int mf = 0; mf < 4; mf++)
#pragma unroll
                for (int nf = 0; nf < 4; nf++)
                    acc[mf][nf] = __builtin_amdgcn_mfma_f32_16x16x32_bf16(a[mf], b[nf], acc[mf][nf], 0, 0, 0);
        }
        __syncthreads();
    }
#pragma unroll
    for (int mf = 0; mf < 4; mf++)
#pragma unroll
        for (int nf = 0; nf < 4; nf++)
#pragma unroll
            for (int r = 0; r < 4; r++) {
                int row = m0 + wm + mf * 16 + (l >> 4) * 4 + r;
                int col = n0 + wn + nf * 16 + (l & 15);
                float v = acc[mf][nf][r] + bias[col];
                if (MODE == 0)
                    ((float*)C)[(size_t)row * N + col] = v;
                else {
                    if (MODE == 2) v = fmaxf(v, 0.f);
                    ((bf16*)C)[(size_t)row * N + col] = __float2bfloat16(v);
                }
            }
}

// ---------------- local windowed attention (unchanged) ----------------
__global__ __launch_bounds__(256) void local_attn(const bf16* __restrict__ Q, const bf16* __restrict__ K,
                                                  const bf16* __restrict__ V, bf16* __restrict__ O) {
    __shared__ bf16 Qs[64][264];
    __shared__ float Ss[64][132];
    __shared__ bf16 KV[256 * 72];
    const int tid = threadIdx.x, l = tid & 63, w = tid >> 6;
    const int qt = blockIdx.x, bh = blockIdx.y;
    const int b = bh >> 3, h = bh & 7;
    const int qs = qt * 64;
    const size_t base = (size_t)b * T_ * HK_ + h * KD_;
    {
        int row = tid >> 2;
        for (int c = 0; c < 8; c++) {
            int col = ((tid & 3) + 4 * c) * 8;
            *(uint4*)&Qs[row][col] = *(const uint4*)&Q[base + (size_t)(qs + row) * HK_ + col];
        }
    }
    bf16(*Ks)[264] = (bf16(*)[264])KV;
    for (int kb = 0; kb < 2; kb++) {
        __syncthreads();
        {
            int row = tid >> 2;
            int tk = qs - 64 + kb * 64 + row;
            for (int c = 0; c < 8; c++) {
                int col = ((tid & 3) + 4 * c) * 8;
                uint4 val = {0, 0, 0, 0};
                if (tk >= 0) val = *(const uint4*)&K[base + (size_t)tk * HK_ + col];
                *(uint4*)&Ks[row][col] = val;
            }
        }
        __syncthreads();
        const int r0 = w * 16;
        for (int nf = 0; nf < 4; nf++) {
            f32x4 acc = {};
            for (int ks = 0; ks < 8; ks++) {
                s16x8 a = *(const s16x8*)&Qs[r0 + (l & 15)][ks * 32 + (l >> 4) * 8];
                s16x8 bb = *(const s16x8*)&Ks[nf * 16 + (l & 15)][ks * 32 + (l >> 4) * 8];
                acc = __builtin_amdgcn_mfma_f32_16x16x32_bf16(a, bb, acc, 0, 0, 0);
            }
            for (int r = 0; r < 4; r++) {
                int srow = r0 + (l >> 4) * 4 + r;
                int scol = nf * 16 + (l & 15);
                int i = qs + srow, j = qs - 64 + kb * 64 + scol;
                bool valid = (j >= 0) && (j <= i) && (j > i - WIN_);
                Ss[srow][kb * 64 + scol] = valid ? acc[r] * (1.f / 16.f) : -1e9f;
            }
        }
    }
    __syncthreads();
    {
        int row = w * 16 + (l >> 2);
        int c0 = (l & 3) * 32;
        float m = -1e30f;
        for (int c = 0; c < 32; c++) m = fmaxf(m, Ss[row][c0 + c]);
        m = fmaxf(m, __shfl_xor(m, 1, 64));
        m = fmaxf(m, __shfl_xor(m, 2, 64));
        float s = 0.f;
        for (int c = 0; c < 32; c++) {
            float e = __expf(Ss[row][c0 + c] - m);
            Ss[row][c0 + c] = e;
            s += e;
        }
        s += __shfl_xor(s, 1, 64);
        s += __shfl_xor(s, 2, 64);
        float inv = 1.f / s;
        for (int c = 0; c < 32; c++) Ss[row][c0 + c] *= inv;
    }
    bf16(*VT)[72] = (bf16(*)[72])KV;
    f32x4 oacc[16] = {};
    for (int kb = 0; kb < 2; kb++) {
        __syncthreads();
        {
            int row = tid >> 2;
            int tk = qs - 64 + kb * 64 + row;
            for (int c = 0; c < 8; c++) {
                int col = ((tid & 3) + 4 * c) * 8;
                if (tk >= 0) {
                    bf16 tmp[8];
                    *(uint4*)tmp = *(const uint4*)&V[base + (size_t)tk * HK_ + col];
                    for (int e = 0; e < 8; e++) VT[col + e][row] = tmp[e];
                } else {
                    bf16 z = __float2bfloat16(0.f);
                    for (int e = 0; e < 8; e++) VT[col + e][row] = z;
                }
            }
        }
        __syncthreads();
        const int r0 = w * 16;
        for (int ks = 0; ks < 2; ks++) {
            s16x8 a;
            {
                const float* p = &Ss[r0 + (l & 15)][kb * 64 + ks * 32 + (l >> 4) * 8];
                for (int e = 0; e < 8; e++) a[e] = f2bs(p[e]);
            }
            for (int nf = 0; nf < 16; nf++) {
                s16x8 bb = *(const s16x8*)&VT[nf * 16 + (l & 15)][ks * 32 + (l >> 4) * 8];
                oacc[nf] = __builtin_amdgcn_mfma_f32_16x16x32_bf16(a, bb, oacc[nf], 0, 0, 0);
            }
        }
    }
    for (int nf = 0; nf < 16; nf++)
        for (int r = 0; r < 4; r++) {
            int row = w * 16 + (l >> 4) * 4 + r;
            int col = nf * 16 + (l & 15);
            O[base + (size_t)(qs + row) * HK_ + col] = __float2bfloat16(oacc[nf][r]);
        }
}

// ---------------- global path (rewritten, parallel) ----------------
// scores: grid (B*H, T/256). q rows = gQ[b, T-2 + i, h*KD + :]
__global__ __launch_bounds__(256) void g2_scores(const bf16* __restrict__ gQ, const bf16* __restrict__ gK,
                                                 float* __restrict__ sc) {
    __shared__ float qf[2][256];
    int bh = blockIdx.x, ch = blockIdx.y;
    int b = bh >> 3, h = bh & 7;
    int tid = threadIdx.x;
    for (int i = 0; i < 2; i++)
        qf[i][tid] = b2f(gQ[((size_t)b * T_ + (T_ - 2 + i)) * HK_ + h * KD_ + tid]);
    __syncthreads();
    int t = ch * 256 + tid;
    const bf16* kr = &gK[((size_t)(b * T_ + t)) * HK_ + h * KD_];
    float a0 = 0.f, a1 = 0.f;
    for (int c = 0; c < 32; c++) {
        s16x8 kv = *(const s16x8*)&kr[c * 8];
#pragma unroll
        for (int e = 0; e < 8; e++) {
            float kf = bs2f(kv[e]);
            a0 += kf * qf[0][c * 8 + e];
            a1 += kf * qf[1][c * 8 + e];
        }
    }
    sc[((size_t)bh * 2 + 0) * T_ + t] = a0 * (1.f / 16.f);
    sc[((size_t)bh * 2 + 1) * T_ + t] = a1 * (1.f / 16.f);
}

// softmax over T=1024 per (b,h,i), in place. grid B*H.
__global__ __launch_bounds__(256) void g2_softmax(float* __restrict__ sc) {
    __shared__ float red[4];
    int bh = blockIdx.x, tid = threadIdx.x;
    int w = tid >> 6;
    for (int i = 0; i < 2; i++) {
        float* row = &sc[((size_t)bh * 2 + i) * T_];
        float vals[4];
        float m = -1e30f;
        for (int c = 0; c < 4; c++) {
            vals[c] = row[tid + 256 * c];
            m = fmaxf(m, vals[c]);
        }
        for (int s = 32; s >= 1; s >>= 1) m = fmaxf(m, __shfl_xor(m, s, 64));
        if ((tid & 63) == 0) red[w] = m;
        __syncthreads();
        m = fmaxf(fmaxf(red[0], red[1]), fmaxf(red[2], red[3]));
        __syncthreads();
        float s = 0.f;
        for (int c = 0; c < 4; c++) {
            vals[c] = __expf(vals[c] - m);
            s += vals[c];
        }
        for (int d = 32; d >= 1; d >>= 1) s += __shfl_xor(s, d, 64);
        if ((tid & 63) == 0) red[w] = s;
        __syncthreads();
        s = red[0] + red[1] + red[2] + red[3];
        float inv = 1.f / s;
        for (int c = 0; c < 4; c++) row[tid + 256 * c] = vals[c] * inv;
        __syncthreads();
    }
}

// PV partial: grid (B*H, 4). og_part[(bh*4+ch)*2+i][kd]
__global__ __launch_bounds__(256) void g2_pv(const float* __restrict__ sc, const bf16* __restrict__ gV,
                                             float* __restrict__ og_part) {
    __shared__ float p2[2][256];
    int bh = blockIdx.x, ch = blockIdx.y;
    int b = bh >> 3, h = bh & 7;
    int tid = threadIdx.x;
    for (int i = 0; i < 2; i++) p2[i][tid] = sc[((size_t)bh * 2 + i) * T_ + ch * 256 + tid];
    __syncthreads();
    const bf16* vb = &gV[((size_t)(b * T_ + ch * 256)) * HK_ + h * KD_ + tid];
    float a0 = 0.f, a1 = 0.f;
    for (int t = 0; t < 256; t++) {
        float vv = b2f(vb[(size_t)t * HK_]);
        a0 += p2[0][t] * vv;
        a1 += p2[1][t] * vv;
    }
    og_part[((size_t)(bh * 4 + ch) * 2 + 0) * KD_ + tid] = a0;
    og_part[((size_t)(bh * 4 + ch) * 2 + 1) * KD_ + tid] = a1;
}

// g2[b][i][d] = sum_{h,kd} og[b,h,i,kd] * gWo_t[d][h*KD+kd] + gbo[d]. grid B.
__global__ __launch_bounds__(256) void g2_lin(const float* __restrict__ og_part, const bf16* __restrict__ gwo_t,
                                              const float* __restrict__ gbo, float* __restrict__ g2buf) {
    __shared__ float ogs[2][2048];
    int b = blockIdx.x, tid = threadIdx.x;
    for (int i = 0; i < 2; i++)
        for (int c = 0; c < 8; c++) {
            int idx = tid + 256 * c;
            int h = idx >> 8, kd = idx & 255;
            float s = 0.f;
            for (int ch = 0; ch < 4; ch++)
                s += og_part[((size_t)((b * 8 + h) * 4 + ch) * 2 + i) * KD_ + kd];
            ogs[i][idx] = s;
        }
    __syncthreads();
    const bf16* row = &gwo_t[(size_t)tid * HK_];
    float a0 = gbo[tid], a1 = gbo[tid];
    for (int c = 0; c < 256; c++) {
        s16x8 wv = *(const s16x8*)&row[c * 8];
#pragma unroll
        for (int e = 0; e < 8; e++) {
            float wf = bs2f(wv[e]);
            a0 += ogs[0][c * 8 + e] * wf;
            a1 += ogs[1][c * 8 + e] * wf;
        }
    }
    g2buf[(size_t)(b * 2 + 0) * 256 + tid] = a0;
    g2buf[(size_t)(b * 2 + 1) * 256 + tid] = a1;
}

// K2/V2 = g2 @ gWk/gWv + bias. grid (B*2, HK/256)
__global__ __launch_bounds__(256) void g2_kv(const float* __restrict__ g2buf, const bf16* __restrict__ gwk_t,
                                             const float* __restrict__ gbk, const bf16* __restrict__ gwv_t,
                                             const float* __restrict__ gbv, bf16* __restrict__ K2,
                                             bf16* __restrict__ V2) {
    __shared__ float g2s[256];
    int bi = blockIdx.x, ch = blockIdx.y;
    int tid = threadIdx.x;
    g2s[tid] = g2buf[(size_t)bi * 256 + tid];
    __syncthreads();
    int hk = ch * 256 + tid;
    const bf16* rk = &gwk_t[(size_t)hk * D_];
    const bf16* rv = &gwv_t[(size_t)hk * D_];
    float ak = gbk[hk], av = gbv[hk];
    for (int c = 0; c < 32; c++) {
        s16x8 kw = *(const s16x8*)&rk[c * 8];
        s16x8 vw = *(const s16x8*)&rv[c * 8];
#pragma unroll
        for (int e = 0; e < 8; e++) {
            float g = g2s[c * 8 + e];
            ak += g * bs2f(kw[e]);
            av += g * bs2f(vw[e]);
        }
    }
    K2[(size_t)bi * HK_ + hk] = __float2bfloat16(ak);
    V2[(size_t)bi * HK_ + hk] = __float2bfloat16(av);
}

// gx attention: softmax over 2 keys. grid BT.
__global__ __launch_bounds__(256) void gx_attn(const bf16* __restrict__ gQ, const bf16* __restrict__ K2,
                                               const bf16* __restrict__ V2, bf16* __restrict__ O) {
    int bt = blockIdx.x;
    int b = bt >> 10;
    int tid = threadIdx.x;
    int h = tid >> 5, ln = tid & 31;
    size_t qoff = (size_t)bt * HK_ + h * KD_;
    size_t koff = (size_t)(b * 2) * HK_ + h * KD_;
    float s0 = 0.f, s1 = 0.f;
    for (int c = 0; c < 8; c++) {
        int d = ln + 32 * c;
        float q = b2f(gQ[qoff + d]);
        s0 += q * b2f(K2[koff + d]);
        s1 += q * b2f(K2[koff + HK_ + d]);
    }
    for (int m = 16; m >= 1; m >>= 1) {
        s0 += __shfl_xor(s0, m, 64);
        s1 += __shfl_xor(s1, m, 64);
    }
    s0 *= (1.f / 16.f);
    s1 *= (1.f / 16.f);
    float mx = fmaxf(s0, s1);
    float e0 = __expf(s0 - mx), e1 = __expf(s1 - mx);
    float inv = 1.f / (e0 + e1);
    float p0 = e0 * inv, p1 = e1 * inv;
    for (int c = 0; c < 8; c++) {
        int d = ln + 32 * c;
        float v = p0 * b2f(V2[koff + d]) + p1 * b2f(V2[koff + HK_ + d]);
        O[qoff + d] = __float2bfloat16(v);
    }
}

// ---------------- LayerNorm over D=256, block per row ----------------
__global__ __launch_bounds__(256) void ln_kernel(const float* __restrict__ a, const float* __restrict__ b2,
                                                 const float* __restrict__ c, const float* __restrict__ g,
                                                 const float* __restrict__ bia, float* __restrict__ outf,
                                                 bf16* __restrict__ outb) {
    __shared__ float red[8];
    int row = blockIdx.x, d = threadIdx.x;
    size_t idx = (size_t)row * D_ + d;
    float v = a[idx] + b2[idx] + (c ? c[idx] : 0.f);
    float s = v;
    for (int m = 32; m >= 1; m >>= 1) s += __shfl_xor(s, m, 64);
    int wid = threadIdx.x >> 6;
    if ((threadIdx.x & 63) == 0) red[wid] = s;
    __syncthreads();
    float mean = (red[0] + red[1] + red[2] + red[3]) * (1.f / 256.f);
    __syncthreads();
    float dv = v - mean;
    float q = dv * dv;
    for (int m = 32; m >= 1; m >>= 1) q += __shfl_xor(q, m, 64);
    if ((threadIdx.x & 63) == 0) red[wid] = q;
    __syncthreads();
    float var = (red[0] + red[1] + red[2] + red[3]) * (1.f / 256.f);
    float o = dv * rsqrtf(var + 1e-6f) * g[d] + bia[d];
    if (outf) outf[idx] = o;
    if (outb) outb[idx] = __float2bfloat16(o);
}

extern "C" void kernel_launch(void* const* d_in, const int* in_sizes, int n_in, void* d_out, int out_size,
                              void* d_ws, size_t ws_size, hipStream_t stream) {
    const float* x = (const float*)d_in[0];
    const float* lWq = (const float*)d_in[1];  const float* lbq = (const float*)d_in[2];
    const float* lWk = (const float*)d_in[3];  const float* lbk = (const float*)d_in[4];
    const float* lWv = (const float*)d_in[5];  const float* lbv = (const float*)d_in[6];
    const float* lWo = (const float*)d_in[7];  const float* lbo = (const float*)d_in[8];
    const float* gWq = (const float*)d_in[9];  const float* gbq = (const float*)d_in[10];
    const float* gWk = (const float*)d_in[11]; const float* gbk = (const float*)d_in[12];
    const float* gWv = (const float*)d_in[13]; const float* gbv = (const float*)d_in[14];
    const float* gWo = (const float*)d_in[15]; const float* gbo = (const float*)d_in[16];
    const float* fW1 = (const float*)d_in[17]; const float* fb1 = (const float*)d_in[18];
    const float* fW2 = (const float*)d_in[19]; const float* fb2 = (const float*)d_in[20];
    const float* ln1g = (const float*)d_in[21]; const float* ln1b = (const float*)d_in[22];
    const float* ln2g = (const float*)d_in[23]; const float* ln2b = (const float*)d_in[24];

    char* ws = (char*)d_ws;
    size_t off = 0;
    auto alloc = [&](size_t bytes) -> char* {
        char* p = ws + off;
        off = (off + bytes + 255) & ~(size_t)255;
        return p;
    };
    bf16* xb = (bf16*)alloc((size_t)BT_ * D_ * 2);
    bf16* wq_t = (bf16*)alloc((size_t)HK_ * D_ * 2);
    bf16* wk_t = (bf16*)alloc((size_t)HK_ * D_ * 2);
    bf16* wv_t = (bf16*)alloc((size_t)HK_ * D_ * 2);
    bf16* wo_t = (bf16*)alloc((size_t)D_ * HK_ * 2);
    bf16* gwq_t = (bf16*)alloc((size_t)HK_ * D_ * 2);
    bf16* gwk_t = (bf16*)alloc((size_t)HK_ * D_ * 2);
    bf16* gwv_t = (bf16*)alloc((size_t)HK_ * D_ * 2);
    bf16* gwo_t = (bf16*)alloc((size_t)D_ * HK_ * 2);
    bf16* fw1_t = (bf16*)alloc((size_t)FF_ * D_ * 2);
    bf16* fw2_t = (bf16*)alloc((size_t)D_ * FF_ * 2);
    bf16* Qb = (bf16*)alloc((size_t)BT_ * HK_ * 2);
    bf16* Kb = (bf16*)alloc((size_t)BT_ * HK_ * 2);
    bf16* Vb = (bf16*)alloc((size_t)BT_ * HK_ * 2);
    bf16* Ob = (bf16*)alloc((size_t)BT_ * HK_ * 2);
    float* attnA = (float*)alloc((size_t)BT_ * D_ * 4);
    float* attnB = (float*)alloc((size_t)BT_ * D_ * 4);
    float* out1 = (float*)alloc((size_t)BT_ * D_ * 4);
    float* sc = (float*)alloc((size_t)B_ * H_ * 2 * T_ * 4);
    float* og_part = (float*)alloc((size_t)B_ * H_ * 4 * 2 * KD_ * 4);
    float* g2buf = (float*)alloc((size_t)B_ * 2 * D_ * 4);
    bf16* K2 = (bf16*)alloc((size_t)B_ * 2 * HK_ * 2);
    bf16* V2 = (bf16*)alloc((size_t)B_ * 2 * HK_ * 2);
    // aliases (lifetimes verified against launch order below):
    bf16* hid = Qb;           // FFN hidden; Qb free after gx_attn
    bf16* out1b = Kb;         // Kb free after g2_scores
    float* ffn = (float*)Vb;  // Vb free after g2_pv

    // 0. convert + fused transposes
    f32_to_bf16_vec<<<(BT_ * D_) / 1024, 256, 0, stream>>>(x, xb, BT_ * D_);
    {
        TJobs js;
        int t = 0;
        auto add = [&](int i, const float* in, bf16* out, int R, int C) {
            js.j[i] = {in, out, R, C, t};
            t += (R / 32) * (C / 32);
        };
        add(0, lWq, wq_t, D_, HK_);
        add(1, lWk, wk_t, D_, HK_);
        add(2, lWv, wv_t, D_, HK_);
        add(3, lWo, wo_t, HK_, D_);
        add(4, gWq, gwq_t, D_, HK_);
        add(5, gWk, gwk_t, D_, HK_);
        add(6, gWv, gwv_t, D_, HK_);
        add(7, gWo, gwo_t, HK_, D_);
        add(8, fW1, fw1_t, D_, FF_);
        add(9, fW2, fw2_t, FF_, D_);
        js.total = t;
        transpose_all<<<t, dim3(32, 8), 0, stream>>>(js);
    }

    // 1. local attention path
    gemm128<1><<<dim3(HK_ / 128, BT_ / 128), 256, 0, stream>>>(xb, wq_t, lbq, Qb, BT_, HK_, D_);
    gemm128<1><<<dim3(HK_ / 128, BT_ / 128), 256, 0, stream>>>(xb, wk_t, lbk, Kb, BT_, HK_, D_);
    gemm128<1><<<dim3(HK_ / 128, BT_ / 128), 256, 0, stream>>>(xb, wv_t, lbv, Vb, BT_, HK_, D_);
    local_attn<<<dim3(T_ / 64, B_ * H_), 256, 0, stream>>>(Qb, Kb, Vb, Ob);
    gemm128<0><<<dim3(D_ / 128, BT_ / 128), 256, 0, stream>>>(Ob, wo_t, lbo, attnA, BT_, D_, HK_);

    // 2. global path
    gemm128<1><<<dim3(HK_ / 128, BT_ / 128), 256, 0, stream>>>(xb, gwq_t, gbq, Qb, BT_, HK_, D_);
    gemm128<1><<<dim3(HK_ / 128, BT_ / 128), 256, 0, stream>>>(xb, gwk_t, gbk, Kb, BT_, HK_, D_);
    gemm128<1><<<dim3(HK_ / 128, BT_ / 128), 256, 0, stream>>>(xb, gwv_t, gbv, Vb, BT_, HK_, D_);
    g2_scores<<<dim3(B_ * H_, T_ / 256), 256, 0, stream>>>(Qb, Kb, sc);
    g2_softmax<<<B_ * H_, 256, 0, stream>>>(sc);
    g2_pv<<<dim3(B_ * H_, 4), 256, 0, stream>>>(sc, Vb, og_part);
    g2_lin<<<B_, 256, 0, stream>>>(og_part, gwo_t, gbo, g2buf);
    g2_kv<<<dim3(B_ * 2, HK_ / 256), 256, 0, stream>>>(g2buf, gwk_t, gbk, gwv_t, gbv, K2, V2);
    gx_attn<<<BT_, 256, 0, stream>>>(Qb, K2, V2, Ob);
    gemm128<0><<<dim3(D_ / 128, BT_ / 128), 256, 0, stream>>>(Ob, gwo_t, gbo, attnB, BT_, D_, HK_);

    // 3. LN1 + FFN + LN2
    ln_kernel<<<BT_, 256, 0, stream>>>(x, attnA, attnB, ln1g, ln1b, out1, out1b);
    gemm128<2><<<dim3(FF_ / 128, BT_ / 128), 256, 0, stream>>>(out1b, fw1_t, fb1, hid, BT_, FF_, D_);
    gemm128<0><<<dim3(D_ / 128, BT_ / 128), 256, 0, stream>>>(hid, fw2_t, fb2, ffn, BT_, D_, FF_);
    ln_kernel<<<BT_, 256, 0, stream>>>(out1, ffn, nullptr, ln2g, ln2b, (float*)d_out, nullptr);
}

// Round 4
// 428.318 us; speedup vs baseline: 1.6422x; 1.0986x over previous
//
#include <hip/hip_runtime.h>
#include <hip/hip_bf16.h>

#define B_ 8
#define T_ 1024
#define D_ 256
#define H_ 8
#define KD_ 256
#define HK_ 2048
#define FF_ 1024
#define WIN_ 64
#define BT_ 8192
#define S6_ 6144

using bf16 = __hip_bfloat16;
typedef float f32x4 __attribute__((ext_vector_type(4)));
typedef short s16x8 __attribute__((ext_vector_type(8)));

__device__ inline float b2f(bf16 h) { return __bfloat162float(h); }
__device__ inline float bs2f(short s) {
    unsigned int u = ((unsigned int)(unsigned short)s) << 16;
    return __builtin_bit_cast(float, u);
}
__device__ inline short f2bs(float x) { bf16 h = __float2bfloat16(x); return __builtin_bit_cast(short, h); }
__device__ inline unsigned short fbits(float x) { bf16 h = __float2bfloat16(x); return __builtin_bit_cast(unsigned short, h); }

// async global->LDS, 16B per lane; lds base wave-uniform, lane l lands at base + l*16
__device__ __forceinline__ void stage16(const void* g, void* l) {
    __builtin_amdgcn_global_load_lds((const __attribute__((address_space(1))) void*)g,
                                     (__attribute__((address_space(3))) void*)l, 16, 0, 0);
}

// ---------------- elementwise f32 -> bf16 ----------------
__global__ __launch_bounds__(256) void f32_to_bf16_vec(const float* __restrict__ in, bf16* __restrict__ out, int n) {
    int i = (blockIdx.x * 256 + threadIdx.x) * 4;
    if (i + 3 < n) {
        float4 v = *(const float4*)(in + i);
        ushort4 o;
        o.x = fbits(v.x); o.y = fbits(v.y); o.z = fbits(v.z); o.w = fbits(v.w);
        *(ushort4*)(out + i) = o;
    }
}

// ---------------- fused weight transposes: in f32[R][C] -> out bf16[C][R] ----------------
struct TJob { const float* in; bf16* out; int R; int C; int tile_start; };
struct TJobs { TJob j[10]; int total; };

__global__ void transpose_all(TJobs js) {
    __shared__ float tile[32][33];
    int bid = blockIdx.x;
    int ji = 0;
    while (ji < 9 && bid >= js.j[ji + 1].tile_start) ji++;
    TJob jb = js.j[ji];
    int t = bid - jb.tile_start;
    int tiles_x = jb.C / 32;
    int cb = (t % tiles_x) * 32, rb = (t / tiles_x) * 32;
    for (int k = 0; k < 4; k++) {
        int r = threadIdx.y + k * 8;
        tile[r][threadIdx.x] = jb.in[(size_t)(rb + r) * jb.C + cb + threadIdx.x];
    }
    __syncthreads();
    for (int k = 0; k < 4; k++) {
        int r = threadIdx.y + k * 8;
        jb.out[(size_t)(cb + r) * jb.R + rb + threadIdx.x] = __float2bfloat16(tile[threadIdx.x][r]);
    }
}

// concat 3 biases (2048 each) into 6144, both local and global sets
__global__ __launch_bounds__(256) void concat_bias(const float* a0, const float* a1, const float* a2,
                                                   const float* b0, const float* b1, const float* b2,
                                                   float* outL, float* outG) {
    int i = blockIdx.x * 256 + threadIdx.x;
    int seg = i >> 11, off = i & 2047;
    const float* pl = seg == 0 ? a0 : seg == 1 ? a1 : a2;
    const float* pg = seg == 0 ? b0 : seg == 1 ? b1 : b2;
    outL[i] = pl[off];
    outG[i] = pg[off];
}

// ---------------- m97-structure GEMM: C[M][N] = A[M][K] * Bt[N][K]^T + bias ----------------
// 128xBN tile, BK=64, 4 waves, global_load_lds staging.
// MODE 0: f32 out; MODE 1: bf16 out; MODE 2: bf16 relu out
template <int MODE, int BN>
__global__ __launch_bounds__(256) void gemm128(const bf16* __restrict__ A, const bf16* __restrict__ Bt,
                                               const float* __restrict__ bias, void* __restrict__ C,
                                               int M, int N, int K) {
    constexpr int NF = BN / 32;
    __shared__ bf16 As[128 * 64];
    __shared__ bf16 Bs[BN * 64];
    const int tid = threadIdx.x;
    const int w = tid >> 6, l = tid & 63;
    const int m0 = blockIdx.y * 128, n0 = blockIdx.x * BN;
    const int wm = (w >> 1) * 64, wn = (w & 1) * (BN / 2);
    const int srow = w * 8 + (l >> 3);
    const int scol = (l & 7) * 8;
    const int ldsOff = w * 512;
    f32x4 acc[4][NF] = {};
    for (int k0 = 0; k0 < K; k0 += 64) {
#pragma unroll
        for (int j = 0; j < 4; j++)
            stage16(A + (size_t)(m0 + j * 32 + srow) * K + k0 + scol, &As[ldsOff + j * 2048]);
#pragma unroll
        for (int j = 0; j < BN / 32; j++)
            stage16(Bt + (size_t)(n0 + j * 32 + srow) * K + k0 + scol, &Bs[ldsOff + j * 2048]);
        __syncthreads();
#pragma unroll
        for (int ks = 0; ks < 2; ks++) {
            s16x8 a[4], b[NF];
#pragma unroll
            for (int mf = 0; mf < 4; mf++) a[mf] = *(const s16x8*)&As[(wm + mf * 16 + (l & 15)) * 64 + ks * 32 + (l >> 4) * 8];
#pragma unroll
            for (int nf = 0; nf < NF; nf++) b[nf] = *(const s16x8*)&Bs[(wn + nf * 16 + (l & 15)) * 64 + ks * 32 + (l >> 4) * 8];
            __builtin_amdgcn_s_setprio(1);
#pragma unroll
            for (int mf = 0; mf < 4; mf++)
#pragma unroll
                for (int nf = 0; nf < NF; nf++)
                    acc[mf][nf] = __builtin_amdgcn_mfma_f32_16x16x32_bf16(a[mf], b[nf], acc[mf][nf], 0, 0, 0);
            __builtin_amdgcn_s_setprio(0);
        }
        __syncthreads();
    }
#pragma unroll
    for (int mf = 0; mf < 4; mf++)
#pragma unroll
        for (int nf = 0; nf < NF; nf++)
#pragma unroll
            for (int r = 0; r < 4; r++) {
                int row = m0 + wm + mf * 16 + (l >> 4) * 4 + r;
                int col = n0 + wn + nf * 16 + (l & 15);
                float v = acc[mf][nf][r] + bias[col];
                if (MODE == 0)
                    ((float*)C)[(size_t)row * N + col] = v;
                else {
                    if (MODE == 2) v = fmaxf(v, 0.f);
                    ((bf16*)C)[(size_t)row * N + col] = __float2bfloat16(v);
                }
            }
}

// ---------------- local windowed attention (round-2 proven version, QKV strides) ----------------
// QKV: [B*T][6144] (lQ | lK | lV). O: [B*T][2048]. grid (T/64, B*H), 256 threads.
__global__ __launch_bounds__(256) void local_attn(const bf16* __restrict__ QKV, bf16* __restrict__ O) {
    __shared__ bf16 Qs[64][264];
    __shared__ float Ss[64][132];
    __shared__ bf16 KV[256 * 72];  // phase1: Ks[64][264]; phase2: VT[256][72]
    const int tid = threadIdx.x, l = tid & 63, w = tid >> 6;
    const int qt = blockIdx.x, bh = blockIdx.y;
    const int b = bh >> 3, h = bh & 7;
    const int qs = qt * 64;
    const size_t obase = (size_t)b * T_ * HK_ + h * KD_;

    {   // load Q tile
        int row = tid >> 2;
        const bf16* qrow = QKV + (size_t)(b * T_ + qs + row) * S6_ + h * KD_;
        for (int c = 0; c < 8; c++) {
            int col = ((tid & 3) + 4 * c) * 8;
            *(uint4*)&Qs[row][col] = *(const uint4*)(qrow + col);
        }
    }
    bf16(*Ks)[264] = (bf16(*)[264])KV;
    for (int kb = 0; kb < 2; kb++) {
        __syncthreads();
        {
            int row = tid >> 2;
            int tk = qs - 64 + kb * 64 + row;
            for (int c = 0; c < 8; c++) {
                int col = ((tid & 3) + 4 * c) * 8;
                uint4 val = {0, 0, 0, 0};
                if (tk >= 0) val = *(const uint4*)(QKV + (size_t)(b * T_ + tk) * S6_ + 2048 + h * KD_ + col);
                *(uint4*)&Ks[row][col] = val;
            }
        }
        __syncthreads();
        const int r0 = w * 16;
        for (int nf = 0; nf < 4; nf++) {
            f32x4 acc = {};
            for (int ks = 0; ks < 8; ks++) {
                s16x8 a = *(const s16x8*)&Qs[r0 + (l & 15)][ks * 32 + (l >> 4) * 8];
                s16x8 bb = *(const s16x8*)&Ks[nf * 16 + (l & 15)][ks * 32 + (l >> 4) * 8];
                acc = __builtin_amdgcn_mfma_f32_16x16x32_bf16(a, bb, acc, 0, 0, 0);
            }
            for (int r = 0; r < 4; r++) {
                int srow = r0 + (l >> 4) * 4 + r;
                int scol = nf * 16 + (l & 15);
                int i = qs + srow, j = qs - 64 + kb * 64 + scol;
                bool valid = (j >= 0) && (j <= i) && (j > i - WIN_);
                Ss[srow][kb * 64 + scol] = valid ? acc[r] * (1.f / 16.f) : -1e9f;
            }
        }
    }
    __syncthreads();
    {   // softmax: wave w handles rows w*16 + (l>>2); 4 lanes/row, 32 cols each
        int row = w * 16 + (l >> 2);
        int c0 = (l & 3) * 32;
        float m = -1e30f;
        for (int c = 0; c < 32; c++) m = fmaxf(m, Ss[row][c0 + c]);
        m = fmaxf(m, __shfl_xor(m, 1, 64));
        m = fmaxf(m, __shfl_xor(m, 2, 64));
        float s = 0.f;
        for (int c = 0; c < 32; c++) {
            float e = __expf(Ss[row][c0 + c] - m);
            Ss[row][c0 + c] = e;
            s += e;
        }
        s += __shfl_xor(s, 1, 64);
        s += __shfl_xor(s, 2, 64);
        float inv = 1.f / s;
        for (int c = 0; c < 32; c++) Ss[row][c0 + c] *= inv;
    }
    bf16(*VT)[72] = (bf16(*)[72])KV;
    f32x4 oacc[16] = {};
    for (int kb = 0; kb < 2; kb++) {
        __syncthreads();
        {
            int row = tid >> 2;
            int tk = qs - 64 + kb * 64 + row;
            for (int c = 0; c < 8; c++) {
                int col = ((tid & 3) + 4 * c) * 8;
                if (tk >= 0) {
                    bf16 tmp[8];
                    *(uint4*)tmp = *(const uint4*)(QKV + (size_t)(b * T_ + tk) * S6_ + 4096 + h * KD_ + col);
                    for (int e = 0; e < 8; e++) VT[col + e][row] = tmp[e];
                } else {
                    bf16 z = __float2bfloat16(0.f);
                    for (int e = 0; e < 8; e++) VT[col + e][row] = z;
                }
            }
        }
        __syncthreads();
        const int r0 = w * 16;
        for (int ks = 0; ks < 2; ks++) {
            s16x8 a;
            {
                const float* p = &Ss[r0 + (l & 15)][kb * 64 + ks * 32 + (l >> 4) * 8];
                for (int e = 0; e < 8; e++) a[e] = f2bs(p[e]);
            }
            for (int nf = 0; nf < 16; nf++) {
                s16x8 bb = *(const s16x8*)&VT[nf * 16 + (l & 15)][ks * 32 + (l >> 4) * 8];
                oacc[nf] = __builtin_amdgcn_mfma_f32_16x16x32_bf16(a, bb, oacc[nf], 0, 0, 0);
            }
        }
    }
    for (int nf = 0; nf < 16; nf++)
        for (int r = 0; r < 4; r++) {
            int row = w * 16 + (l >> 4) * 4 + r;
            int col = nf * 16 + (l & 15);
            O[obase + (size_t)(qs + row) * HK_ + col] = __float2bfloat16(oacc[nf][r]);
        }
}

// ---------------- global path (split, parallel) ----------------
// scores: grid (B*H, T/256). q rows = QKV[b, T-2+i, head h]
__global__ __launch_bounds__(256) void g2_scores(const bf16* __restrict__ QKV, float* __restrict__ sc) {
    __shared__ float qf[2][256];
    int bh = blockIdx.x, ch = blockIdx.y;
    int b = bh >> 3, h = bh & 7;
    int tid = threadIdx.x;
    for (int i = 0; i < 2; i++)
        qf[i][tid] = b2f(QKV[((size_t)b * T_ + (T_ - 2 + i)) * S6_ + h * KD_ + tid]);
    __syncthreads();
    int t = ch * 256 + tid;
    const bf16* kr = &QKV[((size_t)(b * T_ + t)) * S6_ + 2048 + h * KD_];
    float a0 = 0.f, a1 = 0.f;
    for (int c = 0; c < 32; c++) {
        s16x8 kv = *(const s16x8*)&kr[c * 8];
#pragma unroll
        for (int e = 0; e < 8; e++) {
            float kf = bs2f(kv[e]);
            a0 += kf * qf[0][c * 8 + e];
            a1 += kf * qf[1][c * 8 + e];
        }
    }
    sc[((size_t)bh * 2 + 0) * T_ + t] = a0 * (1.f / 16.f);
    sc[((size_t)bh * 2 + 1) * T_ + t] = a1 * (1.f / 16.f);
}

__global__ __launch_bounds__(256) void g2_softmax(float* __restrict__ sc) {
    __shared__ float red[4];
    int bh = blockIdx.x, tid = threadIdx.x;
    int w = tid >> 6;
    for (int i = 0; i < 2; i++) {
        float* row = &sc[((size_t)bh * 2 + i) * T_];
        float vals[4];
        float m = -1e30f;
        for (int c = 0; c < 4; c++) {
            vals[c] = row[tid + 256 * c];
            m = fmaxf(m, vals[c]);
        }
        for (int s = 32; s >= 1; s >>= 1) m = fmaxf(m, __shfl_xor(m, s, 64));
        if ((tid & 63) == 0) red[w] = m;
        __syncthreads();
        m = fmaxf(fmaxf(red[0], red[1]), fmaxf(red[2], red[3]));
        __syncthreads();
        float s = 0.f;
        for (int c = 0; c < 4; c++) {
            vals[c] = __expf(vals[c] - m);
            s += vals[c];
        }
        for (int d = 32; d >= 1; d >>= 1) s += __shfl_xor(s, d, 64);
        if ((tid & 63) == 0) red[w] = s;
        __syncthreads();
        s = red[0] + red[1] + red[2] + red[3];
        float inv = 1.f / s;
        for (int c = 0; c < 4; c++) row[tid + 256 * c] = vals[c] * inv;
        __syncthreads();
    }
}

__global__ __launch_bounds__(256) void g2_pv(const float* __restrict__ sc, const bf16* __restrict__ QKV,
                                             float* __restrict__ og_part) {
    __shared__ float p2[2][256];
    int bh = blockIdx.x, ch = blockIdx.y;
    int b = bh >> 3, h = bh & 7;
    int tid = threadIdx.x;
    for (int i = 0; i < 2; i++) p2[i][tid] = sc[((size_t)bh * 2 + i) * T_ + ch * 256 + tid];
    __syncthreads();
    const bf16* vb = &QKV[((size_t)(b * T_ + ch * 256)) * S6_ + 4096 + h * KD_ + tid];
    float a0 = 0.f, a1 = 0.f;
    for (int t = 0; t < 256; t++) {
        float vv = b2f(vb[(size_t)t * S6_]);
        a0 += p2[0][t] * vv;
        a1 += p2[1][t] * vv;
    }
    og_part[((size_t)(bh * 4 + ch) * 2 + 0) * KD_ + tid] = a0;
    og_part[((size_t)(bh * 4 + ch) * 2 + 1) * KD_ + tid] = a1;
}

__global__ __launch_bounds__(256) void g2_lin(const float* __restrict__ og_part, const bf16* __restrict__ gwo_t,
                                              const float* __restrict__ gbo, float* __restrict__ g2buf) {
    __shared__ float ogs[2][2048];
    int b = blockIdx.x, tid = threadIdx.x;
    for (int i = 0; i < 2; i++)
        for (int c = 0; c < 8; c++) {
            int idx = tid + 256 * c;
            int h = idx >> 8, kd = idx & 255;
            float s = 0.f;
            for (int ch = 0; ch < 4; ch++)
                s += og_part[((size_t)((b * 8 + h) * 4 + ch) * 2 + i) * KD_ + kd];
            ogs[i][idx] = s;
        }
    __syncthreads();
    const bf16* row = &gwo_t[(size_t)tid * HK_];
    float a0 = gbo[tid], a1 = gbo[tid];
    for (int c = 0; c < 256; c++) {
        s16x8 wv = *(const s16x8*)&row[c * 8];
#pragma unroll
        for (int e = 0; e < 8; e++) {
            float wf = bs2f(wv[e]);
            a0 += ogs[0][c * 8 + e] * wf;
            a1 += ogs[1][c * 8 + e] * wf;
        }
    }
    g2buf[(size_t)(b * 2 + 0) * 256 + tid] = a0;
    g2buf[(size_t)(b * 2 + 1) * 256 + tid] = a1;
}

__global__ __launch_bounds__(256) void g2_kv(const float* __restrict__ g2buf, const bf16* __restrict__ gwk_t,
                                             const float* __restrict__ gbk, const bf16* __restrict__ gwv_t,
                                             const float* __restrict__ gbv, bf16* __restrict__ K2,
                                             bf16* __restrict__ V2) {
    __shared__ float g2s[256];
    int bi = blockIdx.x, ch = blockIdx.y;
    int tid = threadIdx.x;
    g2s[tid] = g2buf[(size_t)bi * 256 + tid];
    __syncthreads();
    int hk = ch * 256 + tid;
    const bf16* rk = &gwk_t[(size_t)hk * D_];
    const bf16* rv = &gwv_t[(size_t)hk * D_];
    float ak = gbk[hk], av = gbv[hk];
    for (int c = 0; c < 32; c++) {
        s16x8 kw = *(const s16x8*)&rk[c * 8];
        s16x8 vw = *(const s16x8*)&rv[c * 8];
#pragma unroll
        for (int e = 0; e < 8; e++) {
            float g = g2s[c * 8 + e];
            ak += g * bs2f(kw[e]);
            av += g * bs2f(vw[e]);
        }
    }
    K2[(size_t)bi * HK_ + hk] = __float2bfloat16(ak);
    V2[(size_t)bi * HK_ + hk] = __float2bfloat16(av);
}

// gx attention: softmax over 2 keys. gQ = QKV cols 0..2047 (stride 6144). grid BT.
__global__ __launch_bounds__(256) void gx_attn(const bf16* __restrict__ QKV, const bf16* __restrict__ K2,
                                               const bf16* __restrict__ V2, bf16* __restrict__ O) {
    int bt = blockIdx.x;
    int b = bt >> 10;
    int tid = threadIdx.x;
    int h = tid >> 5, ln = tid & 31;
    size_t qoff = (size_t)bt * S6_ + h * KD_;
    size_t koff = (size_t)(b * 2) * HK_ + h * KD_;
    float s0 = 0.f, s1 = 0.f;
    for (int c = 0; c < 8; c++) {
        int d = ln + 32 * c;
        float q = b2f(QKV[qoff + d]);
        s0 += q * b2f(K2[koff + d]);
        s1 += q * b2f(K2[koff + HK_ + d]);
    }
    for (int m = 16; m >= 1; m >>= 1) {
        s0 += __shfl_xor(s0, m, 64);
        s1 += __shfl_xor(s1, m, 64);
    }
    s0 *= (1.f / 16.f);
    s1 *= (1.f / 16.f);
    float mx = fmaxf(s0, s1);
    float e0 = __expf(s0 - mx), e1 = __expf(s1 - mx);
    float inv = 1.f / (e0 + e1);
    float p0 = e0 * inv, p1 = e1 * inv;
    for (int c = 0; c < 8; c++) {
        int d = ln + 32 * c;
        float v = p0 * b2f(V2[koff + d]) + p1 * b2f(V2[koff + HK_ + d]);
        O[(size_t)bt * HK_ + h * KD_ + d] = __float2bfloat16(v);
    }
}

// ---------------- LayerNorm over D=256, block per row ----------------
__global__ __launch_bounds__(256) void ln_kernel(const float* __restrict__ a, const float* __restrict__ b2,
                                                 const float* __restrict__ c, const float* __restrict__ g,
                                                 const float* __restrict__ bia, float* __restrict__ outf,
                                                 bf16* __restrict__ outb) {
    __shared__ float red[8];
    int row = blockIdx.x, d = threadIdx.x;
    size_t idx = (size_t)row * D_ + d;
    float v = a[idx] + b2[idx] + (c ? c[idx] : 0.f);
    float s = v;
    for (int m = 32; m >= 1; m >>= 1) s += __shfl_xor(s, m, 64);
    int wid = threadIdx.x >> 6;
    if ((threadIdx.x & 63) == 0) red[wid] = s;
    __syncthreads();
    float mean = (red[0] + red[1] + red[2] + red[3]) * (1.f / 256.f);
    __syncthreads();
    float dv = v - mean;
    float q = dv * dv;
    for (int m = 32; m >= 1; m >>= 1) q += __shfl_xor(q, m, 64);
    if ((threadIdx.x & 63) == 0) red[wid] = q;
    __syncthreads();
    float var = (red[0] + red[1] + red[2] + red[3]) * (1.f / 256.f);
    float o = dv * rsqrtf(var + 1e-6f) * g[d] + bia[d];
    if (outf) outf[idx] = o;
    if (outb) outb[idx] = __float2bfloat16(o);
}

extern "C" void kernel_launch(void* const* d_in, const int* in_sizes, int n_in, void* d_out, int out_size,
                              void* d_ws, size_t ws_size, hipStream_t stream) {
    const float* x = (const float*)d_in[0];
    const float* lWq = (const float*)d_in[1];  const float* lbq = (const float*)d_in[2];
    const float* lWk = (const float*)d_in[3];  const float* lbk = (const float*)d_in[4];
    const float* lWv = (const float*)d_in[5];  const float* lbv = (const float*)d_in[6];
    const float* lWo = (const float*)d_in[7];  const float* lbo = (const float*)d_in[8];
    const float* gWq = (const float*)d_in[9];  const float* gbq = (const float*)d_in[10];
    const float* gWk = (const float*)d_in[11]; const float* gbk = (const float*)d_in[12];
    const float* gWv = (const float*)d_in[13]; const float* gbv = (const float*)d_in[14];
    const float* gWo = (const float*)d_in[15]; const float* gbo = (const float*)d_in[16];
    const float* fW1 = (const float*)d_in[17]; const float* fb1 = (const float*)d_in[18];
    const float* fW2 = (const float*)d_in[19]; const float* fb2 = (const float*)d_in[20];
    const float* ln1g = (const float*)d_in[21]; const float* ln1b = (const float*)d_in[22];
    const float* ln2g = (const float*)d_in[23]; const float* ln2b = (const float*)d_in[24];

    char* ws = (char*)d_ws;
    size_t off = 0;
    auto alloc = [&](size_t bytes) -> char* {
        char* p = ws + off;
        off = (off + bytes + 255) & ~(size_t)255;
        return p;
    };
    bf16* xb = (bf16*)alloc((size_t)BT_ * D_ * 2);
    bf16* WcatL = (bf16*)alloc((size_t)S6_ * D_ * 2);   // [lWq|lWk|lWv]^T, K-major
    bf16* WcatG = (bf16*)alloc((size_t)S6_ * D_ * 2);
    bf16* wo_t = (bf16*)alloc((size_t)D_ * HK_ * 2);
    bf16* gwo_t = (bf16*)alloc((size_t)D_ * HK_ * 2);
    bf16* fw1_t = (bf16*)alloc((size_t)FF_ * D_ * 2);
    bf16* fw2_t = (bf16*)alloc((size_t)D_ * FF_ * 2);
    float* bcatL = (float*)alloc((size_t)S6_ * 4);
    float* bcatG = (float*)alloc((size_t)S6_ * 4);
    bf16* QKV = (bf16*)alloc((size_t)BT_ * S6_ * 2);    // 96 MB, reused local->global
    bf16* Ob = (bf16*)alloc((size_t)BT_ * HK_ * 2);     // 32 MB
    float* attnA = (float*)alloc((size_t)BT_ * D_ * 4);
    float* attnB = (float*)alloc((size_t)BT_ * D_ * 4);
    float* out1 = (float*)alloc((size_t)BT_ * D_ * 4);
    float* sc = (float*)alloc((size_t)B_ * H_ * 2 * T_ * 4);
    float* og_part = (float*)alloc((size_t)B_ * H_ * 4 * 2 * KD_ * 4);
    float* g2buf = (float*)alloc((size_t)B_ * 2 * D_ * 4);
    bf16* K2 = (bf16*)alloc((size_t)B_ * 2 * HK_ * 2);
    bf16* V2 = (bf16*)alloc((size_t)B_ * 2 * HK_ * 2);
    // aliases into QKV (projection data dead after gx_attn + attnB gemm):
    bf16* hid = QKV;                                    // [8192][1024] bf16, 16 MB @ 0
    float* ffn = (float*)((char*)QKV + (32u << 20));    // 8 MB @ 32M
    bf16* out1b = (bf16*)((char*)QKV + (48u << 20));    // 4 MB @ 48M

    // 0. convert + fused transposes + bias concat
    f32_to_bf16_vec<<<(BT_ * D_) / 1024, 256, 0, stream>>>(x, xb, BT_ * D_);
    {
        TJobs js;
        int t = 0;
        auto add = [&](int i, const float* in, bf16* out, int R, int C) {
            js.j[i] = {in, out, R, C, t};
            t += (R / 32) * (C / 32);
        };
        add(0, lWq, WcatL, D_, HK_);
        add(1, lWk, WcatL + (size_t)2048 * D_, D_, HK_);
        add(2, lWv, WcatL + (size_t)4096 * D_, D_, HK_);
        add(3, lWo, wo_t, HK_, D_);
        add(4, gWq, WcatG, D_, HK_);
        add(5, gWk, WcatG + (size_t)2048 * D_, D_, HK_);
        add(6, gWv, WcatG + (size_t)4096 * D_, D_, HK_);
        add(7, gWo, gwo_t, HK_, D_);
        add(8, fW1, fw1_t, D_, FF_);
        add(9, fW2, fw2_t, FF_, D_);
        js.total = t;
        transpose_all<<<t, dim3(32, 8), 0, stream>>>(js);
    }
    concat_bias<<<S6_ / 256, 256, 0, stream>>>(lbq, lbk, lbv, gbq, gbk, gbv, bcatL, bcatG);

    // 1. local path: merged QKV projection, attention, out-proj
    gemm128<1, 128><<<dim3(S6_ / 128, BT_ / 128), 256, 0, stream>>>(xb, WcatL, bcatL, QKV, BT_, S6_, D_);
    local_attn<<<dim3(T_ / 64, B_ * H_), 256, 0, stream>>>(QKV, Ob);
    gemm128<0, 64><<<dim3(D_ / 64, BT_ / 128), 256, 0, stream>>>(Ob, wo_t, lbo, attnA, BT_, D_, HK_);

    // 2. global path
    gemm128<1, 128><<<dim3(S6_ / 128, BT_ / 128), 256, 0, stream>>>(xb, WcatG, bcatG, QKV, BT_, S6_, D_);
    g2_scores<<<dim3(B_ * H_, T_ / 256), 256, 0, stream>>>(QKV, sc);
    g2_softmax<<<B_ * H_, 256, 0, stream>>>(sc);
    g2_pv<<<dim3(B_ * H_, 4), 256, 0, stream>>>(sc, QKV, og_part);
    g2_lin<<<B_, 256, 0, stream>>>(og_part, gwo_t, gbo, g2buf);
    g2_kv<<<dim3(B_ * 2, HK_ / 256), 256, 0, stream>>>(g2buf, WcatG + (size_t)2048 * D_, gbk,
                                                       WcatG + (size_t)4096 * D_, gbv, K2, V2);
    gx_attn<<<BT_, 256, 0, stream>>>(QKV, K2, V2, Ob);
    gemm128<0, 64><<<dim3(D_ / 64, BT_ / 128), 256, 0, stream>>>(Ob, gwo_t, gbo, attnB, BT_, D_, HK_);

    // 3. LN1 + FFN + LN2
    ln_kernel<<<BT_, 256, 0, stream>>>(x, attnA, attnB, ln1g, ln1b, out1, out1b);
    gemm128<2, 128><<<dim3(FF_ / 128, BT_ / 128), 256, 0, stream>>>(out1b, fw1_t, fb1, hid, BT_, FF_, D_);
    gemm128<0, 64><<<dim3(D_ / 64, BT_ / 128), 256, 0, stream>>>(hid, fw2_t, fb2, ffn, BT_, D_, FF_);
    ln_kernel<<<BT_, 256, 0, stream>>>(out1, ffn, nullptr, ln2g, ln2b, (float*)d_out, nullptr);
}

// Round 5
// 347.169 us; speedup vs baseline: 2.0261x; 1.2337x over previous
//
#include <hip/hip_runtime.h>
#include <hip/hip_bf16.h>

#define B_ 8
#define T_ 1024
#define D_ 256
#define H_ 8
#define KD_ 256
#define HK_ 2048
#define FF_ 1024
#define WIN_ 64
#define BT_ 8192
#define S6_ 6144

using bf16 = __hip_bfloat16;
typedef float f32x4 __attribute__((ext_vector_type(4)));
typedef short s16x8 __attribute__((ext_vector_type(8)));

__device__ inline float b2f(bf16 h) { return __bfloat162float(h); }
__device__ inline float bs2f(short s) {
    unsigned int u = ((unsigned int)(unsigned short)s) << 16;
    return __builtin_bit_cast(float, u);
}
__device__ inline unsigned short fbits(float x) { bf16 h = __float2bfloat16(x); return __builtin_bit_cast(unsigned short, h); }

// async global->LDS, 16B per lane; lds base wave-uniform, lane l lands at base + l*16
__device__ __forceinline__ void stage16(const void* g, void* l) {
    __builtin_amdgcn_global_load_lds((const __attribute__((address_space(1))) void*)g,
                                     (__attribute__((address_space(3))) void*)l, 16, 0, 0);
}

// ---------------- elementwise f32 -> bf16 ----------------
__global__ __launch_bounds__(256) void f32_to_bf16_vec(const float* __restrict__ in, bf16* __restrict__ out, int n) {
    int i = (blockIdx.x * 256 + threadIdx.x) * 4;
    if (i + 3 < n) {
        float4 v = *(const float4*)(in + i);
        ushort4 o;
        o.x = fbits(v.x); o.y = fbits(v.y); o.z = fbits(v.z); o.w = fbits(v.w);
        *(ushort4*)(out + i) = o;
    }
}

// ---------------- fused weight transposes: in f32[R][C] -> out bf16[C][R] ----------------
struct TJob { const float* in; bf16* out; int R; int C; int tile_start; };
struct TJobs { TJob j[10]; int total; };

__global__ void transpose_all(TJobs js) {
    __shared__ float tile[32][33];
    int bid = blockIdx.x;
    int ji = 0;
    while (ji < 9 && bid >= js.j[ji + 1].tile_start) ji++;
    TJob jb = js.j[ji];
    int t = bid - jb.tile_start;
    int tiles_x = jb.C / 32;
    int cb = (t % tiles_x) * 32, rb = (t / tiles_x) * 32;
    for (int k = 0; k < 4; k++) {
        int r = threadIdx.y + k * 8;
        tile[r][threadIdx.x] = jb.in[(size_t)(rb + r) * jb.C + cb + threadIdx.x];
    }
    __syncthreads();
    for (int k = 0; k < 4; k++) {
        int r = threadIdx.y + k * 8;
        jb.out[(size_t)(cb + r) * jb.R + rb + threadIdx.x] = __float2bfloat16(tile[threadIdx.x][r]);
    }
}

// concat 3 biases (2048 each) into 6144, both local and global sets
__global__ __launch_bounds__(256) void concat_bias(const float* a0, const float* a1, const float* a2,
                                                   const float* b0, const float* b1, const float* b2,
                                                   float* outL, float* outG) {
    int i = blockIdx.x * 256 + threadIdx.x;
    int seg = i >> 11, off = i & 2047;
    const float* pl = seg == 0 ? a0 : seg == 1 ? a1 : a2;
    const float* pg = seg == 0 ? b0 : seg == 1 ? b1 : b2;
    outL[i] = pl[off];
    outG[i] = pg[off];
}

// ---------------- m97-structure GEMM: C[M][N] = A[M][K] * Bt[N][K]^T + bias ----------------
template <int MODE, int BN>
__global__ __launch_bounds__(256) void gemm128(const bf16* __restrict__ A, const bf16* __restrict__ Bt,
                                               const float* __restrict__ bias, void* __restrict__ C,
                                               int M, int N, int K) {
    constexpr int NF = BN / 32;
    __shared__ bf16 As[128 * 64];
    __shared__ bf16 Bs[BN * 64];
    const int tid = threadIdx.x;
    const int w = tid >> 6, l = tid & 63;
    const int m0 = blockIdx.y * 128, n0 = blockIdx.x * BN;
    const int wm = (w >> 1) * 64, wn = (w & 1) * (BN / 2);
    const int srow = w * 8 + (l >> 3);
    const int scol = (l & 7) * 8;
    const int ldsOff = w * 512;
    f32x4 acc[4][NF] = {};
    for (int k0 = 0; k0 < K; k0 += 64) {
#pragma unroll
        for (int j = 0; j < 4; j++)
            stage16(A + (size_t)(m0 + j * 32 + srow) * K + k0 + scol, &As[ldsOff + j * 2048]);
#pragma unroll
        for (int j = 0; j < BN / 32; j++)
            stage16(Bt + (size_t)(n0 + j * 32 + srow) * K + k0 + scol, &Bs[ldsOff + j * 2048]);
        __syncthreads();
#pragma unroll
        for (int ks = 0; ks < 2; ks++) {
            s16x8 a[4], b[NF];
#pragma unroll
            for (int mf = 0; mf < 4; mf++) a[mf] = *(const s16x8*)&As[(wm + mf * 16 + (l & 15)) * 64 + ks * 32 + (l >> 4) * 8];
#pragma unroll
            for (int nf = 0; nf < NF; nf++) b[nf] = *(const s16x8*)&Bs[(wn + nf * 16 + (l & 15)) * 64 + ks * 32 + (l >> 4) * 8];
            __builtin_amdgcn_s_setprio(1);
#pragma unroll
            for (int mf = 0; mf < 4; mf++)
#pragma unroll
                for (int nf = 0; nf < NF; nf++)
                    acc[mf][nf] = __builtin_amdgcn_mfma_f32_16x16x32_bf16(a[mf], b[nf], acc[mf][nf], 0, 0, 0);
            __builtin_amdgcn_s_setprio(0);
        }
        __syncthreads();
    }
#pragma unroll
    for (int mf = 0; mf < 4; mf++)
#pragma unroll
        for (int nf = 0; nf < NF; nf++)
#pragma unroll
            for (int r = 0; r < 4; r++) {
                int row = m0 + wm + mf * 16 + (l >> 4) * 4 + r;
                int col = n0 + wn + nf * 16 + (l & 15);
                float v = acc[mf][nf][r] + bias[col];
                if (MODE == 0)
                    ((float*)C)[(size_t)row * N + col] = v;
                else {
                    if (MODE == 2) v = fmaxf(v, 0.f);
                    ((bf16*)C)[(size_t)row * N + col] = __float2bfloat16(v);
                }
            }
}

// ---------------- local windowed attention v3 ----------------
// Proven dataflow (round-2) with: Q-frags direct from global, in-register softmax
// (verified v2 mapping), bf16 P in LDS. VT scatter + reads = proven round-2 code.
// QKV: [B*T][6144] (lQ | lK | lV). O: [B*T][2048]. grid (T/64, B*H), 256 threads.
__global__ __launch_bounds__(256) void local_attn(const bf16* __restrict__ QKV, bf16* __restrict__ O) {
    __shared__ bf16 U[256 * 72];     // phase1: Ks[64][264]; phase2: VT[256][72]
    __shared__ bf16 Ps[64][136];     // bf16 probabilities
    const int tid = threadIdx.x, l = tid & 63, w = tid >> 6;
    const int qt = blockIdx.x, bh = blockIdx.y;
    const int b = bh >> 3, h = bh & 7;
    const int qs = qt * 64;
    const int r0 = w * 16;
    const int lrow = tid >> 2, lc4 = (tid & 3) * 8;
    const size_t obase = (size_t)b * T_ * HK_ + h * KD_;

    // ---- Q fragments direct from global (wave-private rows) ----
    s16x8 qa[8];
    {
        const bf16* qbase = QKV + (size_t)(b * T_ + qs + r0 + (l & 15)) * S6_ + h * KD_ + (l >> 4) * 8;
#pragma unroll
        for (int ks = 0; ks < 8; ks++) qa[ks] = *(const s16x8*)(qbase + ks * 32);
    }

    bf16(*Ks)[264] = (bf16(*)[264])U;
    // ---- stage K kb=0 (keys qs-64..qs-1) ----
    {
        int tk = qs - 64 + lrow;
        const bf16* krow = QKV + (size_t)(b * T_ + tk) * S6_ + 2048 + h * KD_;
#pragma unroll
        for (int c = 0; c < 8; c++) {
            int col = lc4 + c * 32;
            uint4 val = {0, 0, 0, 0};
            if (tk >= 0) val = *(const uint4*)(krow + col);
            *(uint4*)&Ks[lrow][col] = val;
        }
    }
    __syncthreads();
    f32x4 sacc[8];
#pragma unroll
    for (int f = 0; f < 8; f++) sacc[f] = (f32x4){0.f, 0.f, 0.f, 0.f};
    __builtin_amdgcn_s_setprio(1);
#pragma unroll
    for (int nf = 0; nf < 4; nf++)
#pragma unroll
        for (int ks = 0; ks < 8; ks++) {
            s16x8 bb = *(const s16x8*)&Ks[nf * 16 + (l & 15)][ks * 32 + (l >> 4) * 8];
            sacc[nf] = __builtin_amdgcn_mfma_f32_16x16x32_bf16(qa[ks], bb, sacc[nf], 0, 0, 0);
        }
    __builtin_amdgcn_s_setprio(0);
    __syncthreads();
    // ---- stage K kb=1 (keys qs..qs+63) ----
    {
        const bf16* krow = QKV + (size_t)(b * T_ + qs + lrow) * S6_ + 2048 + h * KD_;
#pragma unroll
        for (int c = 0; c < 8; c++) {
            int col = lc4 + c * 32;
            *(uint4*)&Ks[lrow][col] = *(const uint4*)(krow + col);
        }
    }
    __syncthreads();
    __builtin_amdgcn_s_setprio(1);
#pragma unroll
    for (int nf = 0; nf < 4; nf++)
#pragma unroll
        for (int ks = 0; ks < 8; ks++) {
            s16x8 bb = *(const s16x8*)&Ks[nf * 16 + (l & 15)][ks * 32 + (l >> 4) * 8];
            sacc[4 + nf] = __builtin_amdgcn_mfma_f32_16x16x32_bf16(qa[ks], bb, sacc[4 + nf], 0, 0, 0);
        }
    __builtin_amdgcn_s_setprio(0);

    // issue V kb=0 global loads early (latency hidden under softmax)
    uint4 vreg[8];
    {
        int tk = qs - 64 + lrow;
        const bf16* vrow = QKV + (size_t)(b * T_ + tk) * S6_ + 4096 + h * KD_;
#pragma unroll
        for (int c = 0; c < 8; c++) {
            uint4 v = {0, 0, 0, 0};
            if (tk >= 0) v = *(const uint4*)(vrow + lc4 + c * 32);
            vreg[c] = v;
        }
    }

    // ---- mask + in-register softmax (rows r0+(l>>4)*4+r; cols f*16+(l&15)) ----
#pragma unroll
    for (int r = 0; r < 4; r++) {
        int i = qs + r0 + (l >> 4) * 4 + r;
#pragma unroll
        for (int f = 0; f < 8; f++) {
            int j = qs - 64 + f * 16 + (l & 15);
            bool valid = (j >= 0) && (j <= i) && (j > i - WIN_);
            sacc[f][r] = valid ? sacc[f][r] * (1.f / 16.f) : -1e9f;
        }
        float mm = -1e30f;
#pragma unroll
        for (int f = 0; f < 8; f++) mm = fmaxf(mm, sacc[f][r]);
        mm = fmaxf(mm, __shfl_xor(mm, 1, 64));
        mm = fmaxf(mm, __shfl_xor(mm, 2, 64));
        mm = fmaxf(mm, __shfl_xor(mm, 4, 64));
        mm = fmaxf(mm, __shfl_xor(mm, 8, 64));
        float ss = 0.f;
#pragma unroll
        for (int f = 0; f < 8; f++) {
            float e = __expf(sacc[f][r] - mm);
            sacc[f][r] = e;
            ss += e;
        }
        ss += __shfl_xor(ss, 1, 64);
        ss += __shfl_xor(ss, 2, 64);
        ss += __shfl_xor(ss, 4, 64);
        ss += __shfl_xor(ss, 8, 64);
        float inv = 1.f / ss;
#pragma unroll
        for (int f = 0; f < 8; f++) sacc[f][r] *= inv;
    }
    __syncthreads();  // all waves done reading Ks; U can become VT

    // ---- write P (bf16) + scatter V kb=0 into VT (proven layout) ----
    bf16(*VT)[72] = (bf16(*)[72])U;
#pragma unroll
    for (int f = 0; f < 8; f++)
#pragma unroll
        for (int r = 0; r < 4; r++)
            Ps[r0 + (l >> 4) * 4 + r][f * 16 + (l & 15)] = __float2bfloat16(sacc[f][r]);
#pragma unroll
    for (int c = 0; c < 8; c++) {
        int col = lc4 + c * 32;
        bf16 tmp[8];
        *(uint4*)tmp = vreg[c];
        for (int e = 0; e < 8; e++) VT[col + e][lrow] = tmp[e];
    }
    __syncthreads();
    // issue V kb=1 loads now (hidden under PV kb=0)
    {
        const bf16* vrow = QKV + (size_t)(b * T_ + qs + lrow) * S6_ + 4096 + h * KD_;
#pragma unroll
        for (int c = 0; c < 8; c++) vreg[c] = *(const uint4*)(vrow + lc4 + c * 32);
    }

    // ---- PV (proven mapping): wave w -> O rows r0..r0+15, all 256 cols ----
    f32x4 oacc[16];
#pragma unroll
    for (int nf = 0; nf < 16; nf++) oacc[nf] = (f32x4){0.f, 0.f, 0.f, 0.f};
    for (int kb = 0; kb < 2; kb++) {
#pragma unroll
        for (int ks = 0; ks < 2; ks++) {
            s16x8 a = *(const s16x8*)&Ps[r0 + (l & 15)][kb * 64 + ks * 32 + (l >> 4) * 8];
            __builtin_amdgcn_s_setprio(1);
#pragma unroll
            for (int nf = 0; nf < 16; nf++) {
                s16x8 bb = *(const s16x8*)&VT[nf * 16 + (l & 15)][ks * 32 + (l >> 4) * 8];
                oacc[nf] = __builtin_amdgcn_mfma_f32_16x16x32_bf16(a, bb, oacc[nf], 0, 0, 0);
            }
            __builtin_amdgcn_s_setprio(0);
        }
        if (kb == 0) {
            __syncthreads();  // done reading VT kb=0
#pragma unroll
            for (int c = 0; c < 8; c++) {
                int col = lc4 + c * 32;
                bf16 tmp[8];
                *(uint4*)tmp = vreg[c];
                for (int e = 0; e < 8; e++) VT[col + e][lrow] = tmp[e];
            }
            __syncthreads();
        }
    }
    // epilogue
#pragma unroll
    for (int nf = 0; nf < 16; nf++)
#pragma unroll
        for (int r = 0; r < 4; r++) {
            int row = r0 + (l >> 4) * 4 + r;
            int col = nf * 16 + (l & 15);
            O[obase + (size_t)(qs + row) * HK_ + col] = __float2bfloat16(oacc[nf][r]);
        }
}

// ---------------- global path (split, parallel) ----------------
__global__ __launch_bounds__(256) void g2_scores(const bf16* __restrict__ QKV, float* __restrict__ sc) {
    __shared__ float qf[2][256];
    int bh = blockIdx.x, ch = blockIdx.y;
    int b = bh >> 3, h = bh & 7;
    int tid = threadIdx.x;
    for (int i = 0; i < 2; i++)
        qf[i][tid] = b2f(QKV[((size_t)b * T_ + (T_ - 2 + i)) * S6_ + h * KD_ + tid]);
    __syncthreads();
    int t = ch * 256 + tid;
    const bf16* kr = &QKV[((size_t)(b * T_ + t)) * S6_ + 2048 + h * KD_];
    float a0 = 0.f, a1 = 0.f;
    for (int c = 0; c < 32; c++) {
        s16x8 kv = *(const s16x8*)&kr[c * 8];
#pragma unroll
        for (int e = 0; e < 8; e++) {
            float kf = bs2f(kv[e]);
            a0 += kf * qf[0][c * 8 + e];
            a1 += kf * qf[1][c * 8 + e];
        }
    }
    sc[((size_t)bh * 2 + 0) * T_ + t] = a0 * (1.f / 16.f);
    sc[((size_t)bh * 2 + 1) * T_ + t] = a1 * (1.f / 16.f);
}

__global__ __launch_bounds__(256) void g2_softmax(float* __restrict__ sc) {
    __shared__ float red[4];
    int bh = blockIdx.x, tid = threadIdx.x;
    int w = tid >> 6;
    for (int i = 0; i < 2; i++) {
        float* row = &sc[((size_t)bh * 2 + i) * T_];
        float vals[4];
        float m = -1e30f;
        for (int c = 0; c < 4; c++) {
            vals[c] = row[tid + 256 * c];
            m = fmaxf(m, vals[c]);
        }
        for (int s = 32; s >= 1; s >>= 1) m = fmaxf(m, __shfl_xor(m, s, 64));
        if ((tid & 63) == 0) red[w] = m;
        __syncthreads();
        m = fmaxf(fmaxf(red[0], red[1]), fmaxf(red[2], red[3]));
        __syncthreads();
        float s = 0.f;
        for (int c = 0; c < 4; c++) {
            vals[c] = __expf(vals[c] - m);
            s += vals[c];
        }
        for (int d = 32; d >= 1; d >>= 1) s += __shfl_xor(s, d, 64);
        if ((tid & 63) == 0) red[w] = s;
        __syncthreads();
        s = red[0] + red[1] + red[2] + red[3];
        float inv = 1.f / s;
        for (int c = 0; c < 4; c++) row[tid + 256 * c] = vals[c] * inv;
        __syncthreads();
    }
}

__global__ __launch_bounds__(256) void g2_pv(const float* __restrict__ sc, const bf16* __restrict__ QKV,
                                             float* __restrict__ og_part) {
    __shared__ float p2[2][256];
    int bh = blockIdx.x, ch = blockIdx.y;
    int b = bh >> 3, h = bh & 7;
    int tid = threadIdx.x;
    for (int i = 0; i < 2; i++) p2[i][tid] = sc[((size_t)bh * 2 + i) * T_ + ch * 256 + tid];
    __syncthreads();
    const bf16* vb = &QKV[((size_t)(b * T_ + ch * 256)) * S6_ + 4096 + h * KD_ + tid];
    float a0 = 0.f, a1 = 0.f;
    for (int t = 0; t < 256; t++) {
        float vv = b2f(vb[(size_t)t * S6_]);
        a0 += p2[0][t] * vv;
        a1 += p2[1][t] * vv;
    }
    og_part[((size_t)(bh * 4 + ch) * 2 + 0) * KD_ + tid] = a0;
    og_part[((size_t)(bh * 4 + ch) * 2 + 1) * KD_ + tid] = a1;
}

// reduce og_part chunks -> og2[(b*2+i)*2048 + h*256+kd]. grid 128.
__global__ __launch_bounds__(256) void g2_red(const float* __restrict__ og_part, float* __restrict__ og2) {
    int idx = blockIdx.x * 256 + threadIdx.x;  // (b,h,i,kd)
    int kd = idx & 255, i = (idx >> 8) & 1, h = (idx >> 9) & 7, b = idx >> 12;
    int bh = b * 8 + h;
    float s = 0.f;
    for (int ch = 0; ch < 4; ch++) s += og_part[((size_t)(bh * 4 + ch) * 2 + i) * KD_ + kd];
    og2[(size_t)(b * 2 + i) * 2048 + h * 256 + kd] = s;
}

// g2buf[bi][d] = og2[bi][:] . gwo_t[d][:] + gbo[d]. grid (16,16), 16 lanes/output.
__global__ __launch_bounds__(256) void g2_lin(const float* __restrict__ og2, const bf16* __restrict__ gwo_t,
                                              const float* __restrict__ gbo, float* __restrict__ g2buf) {
    int bi = blockIdx.x, tid = threadIdx.x;
    int d = blockIdx.y * 16 + (tid >> 4);
    int s16i = tid & 15;
    const float* ogr = og2 + (size_t)bi * 2048 + s16i * 128;
    const bf16* wr = gwo_t + (size_t)d * HK_ + s16i * 128;
    float acc = 0.f;
    for (int c = 0; c < 16; c++) {
        s16x8 wv = *(const s16x8*)&wr[c * 8];
#pragma unroll
        for (int e = 0; e < 8; e++) acc += ogr[c * 8 + e] * bs2f(wv[e]);
    }
    acc += __shfl_xor(acc, 1, 64);
    acc += __shfl_xor(acc, 2, 64);
    acc += __shfl_xor(acc, 4, 64);
    acc += __shfl_xor(acc, 8, 64);
    if (s16i == 0) g2buf[(size_t)bi * 256 + d] = acc + gbo[d];
}

__global__ __launch_bounds__(256) void g2_kv(const float* __restrict__ g2buf, const bf16* __restrict__ gwk_t,
                                             const float* __restrict__ gbk, const bf16* __restrict__ gwv_t,
                                             const float* __restrict__ gbv, bf16* __restrict__ K2,
                                             bf16* __restrict__ V2) {
    __shared__ float g2s[256];
    int bi = blockIdx.x, ch = blockIdx.y;
    int tid = threadIdx.x;
    g2s[tid] = g2buf[(size_t)bi * 256 + tid];
    __syncthreads();
    int hk = ch * 256 + tid;
    const bf16* rk = &gwk_t[(size_t)hk * D_];
    const bf16* rv = &gwv_t[(size_t)hk * D_];
    float ak = gbk[hk], av = gbv[hk];
    for (int c = 0; c < 32; c++) {
        s16x8 kw = *(const s16x8*)&rk[c * 8];
        s16x8 vw = *(const s16x8*)&rv[c * 8];
#pragma unroll
        for (int e = 0; e < 8; e++) {
            float g = g2s[c * 8 + e];
            ak += g * bs2f(kw[e]);
            av += g * bs2f(vw[e]);
        }
    }
    K2[(size_t)bi * HK_ + hk] = __float2bfloat16(ak);
    V2[(size_t)bi * HK_ + hk] = __float2bfloat16(av);
}

// gx attention: softmax over 2 keys. gQ = QKV cols 0..2047 (stride 6144). grid BT.
__global__ __launch_bounds__(256) void gx_attn(const bf16* __restrict__ QKV, const bf16* __restrict__ K2,
                                               const bf16* __restrict__ V2, bf16* __restrict__ O) {
    int bt = blockIdx.x;
    int b = bt >> 10;
    int tid = threadIdx.x;
    int h = tid >> 5, ln = tid & 31;
    size_t qoff = (size_t)bt * S6_ + h * KD_;
    size_t koff = (size_t)(b * 2) * HK_ + h * KD_;
    float s0 = 0.f, s1 = 0.f;
    for (int c = 0; c < 8; c++) {
        int d = ln + 32 * c;
        float q = b2f(QKV[qoff + d]);
        s0 += q * b2f(K2[koff + d]);
        s1 += q * b2f(K2[koff + HK_ + d]);
    }
    for (int m = 16; m >= 1; m >>= 1) {
        s0 += __shfl_xor(s0, m, 64);
        s1 += __shfl_xor(s1, m, 64);
    }
    s0 *= (1.f / 16.f);
    s1 *= (1.f / 16.f);
    float mx = fmaxf(s0, s1);
    float e0 = __expf(s0 - mx), e1 = __expf(s1 - mx);
    float inv = 1.f / (e0 + e1);
    float p0 = e0 * inv, p1 = e1 * inv;
    for (int c = 0; c < 8; c++) {
        int d = ln + 32 * c;
        float v = p0 * b2f(V2[koff + d]) + p1 * b2f(V2[koff + HK_ + d]);
        O[(size_t)bt * HK_ + h * KD_ + d] = __float2bfloat16(v);
    }
}

// ---------------- LayerNorm over D=256, block per row ----------------
__global__ __launch_bounds__(256) void ln_kernel(const float* __restrict__ a, const float* __restrict__ b2,
                                                 const float* __restrict__ c, const float* __restrict__ g,
                                                 const float* __restrict__ bia, float* __restrict__ outf,
                                                 bf16* __restrict__ outb) {
    __shared__ float red[8];
    int row = blockIdx.x, d = threadIdx.x;
    size_t idx = (size_t)row * D_ + d;
    float v = a[idx] + b2[idx] + (c ? c[idx] : 0.f);
    float s = v;
    for (int m = 32; m >= 1; m >>= 1) s += __shfl_xor(s, m, 64);
    int wid = threadIdx.x >> 6;
    if ((threadIdx.x & 63) == 0) red[wid] = s;
    __syncthreads();
    float mean = (red[0] + red[1] + red[2] + red[3]) * (1.f / 256.f);
    __syncthreads();
    float dv = v - mean;
    float q = dv * dv;
    for (int m = 32; m >= 1; m >>= 1) q += __shfl_xor(q, m, 64);
    if ((threadIdx.x & 63) == 0) red[wid] = q;
    __syncthreads();
    float var = (red[0] + red[1] + red[2] + red[3]) * (1.f / 256.f);
    float o = dv * rsqrtf(var + 1e-6f) * g[d] + bia[d];
    if (outf) outf[idx] = o;
    if (outb) outb[idx] = __float2bfloat16(o);
}

extern "C" void kernel_launch(void* const* d_in, const int* in_sizes, int n_in, void* d_out, int out_size,
                              void* d_ws, size_t ws_size, hipStream_t stream) {
    const float* x = (const float*)d_in[0];
    const float* lWq = (const float*)d_in[1];  const float* lbq = (const float*)d_in[2];
    const float* lWk = (const float*)d_in[3];  const float* lbk = (const float*)d_in[4];
    const float* lWv = (const float*)d_in[5];  const float* lbv = (const float*)d_in[6];
    const float* lWo = (const float*)d_in[7];  const float* lbo = (const float*)d_in[8];
    const float* gWq = (const float*)d_in[9];  const float* gbq = (const float*)d_in[10];
    const float* gWk = (const float*)d_in[11]; const float* gbk = (const float*)d_in[12];
    const float* gWv = (const float*)d_in[13]; const float* gbv = (const float*)d_in[14];
    const float* gWo = (const float*)d_in[15]; const float* gbo = (const float*)d_in[16];
    const float* fW1 = (const float*)d_in[17]; const float* fb1 = (const float*)d_in[18];
    const float* fW2 = (const float*)d_in[19]; const float* fb2 = (const float*)d_in[20];
    const float* ln1g = (const float*)d_in[21]; const float* ln1b = (const float*)d_in[22];
    const float* ln2g = (const float*)d_in[23]; const float* ln2b = (const float*)d_in[24];

    char* ws = (char*)d_ws;
    size_t off = 0;
    auto alloc = [&](size_t bytes) -> char* {
        char* p = ws + off;
        off = (off + bytes + 255) & ~(size_t)255;
        return p;
    };
    bf16* xb = (bf16*)alloc((size_t)BT_ * D_ * 2);
    bf16* WcatL = (bf16*)alloc((size_t)S6_ * D_ * 2);   // [lWq|lWk|lWv]^T, K-major
    bf16* WcatG = (bf16*)alloc((size_t)S6_ * D_ * 2);
    bf16* wo_t = (bf16*)alloc((size_t)D_ * HK_ * 2);
    bf16* gwo_t = (bf16*)alloc((size_t)D_ * HK_ * 2);
    bf16* fw1_t = (bf16*)alloc((size_t)FF_ * D_ * 2);
    bf16* fw2_t = (bf16*)alloc((size_t)D_ * FF_ * 2);
    float* bcatL = (float*)alloc((size_t)S6_ * 4);
    float* bcatG = (float*)alloc((size_t)S6_ * 4);
    bf16* QKV = (bf16*)alloc((size_t)BT_ * S6_ * 2);    // 96 MB, reused local->global
    bf16* Ob = (bf16*)alloc((size_t)BT_ * HK_ * 2);     // 32 MB
    float* attnA = (float*)alloc((size_t)BT_ * D_ * 4);
    float* attnB = (float*)alloc((size_t)BT_ * D_ * 4);
    float* out1 = (float*)alloc((size_t)BT_ * D_ * 4);
    float* sc = (float*)alloc((size_t)B_ * H_ * 2 * T_ * 4);
    float* og_part = (float*)alloc((size_t)B_ * H_ * 4 * 2 * KD_ * 4);
    float* og2 = (float*)alloc((size_t)B_ * 2 * HK_ * 4);
    float* g2buf = (float*)alloc((size_t)B_ * 2 * D_ * 4);
    bf16* K2 = (bf16*)alloc((size_t)B_ * 2 * HK_ * 2);
    bf16* V2 = (bf16*)alloc((size_t)B_ * 2 * HK_ * 2);
    // aliases into QKV (projection data dead after gx_attn + attnB gemm):
    bf16* hid = QKV;                                    // [8192][1024] bf16, 16 MB @ 0
    float* ffn = (float*)((char*)QKV + (32u << 20));    // 8 MB @ 32M
    bf16* out1b = (bf16*)((char*)QKV + (48u << 20));    // 4 MB @ 48M

    // 0. convert + fused transposes + bias concat
    f32_to_bf16_vec<<<(BT_ * D_) / 1024, 256, 0, stream>>>(x, xb, BT_ * D_);
    {
        TJobs js;
        int t = 0;
        auto add = [&](int i, const float* in, bf16* out, int R, int C) {
            js.j[i] = {in, out, R, C, t};
            t += (R / 32) * (C / 32);
        };
        add(0, lWq, WcatL, D_, HK_);
        add(1, lWk, WcatL + (size_t)2048 * D_, D_, HK_);
        add(2, lWv, WcatL + (size_t)4096 * D_, D_, HK_);
        add(3, lWo, wo_t, HK_, D_);
        add(4, gWq, WcatG, D_, HK_);
        add(5, gWk, WcatG + (size_t)2048 * D_, D_, HK_);
        add(6, gWv, WcatG + (size_t)4096 * D_, D_, HK_);
        add(7, gWo, gwo_t, HK_, D_);
        add(8, fW1, fw1_t, D_, FF_);
        add(9, fW2, fw2_t, FF_, D_);
        js.total = t;
        transpose_all<<<t, dim3(32, 8), 0, stream>>>(js);
    }
    concat_bias<<<S6_ / 256, 256, 0, stream>>>(lbq, lbk, lbv, gbq, gbk, gbv, bcatL, bcatG);

    // 1. local path: merged QKV projection, attention, out-proj
    gemm128<1, 128><<<dim3(S6_ / 128, BT_ / 128), 256, 0, stream>>>(xb, WcatL, bcatL, QKV, BT_, S6_, D_);
    local_attn<<<dim3(T_ / 64, B_ * H_), 256, 0, stream>>>(QKV, Ob);
    gemm128<0, 64><<<dim3(D_ / 64, BT_ / 128), 256, 0, stream>>>(Ob, wo_t, lbo, attnA, BT_, D_, HK_);

    // 2. global path
    gemm128<1, 128><<<dim3(S6_ / 128, BT_ / 128), 256, 0, stream>>>(xb, WcatG, bcatG, QKV, BT_, S6_, D_);
    g2_scores<<<dim3(B_ * H_, T_ / 256), 256, 0, stream>>>(QKV, sc);
    g2_softmax<<<B_ * H_, 256, 0, stream>>>(sc);
    g2_pv<<<dim3(B_ * H_, 4), 256, 0, stream>>>(sc, QKV, og_part);
    g2_red<<<128, 256, 0, stream>>>(og_part, og2);
    g2_lin<<<dim3(B_ * 2, 16), 256, 0, stream>>>(og2, gwo_t, gbo, g2buf);
    g2_kv<<<dim3(B_ * 2, HK_ / 256), 256, 0, stream>>>(g2buf, WcatG + (size_t)2048 * D_, gbk,
                                                       WcatG + (size_t)4096 * D_, gbv, K2, V2);
    gx_attn<<<BT_, 256, 0, stream>>>(QKV, K2, V2, Ob);
    gemm128<0, 64><<<dim3(D_ / 64, BT_ / 128), 256, 0, stream>>>(Ob, gwo_t, gbo, attnB, BT_, D_, HK_);

    // 3. LN1 + FFN + LN2
    ln_kernel<<<BT_, 256, 0, stream>>>(x, attnA, attnB, ln1g, ln1b, out1, out1b);
    gemm128<2, 128><<<dim3(FF_ / 128, BT_ / 128), 256, 0, stream>>>(out1b, fw1_t, fb1, hid, BT_, FF_, D_);
    gemm128<0, 64><<<dim3(D_ / 64, BT_ / 128), 256, 0, stream>>>(hid, fw2_t, fb2, ffn, BT_, D_, FF_);
    ln_kernel<<<BT_, 256, 0, stream>>>(out1, ffn, nullptr, ln2g, ln2b, (float*)d_out, nullptr);
}

// Round 6
// 335.107 us; speedup vs baseline: 2.0990x; 1.0360x over previous
//
#include <hip/hip_runtime.h>
#include <hip/hip_bf16.h>

#define B_ 8
#define T_ 1024
#define D_ 256
#define H_ 8
#define KD_ 256
#define HK_ 2048
#define FF_ 1024
#define WIN_ 64
#define BT_ 8192
#define S6_ 6144

using bf16 = __hip_bfloat16;
typedef float f32x4 __attribute__((ext_vector_type(4)));
typedef short s16x8 __attribute__((ext_vector_type(8)));

__device__ inline float b2f(bf16 h) { return __bfloat162float(h); }
__device__ inline float bs2f(short s) {
    unsigned int u = ((unsigned int)(unsigned short)s) << 16;
    return __builtin_bit_cast(float, u);
}
__device__ inline float us2f(unsigned short s) {
    unsigned int u = ((unsigned int)s) << 16;
    return __builtin_bit_cast(float, u);
}
__device__ inline unsigned short fbits(float x) { bf16 h = __float2bfloat16(x); return __builtin_bit_cast(unsigned short, h); }

// async global->LDS, 16B per lane; lds base wave-uniform, lane l lands at base + l*16
__device__ __forceinline__ void stage16(const void* g, void* l) {
    __builtin_amdgcn_global_load_lds((const __attribute__((address_space(1))) void*)g,
                                     (__attribute__((address_space(3))) void*)l, 16, 0, 0);
}

// ---------------- elementwise f32 -> bf16 ----------------
__global__ __launch_bounds__(256) void f32_to_bf16_vec(const float* __restrict__ in, bf16* __restrict__ out, int n) {
    int i = (blockIdx.x * 256 + threadIdx.x) * 4;
    if (i + 3 < n) {
        float4 v = *(const float4*)(in + i);
        ushort4 o;
        o.x = fbits(v.x); o.y = fbits(v.y); o.z = fbits(v.z); o.w = fbits(v.w);
        *(ushort4*)(out + i) = o;
    }
}

// ---------------- fused weight transposes: in f32[R][C] -> out bf16[C][R] ----------------
struct TJob { const float* in; bf16* out; int R; int C; int tile_start; };
struct TJobs { TJob j[10]; int total; };

__global__ void transpose_all(TJobs js) {
    __shared__ float tile[32][33];
    int bid = blockIdx.x;
    int ji = 0;
    while (ji < 9 && bid >= js.j[ji + 1].tile_start) ji++;
    TJob jb = js.j[ji];
    int t = bid - jb.tile_start;
    int tiles_x = jb.C / 32;
    int cb = (t % tiles_x) * 32, rb = (t / tiles_x) * 32;
    for (int k = 0; k < 4; k++) {
        int r = threadIdx.y + k * 8;
        tile[r][threadIdx.x] = jb.in[(size_t)(rb + r) * jb.C + cb + threadIdx.x];
    }
    __syncthreads();
    for (int k = 0; k < 4; k++) {
        int r = threadIdx.y + k * 8;
        jb.out[(size_t)(cb + r) * jb.R + rb + threadIdx.x] = __float2bfloat16(tile[threadIdx.x][r]);
    }
}

// concat 3 biases (2048 each) into 6144, both local and global sets
__global__ __launch_bounds__(256) void concat_bias(const float* a0, const float* a1, const float* a2,
                                                   const float* b0, const float* b1, const float* b2,
                                                   float* outL, float* outG) {
    int i = blockIdx.x * 256 + threadIdx.x;
    int seg = i >> 11, off = i & 2047;
    const float* pl = seg == 0 ? a0 : seg == 1 ? a1 : a2;
    const float* pg = seg == 0 ? b0 : seg == 1 ? b1 : b2;
    outL[i] = pl[off];
    outG[i] = pg[off];
}

// ---------------- m97-structure GEMM: C[M][N] = A[M][K] * Bt[N][K]^T + bias ----------------
// 128xBN tile, BK=64, 4 waves, global_load_lds staging, LDS-staged vectorized epilogue.
// Output always bf16. MODE 1: plain; MODE 2: relu.
template <int MODE, int BN>
__global__ __launch_bounds__(256) void gemm128(const bf16* __restrict__ A, const bf16* __restrict__ Bt,
                                               const float* __restrict__ bias, bf16* __restrict__ C,
                                               int M, int N, int K) {
    constexpr int NF = BN / 32;
    constexpr int EC = BN + 8;                       // epilogue LDS row stride (elements)
    constexpr int STAGE_B = 128 * 64 * 2 + BN * 64 * 2;
    constexpr int EPI_B = 128 * EC * 2;
    constexpr int ARENA = STAGE_B > EPI_B ? STAGE_B : EPI_B;
    __shared__ __align__(16) char arena[ARENA];
    bf16* As = (bf16*)arena;
    bf16* Bs = (bf16*)(arena + 128 * 64 * 2);
    const int tid = threadIdx.x;
    const int w = tid >> 6, l = tid & 63;
    const int m0 = blockIdx.y * 128, n0 = blockIdx.x * BN;
    const int wm = (w >> 1) * 64, wn = (w & 1) * (BN / 2);
    const int srow = w * 8 + (l >> 3);
    const int scol = (l & 7) * 8;
    const int ldsOff = w * 512;
    f32x4 acc[4][NF] = {};
    for (int k0 = 0; k0 < K; k0 += 64) {
#pragma unroll
        for (int j = 0; j < 4; j++)
            stage16(A + (size_t)(m0 + j * 32 + srow) * K + k0 + scol, &As[ldsOff + j * 2048]);
#pragma unroll
        for (int j = 0; j < BN / 32; j++)
            stage16(Bt + (size_t)(n0 + j * 32 + srow) * K + k0 + scol, &Bs[ldsOff + j * 2048]);
        __syncthreads();
#pragma unroll
        for (int ks = 0; ks < 2; ks++) {
            s16x8 a[4], b[NF];
#pragma unroll
            for (int mf = 0; mf < 4; mf++) a[mf] = *(const s16x8*)&As[(wm + mf * 16 + (l & 15)) * 64 + ks * 32 + (l >> 4) * 8];
#pragma unroll
            for (int nf = 0; nf < NF; nf++) b[nf] = *(const s16x8*)&Bs[(wn + nf * 16 + (l & 15)) * 64 + ks * 32 + (l >> 4) * 8];
            __builtin_amdgcn_s_setprio(1);
#pragma unroll
            for (int mf = 0; mf < 4; mf++)
#pragma unroll
                for (int nf = 0; nf < NF; nf++)
                    acc[mf][nf] = __builtin_amdgcn_mfma_f32_16x16x32_bf16(a[mf], b[nf], acc[mf][nf], 0, 0, 0);
            __builtin_amdgcn_s_setprio(0);
        }
        __syncthreads();
    }
    // ---- epilogue: bias(+relu), cvt bf16, stage tile in LDS, coalesced 16B stores ----
    bf16* Es = (bf16*)arena;
#pragma unroll
    for (int mf = 0; mf < 4; mf++)
#pragma unroll
        for (int nf = 0; nf < NF; nf++)
#pragma unroll
            for (int r = 0; r < 4; r++) {
                int row = wm + mf * 16 + (l >> 4) * 4 + r;
                int col = wn + nf * 16 + (l & 15);
                float v = acc[mf][nf][r] + bias[n0 + col];
                if (MODE == 2) v = fmaxf(v, 0.f);
                Es[row * EC + col] = __float2bfloat16(v);
            }
    __syncthreads();
    constexpr int RPC = BN / 8;                   // 16B chunks per row
    constexpr int CPT = (128 * BN) / (256 * 8);   // chunks per thread
#pragma unroll
    for (int c = 0; c < CPT; c++) {
        int lin = c * 256 + tid;
        int row = lin / RPC, cc = lin - row * RPC;
        s16x8 v = *(const s16x8*)&Es[row * EC + cc * 8];
        *(s16x8*)(C + (size_t)(m0 + row) * N + n0 + cc * 8) = v;
    }
}

// ---------------- local windowed attention v3 (proven round-5 version) ----------------
// QKV: [B*T][6144] (lQ | lK | lV). O: [B*T][2048]. grid (T/64, B*H), 256 threads.
__global__ __launch_bounds__(256) void local_attn(const bf16* __restrict__ QKV, bf16* __restrict__ O) {
    __shared__ bf16 U[256 * 72];     // phase1: Ks[64][264]; phase2: VT[256][72]
    __shared__ bf16 Ps[64][136];     // bf16 probabilities
    const int tid = threadIdx.x, l = tid & 63, w = tid >> 6;
    const int qt = blockIdx.x, bh = blockIdx.y;
    const int b = bh >> 3, h = bh & 7;
    const int qs = qt * 64;
    const int r0 = w * 16;
    const int lrow = tid >> 2, lc4 = (tid & 3) * 8;
    const size_t obase = (size_t)b * T_ * HK_ + h * KD_;

    s16x8 qa[8];
    {
        const bf16* qbase = QKV + (size_t)(b * T_ + qs + r0 + (l & 15)) * S6_ + h * KD_ + (l >> 4) * 8;
#pragma unroll
        for (int ks = 0; ks < 8; ks++) qa[ks] = *(const s16x8*)(qbase + ks * 32);
    }

    bf16(*Ks)[264] = (bf16(*)[264])U;
    {
        int tk = qs - 64 + lrow;
        const bf16* krow = QKV + (size_t)(b * T_ + tk) * S6_ + 2048 + h * KD_;
#pragma unroll
        for (int c = 0; c < 8; c++) {
            int col = lc4 + c * 32;
            uint4 val = {0, 0, 0, 0};
            if (tk >= 0) val = *(const uint4*)(krow + col);
            *(uint4*)&Ks[lrow][col] = val;
        }
    }
    __syncthreads();
    f32x4 sacc[8];
#pragma unroll
    for (int f = 0; f < 8; f++) sacc[f] = (f32x4){0.f, 0.f, 0.f, 0.f};
    __builtin_amdgcn_s_setprio(1);
#pragma unroll
    for (int nf = 0; nf < 4; nf++)
#pragma unroll
        for (int ks = 0; ks < 8; ks++) {
            s16x8 bb = *(const s16x8*)&Ks[nf * 16 + (l & 15)][ks * 32 + (l >> 4) * 8];
            sacc[nf] = __builtin_amdgcn_mfma_f32_16x16x32_bf16(qa[ks], bb, sacc[nf], 0, 0, 0);
        }
    __builtin_amdgcn_s_setprio(0);
    __syncthreads();
    {
        const bf16* krow = QKV + (size_t)(b * T_ + qs + lrow) * S6_ + 2048 + h * KD_;
#pragma unroll
        for (int c = 0; c < 8; c++) {
            int col = lc4 + c * 32;
            *(uint4*)&Ks[lrow][col] = *(const uint4*)(krow + col);
        }
    }
    __syncthreads();
    __builtin_amdgcn_s_setprio(1);
#pragma unroll
    for (int nf = 0; nf < 4; nf++)
#pragma unroll
        for (int ks = 0; ks < 8; ks++) {
            s16x8 bb = *(const s16x8*)&Ks[nf * 16 + (l & 15)][ks * 32 + (l >> 4) * 8];
            sacc[4 + nf] = __builtin_amdgcn_mfma_f32_16x16x32_bf16(qa[ks], bb, sacc[4 + nf], 0, 0, 0);
        }
    __builtin_amdgcn_s_setprio(0);

    uint4 vreg[8];
    {
        int tk = qs - 64 + lrow;
        const bf16* vrow = QKV + (size_t)(b * T_ + tk) * S6_ + 4096 + h * KD_;
#pragma unroll
        for (int c = 0; c < 8; c++) {
            uint4 v = {0, 0, 0, 0};
            if (tk >= 0) v = *(const uint4*)(vrow + lc4 + c * 32);
            vreg[c] = v;
        }
    }

#pragma unroll
    for (int r = 0; r < 4; r++) {
        int i = qs + r0 + (l >> 4) * 4 + r;
#pragma unroll
        for (int f = 0; f < 8; f++) {
            int j = qs - 64 + f * 16 + (l & 15);
            bool valid = (j >= 0) && (j <= i) && (j > i - WIN_);
            sacc[f][r] = valid ? sacc[f][r] * (1.f / 16.f) : -1e9f;
        }
        float mm = -1e30f;
#pragma unroll
        for (int f = 0; f < 8; f++) mm = fmaxf(mm, sacc[f][r]);
        mm = fmaxf(mm, __shfl_xor(mm, 1, 64));
        mm = fmaxf(mm, __shfl_xor(mm, 2, 64));
        mm = fmaxf(mm, __shfl_xor(mm, 4, 64));
        mm = fmaxf(mm, __shfl_xor(mm, 8, 64));
        float ss = 0.f;
#pragma unroll
        for (int f = 0; f < 8; f++) {
            float e = __expf(sacc[f][r] - mm);
            sacc[f][r] = e;
            ss += e;
        }
        ss += __shfl_xor(ss, 1, 64);
        ss += __shfl_xor(ss, 2, 64);
        ss += __shfl_xor(ss, 4, 64);
        ss += __shfl_xor(ss, 8, 64);
        float inv = 1.f / ss;
#pragma unroll
        for (int f = 0; f < 8; f++) sacc[f][r] *= inv;
    }
    __syncthreads();

    bf16(*VT)[72] = (bf16(*)[72])U;
#pragma unroll
    for (int f = 0; f < 8; f++)
#pragma unroll
        for (int r = 0; r < 4; r++)
            Ps[r0 + (l >> 4) * 4 + r][f * 16 + (l & 15)] = __float2bfloat16(sacc[f][r]);
#pragma unroll
    for (int c = 0; c < 8; c++) {
        int col = lc4 + c * 32;
        bf16 tmp[8];
        *(uint4*)tmp = vreg[c];
        for (int e = 0; e < 8; e++) VT[col + e][lrow] = tmp[e];
    }
    __syncthreads();
    {
        const bf16* vrow = QKV + (size_t)(b * T_ + qs + lrow) * S6_ + 4096 + h * KD_;
#pragma unroll
        for (int c = 0; c < 8; c++) vreg[c] = *(const uint4*)(vrow + lc4 + c * 32);
    }

    f32x4 oacc[16];
#pragma unroll
    for (int nf = 0; nf < 16; nf++) oacc[nf] = (f32x4){0.f, 0.f, 0.f, 0.f};
    for (int kb = 0; kb < 2; kb++) {
#pragma unroll
        for (int ks = 0; ks < 2; ks++) {
            s16x8 a = *(const s16x8*)&Ps[r0 + (l & 15)][kb * 64 + ks * 32 + (l >> 4) * 8];
            __builtin_amdgcn_s_setprio(1);
#pragma unroll
            for (int nf = 0; nf < 16; nf++) {
                s16x8 bb = *(const s16x8*)&VT[nf * 16 + (l & 15)][ks * 32 + (l >> 4) * 8];
                oacc[nf] = __builtin_amdgcn_mfma_f32_16x16x32_bf16(a, bb, oacc[nf], 0, 0, 0);
            }
            __builtin_amdgcn_s_setprio(0);
        }
        if (kb == 0) {
            __syncthreads();
#pragma unroll
            for (int c = 0; c < 8; c++) {
                int col = lc4 + c * 32;
                bf16 tmp[8];
                *(uint4*)tmp = vreg[c];
                for (int e = 0; e < 8; e++) VT[col + e][lrow] = tmp[e];
            }
            __syncthreads();
        }
    }
#pragma unroll
    for (int nf = 0; nf < 16; nf++)
#pragma unroll
        for (int r = 0; r < 4; r++) {
            int row = r0 + (l >> 4) * 4 + r;
            int col = nf * 16 + (l & 15);
            O[obase + (size_t)(qs + row) * HK_ + col] = __float2bfloat16(oacc[nf][r]);
        }
}

// ---------------- global path (split, parallel) ----------------
__global__ __launch_bounds__(256) void g2_scores(const bf16* __restrict__ QKV, float* __restrict__ sc) {
    __shared__ float qf[2][256];
    int bh = blockIdx.x, ch = blockIdx.y;
    int b = bh >> 3, h = bh & 7;
    int tid = threadIdx.x;
    for (int i = 0; i < 2; i++)
        qf[i][tid] = b2f(QKV[((size_t)b * T_ + (T_ - 2 + i)) * S6_ + h * KD_ + tid]);
    __syncthreads();
    int t = ch * 256 + tid;
    const bf16* kr = &QKV[((size_t)(b * T_ + t)) * S6_ + 2048 + h * KD_];
    float a0 = 0.f, a1 = 0.f;
    for (int c = 0; c < 32; c++) {
        s16x8 kv = *(const s16x8*)&kr[c * 8];
#pragma unroll
        for (int e = 0; e < 8; e++) {
            float kf = bs2f(kv[e]);
            a0 += kf * qf[0][c * 8 + e];
            a1 += kf * qf[1][c * 8 + e];
        }
    }
    sc[((size_t)bh * 2 + 0) * T_ + t] = a0 * (1.f / 16.f);
    sc[((size_t)bh * 2 + 1) * T_ + t] = a1 * (1.f / 16.f);
}

__global__ __launch_bounds__(256) void g2_softmax(float* __restrict__ sc) {
    __shared__ float red[4];
    int bh = blockIdx.x, tid = threadIdx.x;
    int w = tid >> 6;
    for (int i = 0; i < 2; i++) {
        float* row = &sc[((size_t)bh * 2 + i) * T_];
        float vals[4];
        float m = -1e30f;
        for (int c = 0; c < 4; c++) {
            vals[c] = row[tid + 256 * c];
            m = fmaxf(m, vals[c]);
        }
        for (int s = 32; s >= 1; s >>= 1) m = fmaxf(m, __shfl_xor(m, s, 64));
        if ((tid & 63) == 0) red[w] = m;
        __syncthreads();
        m = fmaxf(fmaxf(red[0], red[1]), fmaxf(red[2], red[3]));
        __syncthreads();
        float s = 0.f;
        for (int c = 0; c < 4; c++) {
            vals[c] = __expf(vals[c] - m);
            s += vals[c];
        }
        for (int d = 32; d >= 1; d >>= 1) s += __shfl_xor(s, d, 64);
        if ((tid & 63) == 0) red[w] = s;
        __syncthreads();
        s = red[0] + red[1] + red[2] + red[3];
        float inv = 1.f / s;
        for (int c = 0; c < 4; c++) row[tid + 256 * c] = vals[c] * inv;
        __syncthreads();
    }
}

__global__ __launch_bounds__(256) void g2_pv(const float* __restrict__ sc, const bf16* __restrict__ QKV,
                                             float* __restrict__ og_part) {
    __shared__ float p2[2][256];
    int bh = blockIdx.x, ch = blockIdx.y;
    int b = bh >> 3, h = bh & 7;
    int tid = threadIdx.x;
    for (int i = 0; i < 2; i++) p2[i][tid] = sc[((size_t)bh * 2 + i) * T_ + ch * 256 + tid];
    __syncthreads();
    const bf16* vb = &QKV[((size_t)(b * T_ + ch * 256)) * S6_ + 4096 + h * KD_ + tid];
    float a0 = 0.f, a1 = 0.f;
    for (int t = 0; t < 256; t++) {
        float vv = b2f(vb[(size_t)t * S6_]);
        a0 += p2[0][t] * vv;
        a1 += p2[1][t] * vv;
    }
    og_part[((size_t)(bh * 4 + ch) * 2 + 0) * KD_ + tid] = a0;
    og_part[((size_t)(bh * 4 + ch) * 2 + 1) * KD_ + tid] = a1;
}

// reduce og_part chunks -> og2[(b*2+i)*2048 + h*256+kd]. grid 128.
__global__ __launch_bounds__(256) void g2_red(const float* __restrict__ og_part, float* __restrict__ og2) {
    int idx = blockIdx.x * 256 + threadIdx.x;
    int kd = idx & 255, i = (idx >> 8) & 1, h = (idx >> 9) & 7, b = idx >> 12;
    int bh = b * 8 + h;
    float s = 0.f;
    for (int ch = 0; ch < 4; ch++) s += og_part[((size_t)(bh * 4 + ch) * 2 + i) * KD_ + kd];
    og2[(size_t)(b * 2 + i) * 2048 + h * 256 + kd] = s;
}

// g2buf[bi][d] = og2[bi][:] . gwo_t[d][:] + gbo[d]. grid (16,16), 16 lanes/output.
__global__ __launch_bounds__(256) void g2_lin(const float* __restrict__ og2, const bf16* __restrict__ gwo_t,
                                              const float* __restrict__ gbo, float* __restrict__ g2buf) {
    int bi = blockIdx.x, tid = threadIdx.x;
    int d = blockIdx.y * 16 + (tid >> 4);
    int s16i = tid & 15;
    const float* ogr = og2 + (size_t)bi * 2048 + s16i * 128;
    const bf16* wr = gwo_t + (size_t)d * HK_ + s16i * 128;
    float acc = 0.f;
    for (int c = 0; c < 16; c++) {
        s16x8 wv = *(const s16x8*)&wr[c * 8];
#pragma unroll
        for (int e = 0; e < 8; e++) acc += ogr[c * 8 + e] * bs2f(wv[e]);
    }
    acc += __shfl_xor(acc, 1, 64);
    acc += __shfl_xor(acc, 2, 64);
    acc += __shfl_xor(acc, 4, 64);
    acc += __shfl_xor(acc, 8, 64);
    if (s16i == 0) g2buf[(size_t)bi * 256 + d] = acc + gbo[d];
}

__global__ __launch_bounds__(256) void g2_kv(const float* __restrict__ g2buf, const bf16* __restrict__ gwk_t,
                                             const float* __restrict__ gbk, const bf16* __restrict__ gwv_t,
                                             const float* __restrict__ gbv, bf16* __restrict__ K2,
                                             bf16* __restrict__ V2) {
    __shared__ float g2s[256];
    int bi = blockIdx.x, ch = blockIdx.y;
    int tid = threadIdx.x;
    g2s[tid] = g2buf[(size_t)bi * 256 + tid];
    __syncthreads();
    int hk = ch * 256 + tid;
    const bf16* rk = &gwk_t[(size_t)hk * D_];
    const bf16* rv = &gwv_t[(size_t)hk * D_];
    float ak = gbk[hk], av = gbv[hk];
    for (int c = 0; c < 32; c++) {
        s16x8 kw = *(const s16x8*)&rk[c * 8];
        s16x8 vw = *(const s16x8*)&rv[c * 8];
#pragma unroll
        for (int e = 0; e < 8; e++) {
            float g = g2s[c * 8 + e];
            ak += g * bs2f(kw[e]);
            av += g * bs2f(vw[e]);
        }
    }
    K2[(size_t)bi * HK_ + hk] = __float2bfloat16(ak);
    V2[(size_t)bi * HK_ + hk] = __float2bfloat16(av);
}

// gx attention: softmax over 2 keys, fully vectorized 16B loads. grid BT.
__global__ __launch_bounds__(256) void gx_attn(const bf16* __restrict__ QKV, const bf16* __restrict__ K2,
                                               const bf16* __restrict__ V2, bf16* __restrict__ O) {
    int bt = blockIdx.x;
    int b = bt >> 10;
    int tid = threadIdx.x;
    int h = tid >> 5, ln = tid & 31;
    size_t qoff = (size_t)bt * S6_ + h * KD_ + ln * 8;
    size_t koff = (size_t)(b * 2) * HK_ + h * KD_ + ln * 8;
    s16x8 q = *(const s16x8*)(QKV + qoff);
    s16x8 k0 = *(const s16x8*)(K2 + koff);
    s16x8 k1 = *(const s16x8*)(K2 + koff + HK_);
    s16x8 v0 = *(const s16x8*)(V2 + koff);
    s16x8 v1 = *(const s16x8*)(V2 + koff + HK_);
    float s0 = 0.f, s1 = 0.f;
#pragma unroll
    for (int e = 0; e < 8; e++) {
        float qf = bs2f(q[e]);
        s0 += qf * bs2f(k0[e]);
        s1 += qf * bs2f(k1[e]);
    }
#pragma unroll
    for (int m = 16; m >= 1; m >>= 1) {
        s0 += __shfl_xor(s0, m, 64);
        s1 += __shfl_xor(s1, m, 64);
    }
    s0 *= (1.f / 16.f);
    s1 *= (1.f / 16.f);
    float mx = fmaxf(s0, s1);
    float e0 = __expf(s0 - mx), e1 = __expf(s1 - mx);
    float inv = 1.f / (e0 + e1);
    float p0 = e0 * inv, p1 = e1 * inv;
    s16x8 o;
#pragma unroll
    for (int e = 0; e < 8; e++) {
        float v = p0 * bs2f(v0[e]) + p1 * bs2f(v1[e]);
        o[e] = __builtin_bit_cast(short, __float2bfloat16(v));
    }
    *(s16x8*)(O + (size_t)bt * HK_ + h * KD_ + ln * 8) = o;
}

// ---------------- LayerNorm over D=256: wave per row, no LDS ----------------
// v = a(f32) + b2(bf16) [+ c(bf16)]; out = LN(v)*g + bia. grid BT/4.
__global__ __launch_bounds__(256) void ln_kernel(const float* __restrict__ a, const bf16* __restrict__ b2,
                                                 const bf16* __restrict__ c, const float* __restrict__ g,
                                                 const float* __restrict__ bia, float* __restrict__ outf,
                                                 bf16* __restrict__ outb) {
    int w = threadIdx.x >> 6, l = threadIdx.x & 63;
    int row = blockIdx.x * 4 + w;
    size_t base = (size_t)row * D_ + l * 4;
    float4 av = *(const float4*)(a + base);
    ushort4 bv = *(const ushort4*)(b2 + base);
    float vv[4];
    vv[0] = av.x + us2f(bv.x); vv[1] = av.y + us2f(bv.y);
    vv[2] = av.z + us2f(bv.z); vv[3] = av.w + us2f(bv.w);
    if (c) {
        ushort4 cv = *(const ushort4*)(c + base);
        vv[0] += us2f(cv.x); vv[1] += us2f(cv.y); vv[2] += us2f(cv.z); vv[3] += us2f(cv.w);
    }
    float s = vv[0] + vv[1] + vv[2] + vv[3];
#pragma unroll
    for (int m = 32; m >= 1; m >>= 1) s += __shfl_xor(s, m, 64);
    float mean = s * (1.f / 256.f);
    float q = 0.f;
#pragma unroll
    for (int e = 0; e < 4; e++) {
        float d = vv[e] - mean;
        q += d * d;
    }
#pragma unroll
    for (int m = 32; m >= 1; m >>= 1) q += __shfl_xor(q, m, 64);
    float rs = rsqrtf(q * (1.f / 256.f) + 1e-6f);
    float4 gv = *(const float4*)(g + l * 4);
    float4 biv = *(const float4*)(bia + l * 4);
    float o0 = (vv[0] - mean) * rs * gv.x + biv.x;
    float o1 = (vv[1] - mean) * rs * gv.y + biv.y;
    float o2 = (vv[2] - mean) * rs * gv.z + biv.z;
    float o3 = (vv[3] - mean) * rs * gv.w + biv.w;
    if (outf) *(float4*)(outf + base) = (float4){o0, o1, o2, o3};
    if (outb) {
        ushort4 ou;
        ou.x = fbits(o0); ou.y = fbits(o1); ou.z = fbits(o2); ou.w = fbits(o3);
        *(ushort4*)(outb + base) = ou;
    }
}

extern "C" void kernel_launch(void* const* d_in, const int* in_sizes, int n_in, void* d_out, int out_size,
                              void* d_ws, size_t ws_size, hipStream_t stream) {
    const float* x = (const float*)d_in[0];
    const float* lWq = (const float*)d_in[1];  const float* lbq = (const float*)d_in[2];
    const float* lWk = (const float*)d_in[3];  const float* lbk = (const float*)d_in[4];
    const float* lWv = (const float*)d_in[5];  const float* lbv = (const float*)d_in[6];
    const float* lWo = (const float*)d_in[7];  const float* lbo = (const float*)d_in[8];
    const float* gWq = (const float*)d_in[9];  const float* gbq = (const float*)d_in[10];
    const float* gWk = (const float*)d_in[11]; const float* gbk = (const float*)d_in[12];
    const float* gWv = (const float*)d_in[13]; const float* gbv = (const float*)d_in[14];
    const float* gWo = (const float*)d_in[15]; const float* gbo = (const float*)d_in[16];
    const float* fW1 = (const float*)d_in[17]; const float* fb1 = (const float*)d_in[18];
    const float* fW2 = (const float*)d_in[19]; const float* fb2 = (const float*)d_in[20];
    const float* ln1g = (const float*)d_in[21]; const float* ln1b = (const float*)d_in[22];
    const float* ln2g = (const float*)d_in[23]; const float* ln2b = (const float*)d_in[24];

    char* ws = (char*)d_ws;
    size_t off = 0;
    auto alloc = [&](size_t bytes) -> char* {
        char* p = ws + off;
        off = (off + bytes + 255) & ~(size_t)255;
        return p;
    };
    bf16* xb = (bf16*)alloc((size_t)BT_ * D_ * 2);
    bf16* WcatL = (bf16*)alloc((size_t)S6_ * D_ * 2);
    bf16* WcatG = (bf16*)alloc((size_t)S6_ * D_ * 2);
    bf16* wo_t = (bf16*)alloc((size_t)D_ * HK_ * 2);
    bf16* gwo_t = (bf16*)alloc((size_t)D_ * HK_ * 2);
    bf16* fw1_t = (bf16*)alloc((size_t)FF_ * D_ * 2);
    bf16* fw2_t = (bf16*)alloc((size_t)D_ * FF_ * 2);
    float* bcatL = (float*)alloc((size_t)S6_ * 4);
    float* bcatG = (float*)alloc((size_t)S6_ * 4);
    bf16* QKV = (bf16*)alloc((size_t)BT_ * S6_ * 2);    // 96 MB, reused local->global
    bf16* Ob = (bf16*)alloc((size_t)BT_ * HK_ * 2);     // 32 MB
    bf16* attnA = (bf16*)alloc((size_t)BT_ * D_ * 2);
    bf16* attnB = (bf16*)alloc((size_t)BT_ * D_ * 2);
    float* out1 = (float*)alloc((size_t)BT_ * D_ * 4);
    float* sc = (float*)alloc((size_t)B_ * H_ * 2 * T_ * 4);
    float* og_part = (float*)alloc((size_t)B_ * H_ * 4 * 2 * KD_ * 4);
    float* og2 = (float*)alloc((size_t)B_ * 2 * HK_ * 4);
    float* g2buf = (float*)alloc((size_t)B_ * 2 * D_ * 4);
    bf16* K2 = (bf16*)alloc((size_t)B_ * 2 * HK_ * 2);
    bf16* V2 = (bf16*)alloc((size_t)B_ * 2 * HK_ * 2);
    // aliases into QKV (projection data dead after gx_attn + attnB gemm):
    bf16* hid = QKV;                                    // [8192][1024] bf16, 16 MB @ 0
    bf16* ffn = (bf16*)((char*)QKV + (32u << 20));      // 4 MB @ 32M
    bf16* out1b = (bf16*)((char*)QKV + (48u << 20));    // 4 MB @ 48M

    // 0. convert + fused transposes + bias concat
    f32_to_bf16_vec<<<(BT_ * D_) / 1024, 256, 0, stream>>>(x, xb, BT_ * D_);
    {
        TJobs js;
        int t = 0;
        auto add = [&](int i, const float* in, bf16* out, int R, int C) {
            js.j[i] = {in, out, R, C, t};
            t += (R / 32) * (C / 32);
        };
        add(0, lWq, WcatL, D_, HK_);
        add(1, lWk, WcatL + (size_t)2048 * D_, D_, HK_);
        add(2, lWv, WcatL + (size_t)4096 * D_, D_, HK_);
        add(3, lWo, wo_t, HK_, D_);
        add(4, gWq, WcatG, D_, HK_);
        add(5, gWk, WcatG + (size_t)2048 * D_, D_, HK_);
        add(6, gWv, WcatG + (size_t)4096 * D_, D_, HK_);
        add(7, gWo, gwo_t, HK_, D_);
        add(8, fW1, fw1_t, D_, FF_);
        add(9, fW2, fw2_t, FF_, D_);
        js.total = t;
        transpose_all<<<t, dim3(32, 8), 0, stream>>>(js);
    }
    concat_bias<<<S6_ / 256, 256, 0, stream>>>(lbq, lbk, lbv, gbq, gbk, gbv, bcatL, bcatG);

    // 1. local path: merged QKV projection, attention, out-proj
    gemm128<1, 128><<<dim3(S6_ / 128, BT_ / 128), 256, 0, stream>>>(xb, WcatL, bcatL, QKV, BT_, S6_, D_);
    local_attn<<<dim3(T_ / 64, B_ * H_), 256, 0, stream>>>(QKV, Ob);
    gemm128<1, 64><<<dim3(D_ / 64, BT_ / 128), 256, 0, stream>>>(Ob, wo_t, lbo, attnA, BT_, D_, HK_);

    // 2. global path
    gemm128<1, 128><<<dim3(S6_ / 128, BT_ / 128), 256, 0, stream>>>(xb, WcatG, bcatG, QKV, BT_, S6_, D_);
    g2_scores<<<dim3(B_ * H_, T_ / 256), 256, 0, stream>>>(QKV, sc);
    g2_softmax<<<B_ * H_, 256, 0, stream>>>(sc);
    g2_pv<<<dim3(B_ * H_, 4), 256, 0, stream>>>(sc, QKV, og_part);
    g2_red<<<128, 256, 0, stream>>>(og_part, og2);
    g2_lin<<<dim3(B_ * 2, 16), 256, 0, stream>>>(og2, gwo_t, gbo, g2buf);
    g2_kv<<<dim3(B_ * 2, HK_ / 256), 256, 0, stream>>>(g2buf, WcatG + (size_t)2048 * D_, gbk,
                                                       WcatG + (size_t)4096 * D_, gbv, K2, V2);
    gx_attn<<<BT_, 256, 0, stream>>>(QKV, K2, V2, Ob);
    gemm128<1, 64><<<dim3(D_ / 64, BT_ / 128), 256, 0, stream>>>(Ob, gwo_t, gbo, attnB, BT_, D_, HK_);

    // 3. LN1 + FFN + LN2
    ln_kernel<<<BT_ / 4, 256, 0, stream>>>(x, attnA, attnB, ln1g, ln1b, out1, out1b);
    gemm128<2, 128><<<dim3(FF_ / 128, BT_ / 128), 256, 0, stream>>>(out1b, fw1_t, fb1, hid, BT_, FF_, D_);
    gemm128<1, 64><<<dim3(D_ / 64, BT_ / 128), 256, 0, stream>>>(hid, fw2_t, fb2, ffn, BT_, D_, FF_);
    ln_kernel<<<BT_ / 4, 256, 0, stream>>>(out1, ffn, nullptr, ln2g, ln2b, (float*)d_out, nullptr);
}

// Round 7
// 307.906 us; speedup vs baseline: 2.2844x; 1.0883x over previous
//
#include <hip/hip_runtime.h>
#include <hip/hip_bf16.h>

#define B_ 8
#define T_ 1024
#define D_ 256
#define H_ 8
#define KD_ 256
#define HK_ 2048
#define FF_ 1024
#define WIN_ 64
#define BT_ 8192
#define S6_ 6144
#define OS_ 4096   // Ob row stride: [local 0..2047 | gx 2048..4095]

using bf16 = __hip_bfloat16;
typedef float f32x4 __attribute__((ext_vector_type(4)));
typedef short s16x8 __attribute__((ext_vector_type(8)));

__device__ inline float b2f(bf16 h) { return __bfloat162float(h); }
__device__ inline float bs2f(short s) {
    unsigned int u = ((unsigned int)(unsigned short)s) << 16;
    return __builtin_bit_cast(float, u);
}
__device__ inline float us2f(unsigned short s) {
    unsigned int u = ((unsigned int)s) << 16;
    return __builtin_bit_cast(float, u);
}
__device__ inline unsigned short fbits(float x) { bf16 h = __float2bfloat16(x); return __builtin_bit_cast(unsigned short, h); }

// async global->LDS, 16B per lane; lds base wave-uniform, lane l lands at base + l*16
__device__ __forceinline__ void stage16(const void* g, void* l) {
    __builtin_amdgcn_global_load_lds((const __attribute__((address_space(1))) void*)g,
                                     (__attribute__((address_space(3))) void*)l, 16, 0, 0);
}

// ---------------- elementwise f32 -> bf16 ----------------
__global__ __launch_bounds__(256) void f32_to_bf16_vec(const float* __restrict__ in, bf16* __restrict__ out, int n) {
    int i = (blockIdx.x * 256 + threadIdx.x) * 4;
    if (i + 3 < n) {
        float4 v = *(const float4*)(in + i);
        ushort4 o;
        o.x = fbits(v.x); o.y = fbits(v.y); o.z = fbits(v.z); o.w = fbits(v.w);
        *(ushort4*)(out + i) = o;
    }
}

// ---------------- fused weight transposes: in f32[R][C] -> out bf16[C][R], row stride os ----------------
struct TJob { const float* in; bf16* out; int R; int C; int os; int tile_start; };
struct TJobs { TJob j[10]; int total; };

__global__ void transpose_all(TJobs js) {
    __shared__ float tile[32][33];
    int bid = blockIdx.x;
    int ji = 0;
    while (ji < 9 && bid >= js.j[ji + 1].tile_start) ji++;
    TJob jb = js.j[ji];
    int t = bid - jb.tile_start;
    int tiles_x = jb.C / 32;
    int cb = (t % tiles_x) * 32, rb = (t / tiles_x) * 32;
    for (int k = 0; k < 4; k++) {
        int r = threadIdx.y + k * 8;
        tile[r][threadIdx.x] = jb.in[(size_t)(rb + r) * jb.C + cb + threadIdx.x];
    }
    __syncthreads();
    for (int k = 0; k < 4; k++) {
        int r = threadIdx.y + k * 8;
        jb.out[(size_t)(cb + r) * jb.os + rb + threadIdx.x] = __float2bfloat16(tile[threadIdx.x][r]);
    }
}

// concat 3 biases (2048 each) into 6144 (local+global) and boC = lbo + gbo (256)
__global__ __launch_bounds__(256) void concat_bias(const float* a0, const float* a1, const float* a2,
                                                   const float* b0, const float* b1, const float* b2,
                                                   const float* lbo, const float* gbo,
                                                   float* outL, float* outG, float* outO) {
    int i = blockIdx.x * 256 + threadIdx.x;
    int seg = i >> 11, off = i & 2047;
    const float* pl = seg == 0 ? a0 : seg == 1 ? a1 : a2;
    const float* pg = seg == 0 ? b0 : seg == 1 ? b1 : b2;
    outL[i] = pl[off];
    outG[i] = pg[off];
    if (i < 256) outO[i] = lbo[i] + gbo[i];
}

// ---------------- dbuf 2-phase GEMM: C[M][N] = A[M][K] * Bt[N][K]^T + bias ----------------
// 128xBN tile, BK=64, 4 waves, double-buffered global_load_lds staging (stage next
// before compute current; one barrier per K-iter), LDS-staged vectorized bf16 epilogue.
// MODE 1: plain; MODE 2: relu.
template <int MODE, int BN>
__global__ __launch_bounds__(256) void gemm128(const bf16* __restrict__ A, const bf16* __restrict__ Bt,
                                               const float* __restrict__ bias, bf16* __restrict__ C,
                                               int M, int N, int K) {
    constexpr int NF = BN / 32;
    constexpr int ABUF = 128 * 64;        // elements per A buffer
    constexpr int BBUF = BN * 64;
    constexpr int BUFE = ABUF + BBUF;
    constexpr int EC = BN + 8;            // epilogue LDS row stride (elements)
    constexpr int ARENA_E = (2 * BUFE > 128 * EC) ? 2 * BUFE : 128 * EC;
    __shared__ __align__(16) bf16 arena[ARENA_E];
    const int tid = threadIdx.x;
    const int w = tid >> 6, l = tid & 63;
    const int m0 = blockIdx.y * 128, n0 = blockIdx.x * BN;
    const int wm = (w >> 1) * 64, wn = (w & 1) * (BN / 2);
    const int srow = w * 8 + (l >> 3);
    const int scol = (l & 7) * 8;
    const int ldsOff = w * 512;
    const int nt = K / 64;

    auto stageT = [&](int buf, int k0) {
        bf16* Ad = arena + buf * BUFE;
        bf16* Bd = Ad + ABUF;
#pragma unroll
        for (int j = 0; j < 4; j++)
            stage16(A + (size_t)(m0 + j * 32 + srow) * K + k0 + scol, &Ad[ldsOff + j * 2048]);
#pragma unroll
        for (int j = 0; j < NF; j++)
            stage16(Bt + (size_t)(n0 + j * 32 + srow) * K + k0 + scol, &Bd[ldsOff + j * 2048]);
    };

    f32x4 acc[4][NF] = {};
    stageT(0, 0);
    __syncthreads();
    int cur = 0;
    for (int t = 0; t < nt; t++) {
        if (t + 1 < nt) stageT(cur ^ 1, (t + 1) * 64);   // loads fly under MFMA below
        const bf16* As = arena + cur * BUFE;
        const bf16* Bs = As + ABUF;
#pragma unroll
        for (int ks = 0; ks < 2; ks++) {
            s16x8 a[4], b[NF];
#pragma unroll
            for (int mf = 0; mf < 4; mf++) a[mf] = *(const s16x8*)&As[(wm + mf * 16 + (l & 15)) * 64 + ks * 32 + (l >> 4) * 8];
#pragma unroll
            for (int nf = 0; nf < NF; nf++) b[nf] = *(const s16x8*)&Bs[(wn + nf * 16 + (l & 15)) * 64 + ks * 32 + (l >> 4) * 8];
            __builtin_amdgcn_s_setprio(1);
#pragma unroll
            for (int mf = 0; mf < 4; mf++)
#pragma unroll
                for (int nf = 0; nf < NF; nf++)
                    acc[mf][nf] = __builtin_amdgcn_mfma_f32_16x16x32_bf16(a[mf], b[nf], acc[mf][nf], 0, 0, 0);
            __builtin_amdgcn_s_setprio(0);
        }
        __syncthreads();   // implicit vmcnt(0): next buffer complete; all reads of cur done
        cur ^= 1;
    }
    // ---- epilogue: bias(+relu), cvt bf16, stage tile in LDS, coalesced 16B stores ----
    bf16* Es = arena;
#pragma unroll
    for (int mf = 0; mf < 4; mf++)
#pragma unroll
        for (int nf = 0; nf < NF; nf++)
#pragma unroll
            for (int r = 0; r < 4; r++) {
                int row = wm + mf * 16 + (l >> 4) * 4 + r;
                int col = wn + nf * 16 + (l & 15);
                float v = acc[mf][nf][r] + bias[n0 + col];
                if (MODE == 2) v = fmaxf(v, 0.f);
                Es[row * EC + col] = __float2bfloat16(v);
            }
    __syncthreads();
    constexpr int RPC = BN / 8;
    constexpr int CPT = (128 * BN) / (256 * 8);
#pragma unroll
    for (int c = 0; c < CPT; c++) {
        int lin = c * 256 + tid;
        int row = lin / RPC, cc = lin - row * RPC;
        s16x8 v = *(const s16x8*)&Es[row * EC + cc * 8];
        *(s16x8*)(C + (size_t)(m0 + row) * N + n0 + cc * 8) = v;
    }
}

// ---------------- local windowed attention v3 (proven) ----------------
// QKV: [B*T][6144] (lQ | lK | lV). O: [B*T][OS_] cols 0..2047. grid (T/64, B*H).
__global__ __launch_bounds__(256) void local_attn(const bf16* __restrict__ QKV, bf16* __restrict__ O) {
    __shared__ bf16 U[256 * 72];     // phase1: Ks[64][264]; phase2: VT[256][72]
    __shared__ bf16 Ps[64][136];     // bf16 probabilities
    const int tid = threadIdx.x, l = tid & 63, w = tid >> 6;
    const int qt = blockIdx.x, bh = blockIdx.y;
    const int b = bh >> 3, h = bh & 7;
    const int qs = qt * 64;
    const int r0 = w * 16;
    const int lrow = tid >> 2, lc4 = (tid & 3) * 8;
    const size_t obase = (size_t)b * T_ * OS_ + h * KD_;

    s16x8 qa[8];
    {
        const bf16* qbase = QKV + (size_t)(b * T_ + qs + r0 + (l & 15)) * S6_ + h * KD_ + (l >> 4) * 8;
#pragma unroll
        for (int ks = 0; ks < 8; ks++) qa[ks] = *(const s16x8*)(qbase + ks * 32);
    }

    bf16(*Ks)[264] = (bf16(*)[264])U;
    {
        int tk = qs - 64 + lrow;
        const bf16* krow = QKV + (size_t)(b * T_ + tk) * S6_ + 2048 + h * KD_;
#pragma unroll
        for (int c = 0; c < 8; c++) {
            int col = lc4 + c * 32;
            uint4 val = {0, 0, 0, 0};
            if (tk >= 0) val = *(const uint4*)(krow + col);
            *(uint4*)&Ks[lrow][col] = val;
        }
    }
    __syncthreads();
    f32x4 sacc[8];
#pragma unroll
    for (int f = 0; f < 8; f++) sacc[f] = (f32x4){0.f, 0.f, 0.f, 0.f};
    __builtin_amdgcn_s_setprio(1);
#pragma unroll
    for (int nf = 0; nf < 4; nf++)
#pragma unroll
        for (int ks = 0; ks < 8; ks++) {
            s16x8 bb = *(const s16x8*)&Ks[nf * 16 + (l & 15)][ks * 32 + (l >> 4) * 8];
            sacc[nf] = __builtin_amdgcn_mfma_f32_16x16x32_bf16(qa[ks], bb, sacc[nf], 0, 0, 0);
        }
    __builtin_amdgcn_s_setprio(0);
    __syncthreads();
    {
        const bf16* krow = QKV + (size_t)(b * T_ + qs + lrow) * S6_ + 2048 + h * KD_;
#pragma unroll
        for (int c = 0; c < 8; c++) {
            int col = lc4 + c * 32;
            *(uint4*)&Ks[lrow][col] = *(const uint4*)(krow + col);
        }
    }
    __syncthreads();
    __builtin_amdgcn_s_setprio(1);
#pragma unroll
    for (int nf = 0; nf < 4; nf++)
#pragma unroll
        for (int ks = 0; ks < 8; ks++) {
            s16x8 bb = *(const s16x8*)&Ks[nf * 16 + (l & 15)][ks * 32 + (l >> 4) * 8];
            sacc[4 + nf] = __builtin_amdgcn_mfma_f32_16x16x32_bf16(qa[ks], bb, sacc[4 + nf], 0, 0, 0);
        }
    __builtin_amdgcn_s_setprio(0);

    uint4 vreg[8];
    {
        int tk = qs - 64 + lrow;
        const bf16* vrow = QKV + (size_t)(b * T_ + tk) * S6_ + 4096 + h * KD_;
#pragma unroll
        for (int c = 0; c < 8; c++) {
            uint4 v = {0, 0, 0, 0};
            if (tk >= 0) v = *(const uint4*)(vrow + lc4 + c * 32);
            vreg[c] = v;
        }
    }

#pragma unroll
    for (int r = 0; r < 4; r++) {
        int i = qs + r0 + (l >> 4) * 4 + r;
#pragma unroll
        for (int f = 0; f < 8; f++) {
            int j = qs - 64 + f * 16 + (l & 15);
            bool valid = (j >= 0) && (j <= i) && (j > i - WIN_);
            sacc[f][r] = valid ? sacc[f][r] * (1.f / 16.f) : -1e9f;
        }
        float mm = -1e30f;
#pragma unroll
        for (int f = 0; f < 8; f++) mm = fmaxf(mm, sacc[f][r]);
        mm = fmaxf(mm, __shfl_xor(mm, 1, 64));
        mm = fmaxf(mm, __shfl_xor(mm, 2, 64));
        mm = fmaxf(mm, __shfl_xor(mm, 4, 64));
        mm = fmaxf(mm, __shfl_xor(mm, 8, 64));
        float ss = 0.f;
#pragma unroll
        for (int f = 0; f < 8; f++) {
            float e = __expf(sacc[f][r] - mm);
            sacc[f][r] = e;
            ss += e;
        }
        ss += __shfl_xor(ss, 1, 64);
        ss += __shfl_xor(ss, 2, 64);
        ss += __shfl_xor(ss, 4, 64);
        ss += __shfl_xor(ss, 8, 64);
        float inv = 1.f / ss;
#pragma unroll
        for (int f = 0; f < 8; f++) sacc[f][r] *= inv;
    }
    __syncthreads();

    bf16(*VT)[72] = (bf16(*)[72])U;
#pragma unroll
    for (int f = 0; f < 8; f++)
#pragma unroll
        for (int r = 0; r < 4; r++)
            Ps[r0 + (l >> 4) * 4 + r][f * 16 + (l & 15)] = __float2bfloat16(sacc[f][r]);
#pragma unroll
    for (int c = 0; c < 8; c++) {
        int col = lc4 + c * 32;
        bf16 tmp[8];
        *(uint4*)tmp = vreg[c];
        for (int e = 0; e < 8; e++) VT[col + e][lrow] = tmp[e];
    }
    __syncthreads();
    {
        const bf16* vrow = QKV + (size_t)(b * T_ + qs + lrow) * S6_ + 4096 + h * KD_;
#pragma unroll
        for (int c = 0; c < 8; c++) vreg[c] = *(const uint4*)(vrow + lc4 + c * 32);
    }

    f32x4 oacc[16];
#pragma unroll
    for (int nf = 0; nf < 16; nf++) oacc[nf] = (f32x4){0.f, 0.f, 0.f, 0.f};
    for (int kb = 0; kb < 2; kb++) {
#pragma unroll
        for (int ks = 0; ks < 2; ks++) {
            s16x8 a = *(const s16x8*)&Ps[r0 + (l & 15)][kb * 64 + ks * 32 + (l >> 4) * 8];
            __builtin_amdgcn_s_setprio(1);
#pragma unroll
            for (int nf = 0; nf < 16; nf++) {
                s16x8 bb = *(const s16x8*)&VT[nf * 16 + (l & 15)][ks * 32 + (l >> 4) * 8];
                oacc[nf] = __builtin_amdgcn_mfma_f32_16x16x32_bf16(a, bb, oacc[nf], 0, 0, 0);
            }
            __builtin_amdgcn_s_setprio(0);
        }
        if (kb == 0) {
            __syncthreads();
#pragma unroll
            for (int c = 0; c < 8; c++) {
                int col = lc4 + c * 32;
                bf16 tmp[8];
                *(uint4*)tmp = vreg[c];
                for (int e = 0; e < 8; e++) VT[col + e][lrow] = tmp[e];
            }
            __syncthreads();
        }
    }
#pragma unroll
    for (int nf = 0; nf < 16; nf++)
#pragma unroll
        for (int r = 0; r < 4; r++) {
            int row = r0 + (l >> 4) * 4 + r;
            int col = nf * 16 + (l & 15);
            O[obase + (size_t)(qs + row) * OS_ + col] = __float2bfloat16(oacc[nf][r]);
        }
}

// ---------------- global path (split, parallel) ----------------
__global__ __launch_bounds__(256) void g2_scores(const bf16* __restrict__ QKV, float* __restrict__ sc) {
    __shared__ float qf[2][256];
    int bh = blockIdx.x, ch = blockIdx.y;
    int b = bh >> 3, h = bh & 7;
    int tid = threadIdx.x;
    for (int i = 0; i < 2; i++)
        qf[i][tid] = b2f(QKV[((size_t)b * T_ + (T_ - 2 + i)) * S6_ + h * KD_ + tid]);
    __syncthreads();
    int t = ch * 256 + tid;
    const bf16* kr = &QKV[((size_t)(b * T_ + t)) * S6_ + 2048 + h * KD_];
    float a0 = 0.f, a1 = 0.f;
    for (int c = 0; c < 32; c++) {
        s16x8 kv = *(const s16x8*)&kr[c * 8];
#pragma unroll
        for (int e = 0; e < 8; e++) {
            float kf = bs2f(kv[e]);
            a0 += kf * qf[0][c * 8 + e];
            a1 += kf * qf[1][c * 8 + e];
        }
    }
    sc[((size_t)bh * 2 + 0) * T_ + t] = a0 * (1.f / 16.f);
    sc[((size_t)bh * 2 + 1) * T_ + t] = a1 * (1.f / 16.f);
}

__global__ __launch_bounds__(256) void g2_softmax(float* __restrict__ sc) {
    __shared__ float red[4];
    int bh = blockIdx.x, tid = threadIdx.x;
    int w = tid >> 6;
    for (int i = 0; i < 2; i++) {
        float* row = &sc[((size_t)bh * 2 + i) * T_];
        float vals[4];
        float m = -1e30f;
        for (int c = 0; c < 4; c++) {
            vals[c] = row[tid + 256 * c];
            m = fmaxf(m, vals[c]);
        }
        for (int s = 32; s >= 1; s >>= 1) m = fmaxf(m, __shfl_xor(m, s, 64));
        if ((tid & 63) == 0) red[w] = m;
        __syncthreads();
        m = fmaxf(fmaxf(red[0], red[1]), fmaxf(red[2], red[3]));
        __syncthreads();
        float s = 0.f;
        for (int c = 0; c < 4; c++) {
            vals[c] = __expf(vals[c] - m);
            s += vals[c];
        }
        for (int d = 32; d >= 1; d >>= 1) s += __shfl_xor(s, d, 64);
        if ((tid & 63) == 0) red[w] = s;
        __syncthreads();
        s = red[0] + red[1] + red[2] + red[3];
        float inv = 1.f / s;
        for (int c = 0; c < 4; c++) row[tid + 256 * c] = vals[c] * inv;
        __syncthreads();
    }
}

__global__ __launch_bounds__(256) void g2_pv(const float* __restrict__ sc, const bf16* __restrict__ QKV,
                                             float* __restrict__ og_part) {
    __shared__ float p2[2][256];
    int bh = blockIdx.x, ch = blockIdx.y;
    int b = bh >> 3, h = bh & 7;
    int tid = threadIdx.x;
    for (int i = 0; i < 2; i++) p2[i][tid] = sc[((size_t)bh * 2 + i) * T_ + ch * 256 + tid];
    __syncthreads();
    const bf16* vb = &QKV[((size_t)(b * T_ + ch * 256)) * S6_ + 4096 + h * KD_ + tid];
    float a0 = 0.f, a1 = 0.f;
    for (int t = 0; t < 256; t++) {
        float vv = b2f(vb[(size_t)t * S6_]);
        a0 += p2[0][t] * vv;
        a1 += p2[1][t] * vv;
    }
    og_part[((size_t)(bh * 4 + ch) * 2 + 0) * KD_ + tid] = a0;
    og_part[((size_t)(bh * 4 + ch) * 2 + 1) * KD_ + tid] = a1;
}

// reduce og_part chunks -> og2[(b*2+i)*2048 + h*256+kd]. grid 128.
__global__ __launch_bounds__(256) void g2_red(const float* __restrict__ og_part, float* __restrict__ og2) {
    int idx = blockIdx.x * 256 + threadIdx.x;
    int kd = idx & 255, i = (idx >> 8) & 1, h = (idx >> 9) & 7, b = idx >> 12;
    int bh = b * 8 + h;
    float s = 0.f;
    for (int ch = 0; ch < 4; ch++) s += og_part[((size_t)(bh * 4 + ch) * 2 + i) * KD_ + kd];
    og2[(size_t)(b * 2 + i) * 2048 + h * 256 + kd] = s;
}

// g2buf[bi][d] = og2[bi][:] . gwo_t[d][:] + gbo[d]. grid (16,16), 16 lanes/output.
// gwo_t rows have stride OS_wo (woC layout), offset 2048 within row.
__global__ __launch_bounds__(256) void g2_lin(const float* __restrict__ og2, const bf16* __restrict__ woC,
                                              const float* __restrict__ gbo, float* __restrict__ g2buf) {
    int bi = blockIdx.x, tid = threadIdx.x;
    int d = blockIdx.y * 16 + (tid >> 4);
    int s16i = tid & 15;
    const float* ogr = og2 + (size_t)bi * 2048 + s16i * 128;
    const bf16* wr = woC + (size_t)d * OS_ + 2048 + s16i * 128;   // gWo half
    float acc = 0.f;
    for (int c = 0; c < 16; c++) {
        s16x8 wv = *(const s16x8*)&wr[c * 8];
#pragma unroll
        for (int e = 0; e < 8; e++) acc += ogr[c * 8 + e] * bs2f(wv[e]);
    }
    acc += __shfl_xor(acc, 1, 64);
    acc += __shfl_xor(acc, 2, 64);
    acc += __shfl_xor(acc, 4, 64);
    acc += __shfl_xor(acc, 8, 64);
    if (s16i == 0) g2buf[(size_t)bi * 256 + d] = acc + gbo[d];
}

__global__ __launch_bounds__(256) void g2_kv(const float* __restrict__ g2buf, const bf16* __restrict__ gwk_t,
                                             const float* __restrict__ gbk, const bf16* __restrict__ gwv_t,
                                             const float* __restrict__ gbv, bf16* __restrict__ K2,
                                             bf16* __restrict__ V2) {
    __shared__ float g2s[256];
    int bi = blockIdx.x, ch = blockIdx.y;
    int tid = threadIdx.x;
    g2s[tid] = g2buf[(size_t)bi * 256 + tid];
    __syncthreads();
    int hk = ch * 256 + tid;
    const bf16* rk = &gwk_t[(size_t)hk * D_];
    const bf16* rv = &gwv_t[(size_t)hk * D_];
    float ak = gbk[hk], av = gbv[hk];
    for (int c = 0; c < 32; c++) {
        s16x8 kw = *(const s16x8*)&rk[c * 8];
        s16x8 vw = *(const s16x8*)&rv[c * 8];
#pragma unroll
        for (int e = 0; e < 8; e++) {
            float g = g2s[c * 8 + e];
            ak += g * bs2f(kw[e]);
            av += g * bs2f(vw[e]);
        }
    }
    K2[(size_t)bi * HK_ + hk] = __float2bfloat16(ak);
    V2[(size_t)bi * HK_ + hk] = __float2bfloat16(av);
}

// gx attention: softmax over 2 keys, vectorized. Writes Ob cols 2048..4095. grid BT.
__global__ __launch_bounds__(256) void gx_attn(const bf16* __restrict__ QKV, const bf16* __restrict__ K2,
                                               const bf16* __restrict__ V2, bf16* __restrict__ O) {
    int bt = blockIdx.x;
    int b = bt >> 10;
    int tid = threadIdx.x;
    int h = tid >> 5, ln = tid & 31;
    size_t qoff = (size_t)bt * S6_ + h * KD_ + ln * 8;
    size_t koff = (size_t)(b * 2) * HK_ + h * KD_ + ln * 8;
    s16x8 q = *(const s16x8*)(QKV + qoff);
    s16x8 k0 = *(const s16x8*)(K2 + koff);
    s16x8 k1 = *(const s16x8*)(K2 + koff + HK_);
    s16x8 v0 = *(const s16x8*)(V2 + koff);
    s16x8 v1 = *(const s16x8*)(V2 + koff + HK_);
    float s0 = 0.f, s1 = 0.f;
#pragma unroll
    for (int e = 0; e < 8; e++) {
        float qf = bs2f(q[e]);
        s0 += qf * bs2f(k0[e]);
        s1 += qf * bs2f(k1[e]);
    }
#pragma unroll
    for (int m = 16; m >= 1; m >>= 1) {
        s0 += __shfl_xor(s0, m, 64);
        s1 += __shfl_xor(s1, m, 64);
    }
    s0 *= (1.f / 16.f);
    s1 *= (1.f / 16.f);
    float mx = fmaxf(s0, s1);
    float e0 = __expf(s0 - mx), e1 = __expf(s1 - mx);
    float inv = 1.f / (e0 + e1);
    float p0 = e0 * inv, p1 = e1 * inv;
    s16x8 o;
#pragma unroll
    for (int e = 0; e < 8; e++) {
        float v = p0 * bs2f(v0[e]) + p1 * bs2f(v1[e]);
        o[e] = __builtin_bit_cast(short, __float2bfloat16(v));
    }
    *(s16x8*)(O + (size_t)bt * OS_ + 2048 + h * KD_ + ln * 8) = o;
}

// ---------------- LayerNorm over D=256: wave per row, no LDS ----------------
__global__ __launch_bounds__(256) void ln_kernel(const float* __restrict__ a, const bf16* __restrict__ b2,
                                                 const float* __restrict__ g, const float* __restrict__ bia,
                                                 float* __restrict__ outf, bf16* __restrict__ outb) {
    int w = threadIdx.x >> 6, l = threadIdx.x & 63;
    int row = blockIdx.x * 4 + w;
    size_t base = (size_t)row * D_ + l * 4;
    float4 av = *(const float4*)(a + base);
    ushort4 bv = *(const ushort4*)(b2 + base);
    float vv[4];
    vv[0] = av.x + us2f(bv.x); vv[1] = av.y + us2f(bv.y);
    vv[2] = av.z + us2f(bv.z); vv[3] = av.w + us2f(bv.w);
    float s = vv[0] + vv[1] + vv[2] + vv[3];
#pragma unroll
    for (int m = 32; m >= 1; m >>= 1) s += __shfl_xor(s, m, 64);
    float mean = s * (1.f / 256.f);
    float q = 0.f;
#pragma unroll
    for (int e = 0; e < 4; e++) {
        float d = vv[e] - mean;
        q += d * d;
    }
#pragma unroll
    for (int m = 32; m >= 1; m >>= 1) q += __shfl_xor(q, m, 64);
    float rs = rsqrtf(q * (1.f / 256.f) + 1e-6f);
    float4 gv = *(const float4*)(g + l * 4);
    float4 biv = *(const float4*)(bia + l * 4);
    float o0 = (vv[0] - mean) * rs * gv.x + biv.x;
    float o1 = (vv[1] - mean) * rs * gv.y + biv.y;
    float o2 = (vv[2] - mean) * rs * gv.z + biv.z;
    float o3 = (vv[3] - mean) * rs * gv.w + biv.w;
    if (outf) *(float4*)(outf + base) = (float4){o0, o1, o2, o3};
    if (outb) {
        ushort4 ou;
        ou.x = fbits(o0); ou.y = fbits(o1); ou.z = fbits(o2); ou.w = fbits(o3);
        *(ushort4*)(outb + base) = ou;
    }
}

extern "C" void kernel_launch(void* const* d_in, const int* in_sizes, int n_in, void* d_out, int out_size,
                              void* d_ws, size_t ws_size, hipStream_t stream) {
    const float* x = (const float*)d_in[0];
    const float* lWq = (const float*)d_in[1];  const float* lbq = (const float*)d_in[2];
    const float* lWk = (const float*)d_in[3];  const float* lbk = (const float*)d_in[4];
    const float* lWv = (const float*)d_in[5];  const float* lbv = (const float*)d_in[6];
    const float* lWo = (const float*)d_in[7];  const float* lbo = (const float*)d_in[8];
    const float* gWq = (const float*)d_in[9];  const float* gbq = (const float*)d_in[10];
    const float* gWk = (const float*)d_in[11]; const float* gbk = (const float*)d_in[12];
    const float* gWv = (const float*)d_in[13]; const float* gbv = (const float*)d_in[14];
    const float* gWo = (const float*)d_in[15]; const float* gbo = (const float*)d_in[16];
    const float* fW1 = (const float*)d_in[17]; const float* fb1 = (const float*)d_in[18];
    const float* fW2 = (const float*)d_in[19]; const float* fb2 = (const float*)d_in[20];
    const float* ln1g = (const float*)d_in[21]; const float* ln1b = (const float*)d_in[22];
    const float* ln2g = (const float*)d_in[23]; const float* ln2b = (const float*)d_in[24];

    char* ws = (char*)d_ws;
    size_t off = 0;
    auto alloc = [&](size_t bytes) -> char* {
        char* p = ws + off;
        off = (off + bytes + 255) & ~(size_t)255;
        return p;
    };
    bf16* xb = (bf16*)alloc((size_t)BT_ * D_ * 2);
    bf16* WcatL = (bf16*)alloc((size_t)S6_ * D_ * 2);
    bf16* WcatG = (bf16*)alloc((size_t)S6_ * D_ * 2);
    bf16* woC = (bf16*)alloc((size_t)D_ * OS_ * 2);     // [256][4096] = [lWo^T | gWo^T]
    bf16* fw1_t = (bf16*)alloc((size_t)FF_ * D_ * 2);
    bf16* fw2_t = (bf16*)alloc((size_t)D_ * FF_ * 2);
    float* bcatL = (float*)alloc((size_t)S6_ * 4);
    float* bcatG = (float*)alloc((size_t)S6_ * 4);
    float* boC = (float*)alloc((size_t)D_ * 4);
    bf16* QKV = (bf16*)alloc((size_t)BT_ * S6_ * 2);    // 96 MB, reused local->global
    bf16* Ob = (bf16*)alloc((size_t)BT_ * OS_ * 2);     // 64 MB  [local | gx]
    bf16* attnC = (bf16*)alloc((size_t)BT_ * D_ * 2);
    float* out1 = (float*)alloc((size_t)BT_ * D_ * 4);
    float* sc = (float*)alloc((size_t)B_ * H_ * 2 * T_ * 4);
    float* og_part = (float*)alloc((size_t)B_ * H_ * 4 * 2 * KD_ * 4);
    float* og2 = (float*)alloc((size_t)B_ * 2 * HK_ * 4);
    float* g2buf = (float*)alloc((size_t)B_ * 2 * D_ * 4);
    bf16* K2 = (bf16*)alloc((size_t)B_ * 2 * HK_ * 2);
    bf16* V2 = (bf16*)alloc((size_t)B_ * 2 * HK_ * 2);
    // aliases into QKV (projection data dead after gx_attn):
    bf16* hid = QKV;                                    // [8192][1024] bf16, 16 MB @ 0
    bf16* ffn = (bf16*)((char*)QKV + (32u << 20));      // 4 MB @ 32M
    bf16* out1b = (bf16*)((char*)QKV + (48u << 20));    // 4 MB @ 48M

    // 0. convert + fused transposes + bias prep
    f32_to_bf16_vec<<<(BT_ * D_) / 1024, 256, 0, stream>>>(x, xb, BT_ * D_);
    {
        TJobs js;
        int t = 0;
        auto add = [&](int i, const float* in, bf16* out, int R, int C, int os) {
            js.j[i] = {in, out, R, C, os, t};
            t += (R / 32) * (C / 32);
        };
        add(0, lWq, WcatL, D_, HK_, D_);
        add(1, lWk, WcatL + (size_t)2048 * D_, D_, HK_, D_);
        add(2, lWv, WcatL + (size_t)4096 * D_, D_, HK_, D_);
        add(3, gWq, WcatG, D_, HK_, D_);
        add(4, gWk, WcatG + (size_t)2048 * D_, D_, HK_, D_);
        add(5, gWv, WcatG + (size_t)4096 * D_, D_, HK_, D_);
        add(6, lWo, woC, HK_, D_, OS_);
        add(7, gWo, woC + 2048, HK_, D_, OS_);
        add(8, fW1, fw1_t, D_, FF_, D_);
        add(9, fW2, fw2_t, FF_, D_, FF_);
        js.total = t;
        transpose_all<<<t, dim3(32, 8), 0, stream>>>(js);
    }
    concat_bias<<<S6_ / 256, 256, 0, stream>>>(lbq, lbk, lbv, gbq, gbk, gbv, lbo, gbo, bcatL, bcatG, boC);

    // 1. local path: merged QKV projection + attention (writes Ob left half)
    gemm128<1, 128><<<dim3(S6_ / 128, BT_ / 128), 256, 0, stream>>>(xb, WcatL, bcatL, QKV, BT_, S6_, D_);
    local_attn<<<dim3(T_ / 64, B_ * H_), 256, 0, stream>>>(QKV, Ob);

    // 2. global path (writes Ob right half)
    gemm128<1, 128><<<dim3(S6_ / 128, BT_ / 128), 256, 0, stream>>>(xb, WcatG, bcatG, QKV, BT_, S6_, D_);
    g2_scores<<<dim3(B_ * H_, T_ / 256), 256, 0, stream>>>(QKV, sc);
    g2_softmax<<<B_ * H_, 256, 0, stream>>>(sc);
    g2_pv<<<dim3(B_ * H_, 4), 256, 0, stream>>>(sc, QKV, og_part);
    g2_red<<<128, 256, 0, stream>>>(og_part, og2);
    g2_lin<<<dim3(B_ * 2, 16), 256, 0, stream>>>(og2, woC, gbo, g2buf);
    g2_kv<<<dim3(B_ * 2, HK_ / 256), 256, 0, stream>>>(g2buf, WcatG + (size_t)2048 * D_, gbk,
                                                       WcatG + (size_t)4096 * D_, gbv, K2, V2);
    gx_attn<<<BT_, 256, 0, stream>>>(QKV, K2, V2, Ob);

    // 3. combined out-projection: attnC = Ob @ [lWo; gWo] + (lbo+gbo)
    gemm128<1, 64><<<dim3(D_ / 64, BT_ / 128), 256, 0, stream>>>(Ob, woC, boC, attnC, BT_, D_, OS_);

    // 4. LN1 + FFN + LN2
    ln_kernel<<<BT_ / 4, 256, 0, stream>>>(x, attnC, ln1g, ln1b, out1, out1b);
    gemm128<2, 128><<<dim3(FF_ / 128, BT_ / 128), 256, 0, stream>>>(out1b, fw1_t, fb1, hid, BT_, FF_, D_);
    gemm128<1, 64><<<dim3(D_ / 64, BT_ / 128), 256, 0, stream>>>(hid, fw2_t, fb2, ffn, BT_, D_, FF_);
    ln_kernel<<<BT_ / 4, 256, 0, stream>>>(out1, ffn, ln2g, ln2b, (float*)d_out, nullptr);
}

// Round 8
// 280.739 us; speedup vs baseline: 2.5055x; 1.0968x over previous
//
#include <hip/hip_runtime.h>
#include <hip/hip_bf16.h>

#define B_ 8
#define T_ 1024
#define D_ 256
#define H_ 8
#define KD_ 256
#define HK_ 2048
#define FF_ 1024
#define WIN_ 64
#define BT_ 8192
#define S6_ 6144
#define S4_ 4096

using bf16 = __hip_bfloat16;
typedef float f32x4 __attribute__((ext_vector_type(4)));
typedef short s16x8 __attribute__((ext_vector_type(8)));

__device__ inline float b2f(bf16 h) { return __bfloat162float(h); }
__device__ inline float bs2f(short s) {
    unsigned int u = ((unsigned int)(unsigned short)s) << 16;
    return __builtin_bit_cast(float, u);
}
__device__ inline float us2f(unsigned short s) {
    unsigned int u = ((unsigned int)s) << 16;
    return __builtin_bit_cast(float, u);
}
__device__ inline unsigned short fbits(float x) { bf16 h = __float2bfloat16(x); return __builtin_bit_cast(unsigned short, h); }

// async global->LDS, 16B per lane; lds base wave-uniform, lane l lands at base + l*16
__device__ __forceinline__ void stage16(const void* g, void* l) {
    __builtin_amdgcn_global_load_lds((const __attribute__((address_space(1))) void*)g,
                                     (__attribute__((address_space(3))) void*)l, 16, 0, 0);
}

// ---------------- elementwise f32 -> bf16 ----------------
__global__ __launch_bounds__(256) void f32_to_bf16_vec(const float* __restrict__ in, bf16* __restrict__ out, int n) {
    int i = (blockIdx.x * 256 + threadIdx.x) * 4;
    if (i + 3 < n) {
        float4 v = *(const float4*)(in + i);
        ushort4 o;
        o.x = fbits(v.x); o.y = fbits(v.y); o.z = fbits(v.z); o.w = fbits(v.w);
        *(ushort4*)(out + i) = o;
    }
}

// ---------------- fused weight transposes: in f32[R][C] -> out bf16[C][R], row stride os ----------------
struct TJob { const float* in; bf16* out; int R; int C; int os; int tile_start; };
struct TJobs { TJob j[10]; int total; };

__global__ void transpose_all(TJobs js) {
    __shared__ float tile[32][33];
    int bid = blockIdx.x;
    int ji = 0;
    while (ji < 9 && bid >= js.j[ji + 1].tile_start) ji++;
    TJob jb = js.j[ji];
    int t = bid - jb.tile_start;
    int tiles_x = jb.C / 32;
    int cb = (t % tiles_x) * 32, rb = (t / tiles_x) * 32;
    for (int k = 0; k < 4; k++) {
        int r = threadIdx.y + k * 8;
        tile[r][threadIdx.x] = jb.in[(size_t)(rb + r) * jb.C + cb + threadIdx.x];
    }
    __syncthreads();
    for (int k = 0; k < 4; k++) {
        int r = threadIdx.y + k * 8;
        jb.out[(size_t)(cb + r) * jb.os + rb + threadIdx.x] = __float2bfloat16(tile[threadIdx.x][r]);
    }
}

// biases: outL[6144]=[lbq|lbk|lbv], outG[4096]=[gbk|gbv]
__global__ __launch_bounds__(256) void concat_bias(const float* a0, const float* a1, const float* a2,
                                                   const float* b0, const float* b1,
                                                   float* outL, float* outG) {
    int i = blockIdx.x * 256 + threadIdx.x;
    int seg = i >> 11, off = i & 2047;
    outL[i] = (seg == 0 ? a0 : seg == 1 ? a1 : a2)[off];
    if (i < 4096) outG[i] = (seg == 0 ? b0 : b1)[off];
}

// ---------------- dbuf 2-phase GEMM + XCD-aware block swizzle ----------------
// C[M][N] = A[M][K] * Bt[N][K]^T + bias. 128xBN tile, BK=64, 4 waves. bf16 out.
// MODE 1: plain; MODE 2: relu. Requires gridDim.x*gridDim.y % 8 == 0.
template <int MODE, int BN>
__global__ __launch_bounds__(256) void gemm128(const bf16* __restrict__ A, const bf16* __restrict__ Bt,
                                               const float* __restrict__ bias, bf16* __restrict__ C,
                                               int M, int N, int K) {
    constexpr int NF = BN / 32;
    constexpr int ABUF = 128 * 64;
    constexpr int BBUF = BN * 64;
    constexpr int BUFE = ABUF + BBUF;
    constexpr int EC = BN + 8;
    constexpr int ARENA_E = (2 * BUFE > 128 * EC) ? 2 * BUFE : 128 * EC;
    __shared__ __align__(16) bf16 arena[ARENA_E];
    const int tid = threadIdx.x;
    const int w = tid >> 6, l = tid & 63;
    // XCD-aware bijective swizzle: consecutive work ids (same A-panel) -> same XCD
    const int nwg = gridDim.x * gridDim.y;
    const int bid0 = blockIdx.y * gridDim.x + blockIdx.x;
    const int cpx = nwg >> 3;
    const int bid = (bid0 & 7) * cpx + (bid0 >> 3);
    const int m0 = (bid / gridDim.x) * 128, n0 = (bid % gridDim.x) * BN;
    const int wm = (w >> 1) * 64, wn = (w & 1) * (BN / 2);
    const int srow = w * 8 + (l >> 3);
    const int scol = (l & 7) * 8;
    const int ldsOff = w * 512;
    const int nt = K / 64;

    auto stageT = [&](int buf, int k0) {
        bf16* Ad = arena + buf * BUFE;
        bf16* Bd = Ad + ABUF;
#pragma unroll
        for (int j = 0; j < 4; j++)
            stage16(A + (size_t)(m0 + j * 32 + srow) * K + k0 + scol, &Ad[ldsOff + j * 2048]);
#pragma unroll
        for (int j = 0; j < NF; j++)
            stage16(Bt + (size_t)(n0 + j * 32 + srow) * K + k0 + scol, &Bd[ldsOff + j * 2048]);
    };

    f32x4 acc[4][NF] = {};
    stageT(0, 0);
    __syncthreads();
    int cur = 0;
    for (int t = 0; t < nt; t++) {
        if (t + 1 < nt) stageT(cur ^ 1, (t + 1) * 64);
        const bf16* As = arena + cur * BUFE;
        const bf16* Bs = As + ABUF;
#pragma unroll
        for (int ks = 0; ks < 2; ks++) {
            s16x8 a[4], b[NF];
#pragma unroll
            for (int mf = 0; mf < 4; mf++) a[mf] = *(const s16x8*)&As[(wm + mf * 16 + (l & 15)) * 64 + ks * 32 + (l >> 4) * 8];
#pragma unroll
            for (int nf = 0; nf < NF; nf++) b[nf] = *(const s16x8*)&Bs[(wn + nf * 16 + (l & 15)) * 64 + ks * 32 + (l >> 4) * 8];
            __builtin_amdgcn_s_setprio(1);
#pragma unroll
            for (int mf = 0; mf < 4; mf++)
#pragma unroll
                for (int nf = 0; nf < NF; nf++)
                    acc[mf][nf] = __builtin_amdgcn_mfma_f32_16x16x32_bf16(a[mf], b[nf], acc[mf][nf], 0, 0, 0);
            __builtin_amdgcn_s_setprio(0);
        }
        __syncthreads();
        cur ^= 1;
    }
    bf16* Es = arena;
#pragma unroll
    for (int mf = 0; mf < 4; mf++)
#pragma unroll
        for (int nf = 0; nf < NF; nf++)
#pragma unroll
            for (int r = 0; r < 4; r++) {
                int row = wm + mf * 16 + (l >> 4) * 4 + r;
                int col = wn + nf * 16 + (l & 15);
                float v = acc[mf][nf][r] + bias[n0 + col];
                if (MODE == 2) v = fmaxf(v, 0.f);
                Es[row * EC + col] = __float2bfloat16(v);
            }
    __syncthreads();
    constexpr int RPC = BN / 8;
    constexpr int CPT = (128 * BN) / (256 * 8);
#pragma unroll
    for (int c = 0; c < CPT; c++) {
        int lin = c * 256 + tid;
        int row = lin / RPC, cc = lin - row * RPC;
        s16x8 v = *(const s16x8*)&Es[row * EC + cc * 8];
        *(s16x8*)(C + (size_t)(m0 + row) * N + n0 + cc * 8) = v;
    }
}

// ---------------- local windowed attention (proven) ----------------
// QKV: [B*T][6144] (lQ | lK | lV). O: [B*T][2048]. grid (T/64, B*H).
__global__ __launch_bounds__(256) void local_attn(const bf16* __restrict__ QKV, bf16* __restrict__ O) {
    __shared__ bf16 U[256 * 72];
    __shared__ bf16 Ps[64][136];
    const int tid = threadIdx.x, l = tid & 63, w = tid >> 6;
    const int qt = blockIdx.x, bh = blockIdx.y;
    const int b = bh >> 3, h = bh & 7;
    const int qs = qt * 64;
    const int r0 = w * 16;
    const int lrow = tid >> 2, lc4 = (tid & 3) * 8;
    const size_t obase = (size_t)b * T_ * HK_ + h * KD_;

    s16x8 qa[8];
    {
        const bf16* qbase = QKV + (size_t)(b * T_ + qs + r0 + (l & 15)) * S6_ + h * KD_ + (l >> 4) * 8;
#pragma unroll
        for (int ks = 0; ks < 8; ks++) qa[ks] = *(const s16x8*)(qbase + ks * 32);
    }

    bf16(*Ks)[264] = (bf16(*)[264])U;
    {
        int tk = qs - 64 + lrow;
        const bf16* krow = QKV + (size_t)(b * T_ + tk) * S6_ + 2048 + h * KD_;
#pragma unroll
        for (int c = 0; c < 8; c++) {
            int col = lc4 + c * 32;
            uint4 val = {0, 0, 0, 0};
            if (tk >= 0) val = *(const uint4*)(krow + col);
            *(uint4*)&Ks[lrow][col] = val;
        }
    }
    __syncthreads();
    f32x4 sacc[8];
#pragma unroll
    for (int f = 0; f < 8; f++) sacc[f] = (f32x4){0.f, 0.f, 0.f, 0.f};
    __builtin_amdgcn_s_setprio(1);
#pragma unroll
    for (int nf = 0; nf < 4; nf++)
#pragma unroll
        for (int ks = 0; ks < 8; ks++) {
            s16x8 bb = *(const s16x8*)&Ks[nf * 16 + (l & 15)][ks * 32 + (l >> 4) * 8];
            sacc[nf] = __builtin_amdgcn_mfma_f32_16x16x32_bf16(qa[ks], bb, sacc[nf], 0, 0, 0);
        }
    __builtin_amdgcn_s_setprio(0);
    __syncthreads();
    {
        const bf16* krow = QKV + (size_t)(b * T_ + qs + lrow) * S6_ + 2048 + h * KD_;
#pragma unroll
        for (int c = 0; c < 8; c++) {
            int col = lc4 + c * 32;
            *(uint4*)&Ks[lrow][col] = *(const uint4*)(krow + col);
        }
    }
    __syncthreads();
    __builtin_amdgcn_s_setprio(1);
#pragma unroll
    for (int nf = 0; nf < 4; nf++)
#pragma unroll
        for (int ks = 0; ks < 8; ks++) {
            s16x8 bb = *(const s16x8*)&Ks[nf * 16 + (l & 15)][ks * 32 + (l >> 4) * 8];
            sacc[4 + nf] = __builtin_amdgcn_mfma_f32_16x16x32_bf16(qa[ks], bb, sacc[4 + nf], 0, 0, 0);
        }
    __builtin_amdgcn_s_setprio(0);

    uint4 vreg[8];
    {
        int tk = qs - 64 + lrow;
        const bf16* vrow = QKV + (size_t)(b * T_ + tk) * S6_ + 4096 + h * KD_;
#pragma unroll
        for (int c = 0; c < 8; c++) {
            uint4 v = {0, 0, 0, 0};
            if (tk >= 0) v = *(const uint4*)(vrow + lc4 + c * 32);
            vreg[c] = v;
        }
    }

#pragma unroll
    for (int r = 0; r < 4; r++) {
        int i = qs + r0 + (l >> 4) * 4 + r;
#pragma unroll
        for (int f = 0; f < 8; f++) {
            int j = qs - 64 + f * 16 + (l & 15);
            bool valid = (j >= 0) && (j <= i) && (j > i - WIN_);
            sacc[f][r] = valid ? sacc[f][r] * (1.f / 16.f) : -1e9f;
        }
        float mm = -1e30f;
#pragma unroll
        for (int f = 0; f < 8; f++) mm = fmaxf(mm, sacc[f][r]);
        mm = fmaxf(mm, __shfl_xor(mm, 1, 64));
        mm = fmaxf(mm, __shfl_xor(mm, 2, 64));
        mm = fmaxf(mm, __shfl_xor(mm, 4, 64));
        mm = fmaxf(mm, __shfl_xor(mm, 8, 64));
        float ss = 0.f;
#pragma unroll
        for (int f = 0; f < 8; f++) {
            float e = __expf(sacc[f][r] - mm);
            sacc[f][r] = e;
            ss += e;
        }
        ss += __shfl_xor(ss, 1, 64);
        ss += __shfl_xor(ss, 2, 64);
        ss += __shfl_xor(ss, 4, 64);
        ss += __shfl_xor(ss, 8, 64);
        float inv = 1.f / ss;
#pragma unroll
        for (int f = 0; f < 8; f++) sacc[f][r] *= inv;
    }
    __syncthreads();

    bf16(*VT)[72] = (bf16(*)[72])U;
#pragma unroll
    for (int f = 0; f < 8; f++)
#pragma unroll
        for (int r = 0; r < 4; r++)
            Ps[r0 + (l >> 4) * 4 + r][f * 16 + (l & 15)] = __float2bfloat16(sacc[f][r]);
#pragma unroll
    for (int c = 0; c < 8; c++) {
        int col = lc4 + c * 32;
        bf16 tmp[8];
        *(uint4*)tmp = vreg[c];
        for (int e = 0; e < 8; e++) VT[col + e][lrow] = tmp[e];
    }
    __syncthreads();
    {
        const bf16* vrow = QKV + (size_t)(b * T_ + qs + lrow) * S6_ + 4096 + h * KD_;
#pragma unroll
        for (int c = 0; c < 8; c++) vreg[c] = *(const uint4*)(vrow + lc4 + c * 32);
    }

    f32x4 oacc[16];
#pragma unroll
    for (int nf = 0; nf < 16; nf++) oacc[nf] = (f32x4){0.f, 0.f, 0.f, 0.f};
    for (int kb = 0; kb < 2; kb++) {
#pragma unroll
        for (int ks = 0; ks < 2; ks++) {
            s16x8 a = *(const s16x8*)&Ps[r0 + (l & 15)][kb * 64 + ks * 32 + (l >> 4) * 8];
            __builtin_amdgcn_s_setprio(1);
#pragma unroll
            for (int nf = 0; nf < 16; nf++) {
                s16x8 bb = *(const s16x8*)&VT[nf * 16 + (l & 15)][ks * 32 + (l >> 4) * 8];
                oacc[nf] = __builtin_amdgcn_mfma_f32_16x16x32_bf16(a, bb, oacc[nf], 0, 0, 0);
            }
            __builtin_amdgcn_s_setprio(0);
        }
        if (kb == 0) {
            __syncthreads();
#pragma unroll
            for (int c = 0; c < 8; c++) {
                int col = lc4 + c * 32;
                bf16 tmp[8];
                *(uint4*)tmp = vreg[c];
                for (int e = 0; e < 8; e++) VT[col + e][lrow] = tmp[e];
            }
            __syncthreads();
        }
    }
#pragma unroll
    for (int nf = 0; nf < 16; nf++)
#pragma unroll
        for (int r = 0; r < 4; r++) {
            int row = r0 + (l >> 4) * 4 + r;
            int col = nf * 16 + (l & 15);
            O[obase + (size_t)(qs + row) * HK_ + col] = __float2bfloat16(oacc[nf][r]);
        }
}

// ---------------- global path ----------------
// qg[bi][hk] = x[b, T-2+i] . gWq[:,hk] + gbq[hk]. grid (16, 8).
__global__ __launch_bounds__(256) void qg_kernel(const float* __restrict__ x, const bf16* __restrict__ gwq_t,
                                                 const float* __restrict__ gbq, float* __restrict__ qg) {
    __shared__ float xs[256];
    int bi = blockIdx.x, ch = blockIdx.y, tid = threadIdx.x;
    int b = bi >> 1, i = bi & 1;
    xs[tid] = x[((size_t)b * T_ + (T_ - 2 + i)) * D_ + tid];
    __syncthreads();
    int hk = ch * 256 + tid;
    const bf16* wr = gwq_t + (size_t)hk * D_;
    float acc = gbq[hk];
    for (int c = 0; c < 32; c++) {
        s16x8 wv = *(const s16x8*)&wr[c * 8];
#pragma unroll
        for (int e = 0; e < 8; e++) acc += xs[c * 8 + e] * bs2f(wv[e]);
    }
    qg[(size_t)bi * HK_ + hk] = acc;
}

// scores vs gK. KVg: [B*T][4096] = [gK | gV]. grid (B*H, T/256).
__global__ __launch_bounds__(256) void g2_scores(const float* __restrict__ qg, const bf16* __restrict__ KVg,
                                                 float* __restrict__ sc) {
    __shared__ float qf[2][256];
    int bh = blockIdx.x, ch = blockIdx.y;
    int b = bh >> 3, h = bh & 7;
    int tid = threadIdx.x;
    for (int i = 0; i < 2; i++)
        qf[i][tid] = qg[(size_t)(b * 2 + i) * HK_ + h * KD_ + tid];
    __syncthreads();
    int t = ch * 256 + tid;
    const bf16* kr = &KVg[((size_t)(b * T_ + t)) * S4_ + h * KD_];
    float a0 = 0.f, a1 = 0.f;
    for (int c = 0; c < 32; c++) {
        s16x8 kv = *(const s16x8*)&kr[c * 8];
#pragma unroll
        for (int e = 0; e < 8; e++) {
            float kf = bs2f(kv[e]);
            a0 += kf * qf[0][c * 8 + e];
            a1 += kf * qf[1][c * 8 + e];
        }
    }
    sc[((size_t)bh * 2 + 0) * T_ + t] = a0 * (1.f / 16.f);
    sc[((size_t)bh * 2 + 1) * T_ + t] = a1 * (1.f / 16.f);
}

__global__ __launch_bounds__(256) void g2_softmax(float* __restrict__ sc) {
    __shared__ float red[4];
    int bh = blockIdx.x, tid = threadIdx.x;
    int w = tid >> 6;
    for (int i = 0; i < 2; i++) {
        float* row = &sc[((size_t)bh * 2 + i) * T_];
        float vals[4];
        float m = -1e30f;
        for (int c = 0; c < 4; c++) {
            vals[c] = row[tid + 256 * c];
            m = fmaxf(m, vals[c]);
        }
        for (int s = 32; s >= 1; s >>= 1) m = fmaxf(m, __shfl_xor(m, s, 64));
        if ((tid & 63) == 0) red[w] = m;
        __syncthreads();
        m = fmaxf(fmaxf(red[0], red[1]), fmaxf(red[2], red[3]));
        __syncthreads();
        float s = 0.f;
        for (int c = 0; c < 4; c++) {
            vals[c] = __expf(vals[c] - m);
            s += vals[c];
        }
        for (int d = 32; d >= 1; d >>= 1) s += __shfl_xor(s, d, 64);
        if ((tid & 63) == 0) red[w] = s;
        __syncthreads();
        s = red[0] + red[1] + red[2] + red[3];
        float inv = 1.f / s;
        for (int c = 0; c < 4; c++) row[tid + 256 * c] = vals[c] * inv;
        __syncthreads();
    }
}

__global__ __launch_bounds__(256) void g2_pv(const float* __restrict__ sc, const bf16* __restrict__ KVg,
                                             float* __restrict__ og_part) {
    __shared__ float p2[2][256];
    int bh = blockIdx.x, ch = blockIdx.y;
    int b = bh >> 3, h = bh & 7;
    int tid = threadIdx.x;
    for (int i = 0; i < 2; i++) p2[i][tid] = sc[((size_t)bh * 2 + i) * T_ + ch * 256 + tid];
    __syncthreads();
    const bf16* vb = &KVg[((size_t)(b * T_ + ch * 256)) * S4_ + 2048 + h * KD_ + tid];
    float a0 = 0.f, a1 = 0.f;
    for (int t = 0; t < 256; t++) {
        float vv = b2f(vb[(size_t)t * S4_]);
        a0 += p2[0][t] * vv;
        a1 += p2[1][t] * vv;
    }
    og_part[((size_t)(bh * 4 + ch) * 2 + 0) * KD_ + tid] = a0;
    og_part[((size_t)(bh * 4 + ch) * 2 + 1) * KD_ + tid] = a1;
}

__global__ __launch_bounds__(256) void g2_red(const float* __restrict__ og_part, float* __restrict__ og2) {
    int idx = blockIdx.x * 256 + threadIdx.x;
    int kd = idx & 255, i = (idx >> 8) & 1, h = (idx >> 9) & 7, b = idx >> 12;
    int bh = b * 8 + h;
    float s = 0.f;
    for (int ch = 0; ch < 4; ch++) s += og_part[((size_t)(bh * 4 + ch) * 2 + i) * KD_ + kd];
    og2[(size_t)(b * 2 + i) * 2048 + h * 256 + kd] = s;
}

// g2buf[bi][d] = og2[bi][:] . gwoT[d][:] + gbo[d]. grid (16,16).
__global__ __launch_bounds__(256) void g2_lin(const float* __restrict__ og2, const bf16* __restrict__ gwoT,
                                              const float* __restrict__ gbo, float* __restrict__ g2buf) {
    int bi = blockIdx.x, tid = threadIdx.x;
    int d = blockIdx.y * 16 + (tid >> 4);
    int s16i = tid & 15;
    const float* ogr = og2 + (size_t)bi * 2048 + s16i * 128;
    const bf16* wr = gwoT + (size_t)d * HK_ + s16i * 128;
    float acc = 0.f;
    for (int c = 0; c < 16; c++) {
        s16x8 wv = *(const s16x8*)&wr[c * 8];
#pragma unroll
        for (int e = 0; e < 8; e++) acc += ogr[c * 8 + e] * bs2f(wv[e]);
    }
    acc += __shfl_xor(acc, 1, 64);
    acc += __shfl_xor(acc, 2, 64);
    acc += __shfl_xor(acc, 4, 64);
    acc += __shfl_xor(acc, 8, 64);
    if (s16i == 0) g2buf[(size_t)bi * 256 + d] = acc + gbo[d];
}

__global__ __launch_bounds__(256) void g2_kv(const float* __restrict__ g2buf, const bf16* __restrict__ gwk_t,
                                             const float* __restrict__ gbk, const bf16* __restrict__ gwv_t,
                                             const float* __restrict__ gbv, bf16* __restrict__ K2,
                                             bf16* __restrict__ V2) {
    __shared__ float g2s[256];
    int bi = blockIdx.x, ch = blockIdx.y;
    int tid = threadIdx.x;
    g2s[tid] = g2buf[(size_t)bi * 256 + tid];
    __syncthreads();
    int hk = ch * 256 + tid;
    const bf16* rk = &gwk_t[(size_t)hk * D_];
    const bf16* rv = &gwv_t[(size_t)hk * D_];
    float ak = gbk[hk], av = gbv[hk];
    for (int c = 0; c < 32; c++) {
        s16x8 kw = *(const s16x8*)&rk[c * 8];
        s16x8 vw = *(const s16x8*)&rv[c * 8];
#pragma unroll
        for (int e = 0; e < 8; e++) {
            float g = g2s[c * 8 + e];
            ak += g * bs2f(kw[e]);
            av += g * bs2f(vw[e]);
        }
    }
    K2[(size_t)bi * HK_ + hk] = __float2bfloat16(ak);
    V2[(size_t)bi * HK_ + hk] = __float2bfloat16(av);
}

// A2[bi,h,d] = sum_kd K2[bi,h,kd]*gWq[d,h,kd]; W2[bi,h,d] = sum_kd V2[bi,h,kd]*gWo[h,kd,d];
// c2[bi,h] = gbq_h . K2[bi,h]. grid (16, 8).
__global__ __launch_bounds__(256) void a2w2_kernel(const bf16* __restrict__ K2, const bf16* __restrict__ V2,
                                                   const bf16* __restrict__ gwq_t, const bf16* __restrict__ gwoT,
                                                   const float* __restrict__ gbq, float* __restrict__ A2,
                                                   float* __restrict__ W2, float* __restrict__ c2) {
    __shared__ float k2s[256], v2s[256];
    __shared__ float red[4];
    int bi = blockIdx.x, h = blockIdx.y, tid = threadIdx.x;
    k2s[tid] = b2f(K2[(size_t)bi * HK_ + h * 256 + tid]);
    v2s[tid] = b2f(V2[(size_t)bi * HK_ + h * 256 + tid]);
    __syncthreads();
    // A2: coalesced across threads (thread=d), loop kd
    float accA = 0.f;
    const bf16* wq = gwq_t + (size_t)(h * 256) * D_ + tid;
    for (int kd = 0; kd < 256; kd++)
        accA += k2s[kd] * b2f(wq[(size_t)kd * D_]);
    // W2: per-thread contiguous row of gwoT
    float accW = 0.f;
    const bf16* wo = gwoT + (size_t)tid * HK_ + h * 256;
    for (int c = 0; c < 32; c++) {
        s16x8 wv = *(const s16x8*)&wo[c * 8];
#pragma unroll
        for (int e = 0; e < 8; e++) accW += v2s[c * 8 + e] * bs2f(wv[e]);
    }
    int o = (bi * 8 + h) * 256 + tid;
    A2[o] = accA;
    W2[o] = accW;
    float pc = gbq[h * 256 + tid] * k2s[tid];
#pragma unroll
    for (int m = 32; m >= 1; m >>= 1) pc += __shfl_xor(pc, m, 64);
    if ((tid & 63) == 0) red[tid >> 6] = pc;
    __syncthreads();
    if (tid == 0) c2[bi * 8 + h] = red[0] + red[1] + red[2] + red[3];
}

// gx fused: s[t,h,i] = (x[t].A2[b,i,h] + c2[b,i,h])/16; softmax over i; out = sum_h p.W2 + gbo.
// grid BT/4, wave per row.
__global__ __launch_bounds__(256) void gx_fused(const float* __restrict__ x, const float* __restrict__ A2,
                                                const float* __restrict__ W2, const float* __restrict__ c2,
                                                const float* __restrict__ gbo, bf16* __restrict__ attnG) {
    int w = threadIdx.x >> 6, l = threadIdx.x & 63;
    int t = blockIdx.x * 4 + w;
    int b = t >> 10;
    float4 x4 = *(const float4*)(x + (size_t)t * D_ + l * 4);
    float p[8][2];
#pragma unroll
    for (int h = 0; h < 8; h++)
#pragma unroll
        for (int i = 0; i < 2; i++) {
            const float* a = A2 + ((size_t)((b * 2 + i) * 8 + h)) * 256 + l * 4;
            float4 a4 = *(const float4*)a;
            float dt = x4.x * a4.x + x4.y * a4.y + x4.z * a4.z + x4.w * a4.w;
#pragma unroll
            for (int m = 32; m >= 1; m >>= 1) dt += __shfl_xor(dt, m, 64);
            p[h][i] = dt;
        }
    float4 gb = *(const float4*)(gbo + l * 4);
    float o0 = gb.x, o1 = gb.y, o2 = gb.z, o3 = gb.w;
#pragma unroll
    for (int h = 0; h < 8; h++) {
        float s0 = (p[h][0] + c2[(b * 2 + 0) * 8 + h]) * (1.f / 16.f);
        float s1 = (p[h][1] + c2[(b * 2 + 1) * 8 + h]) * (1.f / 16.f);
        float mx = fmaxf(s0, s1);
        float e0 = __expf(s0 - mx), e1 = __expf(s1 - mx);
        float inv = 1.f / (e0 + e1);
        float p0 = e0 * inv, p1 = e1 * inv;
        float4 w0 = *(const float4*)(W2 + ((size_t)((b * 2 + 0) * 8 + h)) * 256 + l * 4);
        float4 w1 = *(const float4*)(W2 + ((size_t)((b * 2 + 1) * 8 + h)) * 256 + l * 4);
        o0 += p0 * w0.x + p1 * w1.x;
        o1 += p0 * w0.y + p1 * w1.y;
        o2 += p0 * w0.z + p1 * w1.z;
        o3 += p0 * w0.w + p1 * w1.w;
    }
    ushort4 ou;
    ou.x = fbits(o0); ou.y = fbits(o1); ou.z = fbits(o2); ou.w = fbits(o3);
    *(ushort4*)(attnG + (size_t)t * D_ + l * 4) = ou;
}

// ---------------- LayerNorm over D=256: wave per row ----------------
__global__ __launch_bounds__(256) void ln_kernel(const float* __restrict__ a, const bf16* __restrict__ b2,
                                                 const bf16* __restrict__ c, const float* __restrict__ g,
                                                 const float* __restrict__ bia, float* __restrict__ outf,
                                                 bf16* __restrict__ outb) {
    int w = threadIdx.x >> 6, l = threadIdx.x & 63;
    int row = blockIdx.x * 4 + w;
    size_t base = (size_t)row * D_ + l * 4;
    float4 av = *(const float4*)(a + base);
    ushort4 bv = *(const ushort4*)(b2 + base);
    float vv[4];
    vv[0] = av.x + us2f(bv.x); vv[1] = av.y + us2f(bv.y);
    vv[2] = av.z + us2f(bv.z); vv[3] = av.w + us2f(bv.w);
    if (c) {
        ushort4 cv = *(const ushort4*)(c + base);
        vv[0] += us2f(cv.x); vv[1] += us2f(cv.y); vv[2] += us2f(cv.z); vv[3] += us2f(cv.w);
    }
    float s = vv[0] + vv[1] + vv[2] + vv[3];
#pragma unroll
    for (int m = 32; m >= 1; m >>= 1) s += __shfl_xor(s, m, 64);
    float mean = s * (1.f / 256.f);
    float q = 0.f;
#pragma unroll
    for (int e = 0; e < 4; e++) {
        float d = vv[e] - mean;
        q += d * d;
    }
#pragma unroll
    for (int m = 32; m >= 1; m >>= 1) q += __shfl_xor(q, m, 64);
    float rs = rsqrtf(q * (1.f / 256.f) + 1e-6f);
    float4 gv = *(const float4*)(g + l * 4);
    float4 biv = *(const float4*)(bia + l * 4);
    float o0 = (vv[0] - mean) * rs * gv.x + biv.x;
    float o1 = (vv[1] - mean) * rs * gv.y + biv.y;
    float o2 = (vv[2] - mean) * rs * gv.z + biv.z;
    float o3 = (vv[3] - mean) * rs * gv.w + biv.w;
    if (outf) *(float4*)(outf + base) = (float4){o0, o1, o2, o3};
    if (outb) {
        ushort4 ou;
        ou.x = fbits(o0); ou.y = fbits(o1); ou.z = fbits(o2); ou.w = fbits(o3);
        *(ushort4*)(outb + base) = ou;
    }
}

extern "C" void kernel_launch(void* const* d_in, const int* in_sizes, int n_in, void* d_out, int out_size,
                              void* d_ws, size_t ws_size, hipStream_t stream) {
    const float* x = (const float*)d_in[0];
    const float* lWq = (const float*)d_in[1];  const float* lbq = (const float*)d_in[2];
    const float* lWk = (const float*)d_in[3];  const float* lbk = (const float*)d_in[4];
    const float* lWv = (const float*)d_in[5];  const float* lbv = (const float*)d_in[6];
    const float* lWo = (const float*)d_in[7];  const float* lbo = (const float*)d_in[8];
    const float* gWq = (const float*)d_in[9];  const float* gbq = (const float*)d_in[10];
    const float* gWk = (const float*)d_in[11]; const float* gbk = (const float*)d_in[12];
    const float* gWv = (const float*)d_in[13]; const float* gbv = (const float*)d_in[14];
    const float* gWo = (const float*)d_in[15]; const float* gbo = (const float*)d_in[16];
    const float* fW1 = (const float*)d_in[17]; const float* fb1 = (const float*)d_in[18];
    const float* fW2 = (const float*)d_in[19]; const float* fb2 = (const float*)d_in[20];
    const float* ln1g = (const float*)d_in[21]; const float* ln1b = (const float*)d_in[22];
    const float* ln2g = (const float*)d_in[23]; const float* ln2b = (const float*)d_in[24];

    char* ws = (char*)d_ws;
    size_t off = 0;
    auto alloc = [&](size_t bytes) -> char* {
        char* p = ws + off;
        off = (off + bytes + 255) & ~(size_t)255;
        return p;
    };
    bf16* xb = (bf16*)alloc((size_t)BT_ * D_ * 2);
    bf16* WcatL = (bf16*)alloc((size_t)S6_ * D_ * 2);   // [lWq|lWk|lWv]^T
    bf16* WcatG = (bf16*)alloc((size_t)S4_ * D_ * 2);   // [gWk|gWv]^T
    bf16* gwq_t = (bf16*)alloc((size_t)HK_ * D_ * 2);   // gWq^T [2048][256]
    bf16* woL = (bf16*)alloc((size_t)D_ * HK_ * 2);     // lWo^T [256][2048]
    bf16* gwoT = (bf16*)alloc((size_t)D_ * HK_ * 2);    // gWo^T [256][2048]
    bf16* fw1_t = (bf16*)alloc((size_t)FF_ * D_ * 2);
    bf16* fw2_t = (bf16*)alloc((size_t)D_ * FF_ * 2);
    float* bcatL = (float*)alloc((size_t)S6_ * 4);
    float* bcatG = (float*)alloc((size_t)S4_ * 4);
    bf16* QKV = (bf16*)alloc((size_t)BT_ * S6_ * 2);    // 96 MB; local QKV, then KVg + FFN aliases
    bf16* Ob = (bf16*)alloc((size_t)BT_ * HK_ * 2);     // 32 MB local attn out
    bf16* attnL = (bf16*)alloc((size_t)BT_ * D_ * 2);
    bf16* attnG = (bf16*)alloc((size_t)BT_ * D_ * 2);
    float* out1 = (float*)alloc((size_t)BT_ * D_ * 4);
    float* sc = (float*)alloc((size_t)B_ * H_ * 2 * T_ * 4);
    float* og_part = (float*)alloc((size_t)B_ * H_ * 4 * 2 * KD_ * 4);
    float* og2 = (float*)alloc((size_t)B_ * 2 * HK_ * 4);
    float* g2buf = (float*)alloc((size_t)B_ * 2 * D_ * 4);
    float* qg = (float*)alloc((size_t)B_ * 2 * HK_ * 4);
    bf16* K2 = (bf16*)alloc((size_t)B_ * 2 * HK_ * 2);
    bf16* V2 = (bf16*)alloc((size_t)B_ * 2 * HK_ * 2);
    float* A2 = (float*)alloc((size_t)16 * 8 * 256 * 4);
    float* W2 = (float*)alloc((size_t)16 * 8 * 256 * 4);
    float* c2 = (float*)alloc((size_t)16 * 8 * 4);
    // aliases into QKV:
    bf16* KVg = QKV;                                    // [8192][4096] = 64 MB (after local_attn)
    bf16* hid = QKV;                                    // 16 MB @ 0 (after g2_pv)
    bf16* ffn = (bf16*)((char*)QKV + (32u << 20));      // 4 MB @ 32M
    bf16* out1b = (bf16*)((char*)QKV + (48u << 20));    // 4 MB @ 48M

    // 0. convert + transposes + biases + qg
    f32_to_bf16_vec<<<(BT_ * D_) / 1024, 256, 0, stream>>>(x, xb, BT_ * D_);
    {
        TJobs js;
        int t = 0;
        auto add = [&](int i, const float* in, bf16* out, int R, int C, int os) {
            js.j[i] = {in, out, R, C, os, t};
            t += (R / 32) * (C / 32);
        };
        add(0, lWq, WcatL, D_, HK_, D_);
        add(1, lWk, WcatL + (size_t)2048 * D_, D_, HK_, D_);
        add(2, lWv, WcatL + (size_t)4096 * D_, D_, HK_, D_);
        add(3, gWk, WcatG, D_, HK_, D_);
        add(4, gWv, WcatG + (size_t)2048 * D_, D_, HK_, D_);
        add(5, gWq, gwq_t, D_, HK_, D_);
        add(6, lWo, woL, HK_, D_, HK_);
        add(7, gWo, gwoT, HK_, D_, HK_);
        add(8, fW1, fw1_t, D_, FF_, D_);
        add(9, fW2, fw2_t, FF_, D_, FF_);
        js.total = t;
        transpose_all<<<t, dim3(32, 8), 0, stream>>>(js);
    }
    concat_bias<<<S6_ / 256, 256, 0, stream>>>(lbq, lbk, lbv, gbk, gbv, bcatL, bcatG);
    qg_kernel<<<dim3(16, 8), 256, 0, stream>>>(x, gwq_t, gbq, qg);

    // 1. local path
    gemm128<1, 128><<<dim3(S6_ / 128, BT_ / 128), 256, 0, stream>>>(xb, WcatL, bcatL, QKV, BT_, S6_, D_);
    local_attn<<<dim3(T_ / 64, B_ * H_), 256, 0, stream>>>(QKV, Ob);
    gemm128<1, 64><<<dim3(D_ / 64, BT_ / 128), 256, 0, stream>>>(Ob, woL, lbo, attnL, BT_, D_, HK_);

    // 2. global path (QKV region reused as KVg after local_attn)
    gemm128<1, 128><<<dim3(S4_ / 128, BT_ / 128), 256, 0, stream>>>(xb, WcatG, bcatG, KVg, BT_, S4_, D_);
    g2_scores<<<dim3(B_ * H_, T_ / 256), 256, 0, stream>>>(qg, KVg, sc);
    g2_softmax<<<B_ * H_, 256, 0, stream>>>(sc);
    g2_pv<<<dim3(B_ * H_, 4), 256, 0, stream>>>(sc, KVg, og_part);
    g2_red<<<128, 256, 0, stream>>>(og_part, og2);
    g2_lin<<<dim3(B_ * 2, 16), 256, 0, stream>>>(og2, gwoT, gbo, g2buf);
    g2_kv<<<dim3(B_ * 2, HK_ / 256), 256, 0, stream>>>(g2buf, WcatG, gbk, WcatG + (size_t)2048 * D_, gbv, K2, V2);
    a2w2_kernel<<<dim3(16, 8), 256, 0, stream>>>(K2, V2, gwq_t, gwoT, gbq, A2, W2, c2);
    gx_fused<<<BT_ / 4, 256, 0, stream>>>(x, A2, W2, c2, gbo, attnG);

    // 3. LN1 + FFN + LN2
    ln_kernel<<<BT_ / 4, 256, 0, stream>>>(x, attnL, attnG, ln1g, ln1b, out1, out1b);
    gemm128<2, 128><<<dim3(FF_ / 128, BT_ / 128), 256, 0, stream>>>(out1b, fw1_t, fb1, hid, BT_, FF_, D_);
    gemm128<1, 64><<<dim3(D_ / 64, BT_ / 128), 256, 0, stream>>>(hid, fw2_t, fb2, ffn, BT_, D_, FF_);
    ln_kernel<<<BT_ / 4, 256, 0, stream>>>(out1, ffn, nullptr, ln2g, ln2b, (float*)d_out, nullptr);
}

// Round 9
// 271.582 us; speedup vs baseline: 2.5900x; 1.0337x over previous
//
#include <hip/hip_runtime.h>
#include <hip/hip_bf16.h>

#define B_ 8
#define T_ 1024
#define D_ 256
#define H_ 8
#define KD_ 256
#define HK_ 2048
#define FF_ 1024
#define WIN_ 64
#define BT_ 8192
#define S6_ 6144
#define S4_ 4096

using bf16 = __hip_bfloat16;
typedef float f32x4 __attribute__((ext_vector_type(4)));
typedef short s16x8 __attribute__((ext_vector_type(8)));

__device__ inline float b2f(bf16 h) { return __bfloat162float(h); }
__device__ inline float bs2f(short s) {
    unsigned int u = ((unsigned int)(unsigned short)s) << 16;
    return __builtin_bit_cast(float, u);
}
__device__ inline float us2f(unsigned short s) {
    unsigned int u = ((unsigned int)s) << 16;
    return __builtin_bit_cast(float, u);
}
__device__ inline unsigned short fbits(float x) { bf16 h = __float2bfloat16(x); return __builtin_bit_cast(unsigned short, h); }

// async global->LDS, 16B per lane; lds base wave-uniform, lane l lands at base + l*16
__device__ __forceinline__ void stage16(const void* g, void* l) {
    __builtin_amdgcn_global_load_lds((const __attribute__((address_space(1))) void*)g,
                                     (__attribute__((address_space(3))) void*)l, 16, 0, 0);
}

// ---------------- elementwise f32 -> bf16 ----------------
__global__ __launch_bounds__(256) void f32_to_bf16_vec(const float* __restrict__ in, bf16* __restrict__ out, int n) {
    int i = (blockIdx.x * 256 + threadIdx.x) * 4;
    if (i + 3 < n) {
        float4 v = *(const float4*)(in + i);
        ushort4 o;
        o.x = fbits(v.x); o.y = fbits(v.y); o.z = fbits(v.z); o.w = fbits(v.w);
        *(ushort4*)(out + i) = o;
    }
}

// ---------------- fused weight transposes: in f32[R][C] -> out bf16[C][R], row stride os ----------------
struct TJob { const float* in; bf16* out; int R; int C; int os; int tile_start; };
struct TJobs { TJob j[10]; int total; };

__global__ void transpose_all(TJobs js) {
    __shared__ float tile[32][33];
    int bid = blockIdx.x;
    int ji = 0;
    while (ji < 9 && bid >= js.j[ji + 1].tile_start) ji++;
    TJob jb = js.j[ji];
    int t = bid - jb.tile_start;
    int tiles_x = jb.C / 32;
    int cb = (t % tiles_x) * 32, rb = (t / tiles_x) * 32;
    for (int k = 0; k < 4; k++) {
        int r = threadIdx.y + k * 8;
        tile[r][threadIdx.x] = jb.in[(size_t)(rb + r) * jb.C + cb + threadIdx.x];
    }
    __syncthreads();
    for (int k = 0; k < 4; k++) {
        int r = threadIdx.y + k * 8;
        jb.out[(size_t)(cb + r) * jb.os + rb + threadIdx.x] = __float2bfloat16(tile[threadIdx.x][r]);
    }
}

// biases: outL[6144]=[lbq|lbk|lbv], outG[4096]=[gbk|gbv]
__global__ __launch_bounds__(256) void concat_bias(const float* a0, const float* a1, const float* a2,
                                                   const float* b0, const float* b1,
                                                   float* outL, float* outG) {
    int i = blockIdx.x * 256 + threadIdx.x;
    int seg = i >> 11, off = i & 2047;
    outL[i] = (seg == 0 ? a0 : seg == 1 ? a1 : a2)[off];
    if (i < 4096) outG[i] = (seg == 0 ? b0 : b1)[off];
}

// ---------------- dbuf 2-phase GEMM with T2 LDS swizzle ----------------
// C[M][N] = A[M][K] * Bt[N][K]^T + bias. 128xBN tile, BK=64, 4 waves. bf16 out.
// LDS layout: row-major [row][64] with 16B chunks swizzled by chunk^=(row&7).
// Staging keeps LDS dest linear (global_load_lds) and pre-swizzles the SOURCE column.
// MODE 1: plain; MODE 2: relu.
template <int MODE, int BN>
__global__ __launch_bounds__(256) void gemm128(const bf16* __restrict__ A, const bf16* __restrict__ Bt,
                                               const float* __restrict__ bias, bf16* __restrict__ C,
                                               int M, int N, int K) {
    constexpr int NF = BN / 32;
    constexpr int ABUF = 128 * 64;
    constexpr int BBUF = BN * 64;
    constexpr int BUFE = ABUF + BBUF;
    constexpr int EC = BN + 8;
    constexpr int ARENA_E = (2 * BUFE > 128 * EC) ? 2 * BUFE : 128 * EC;
    __shared__ __align__(16) bf16 arena[ARENA_E];
    const int tid = threadIdx.x;
    const int w = tid >> 6, l = tid & 63;
    const int m0 = blockIdx.y * 128, n0 = blockIdx.x * BN;
    const int wm = (w >> 1) * 64, wn = (w & 1) * (BN / 2);
    const int srow = w * 8 + (l >> 3);
    const int scol = ((l & 7) ^ (l >> 3)) * 8;   // T2: pre-swizzled source column
    const int ldsOff = w * 512;
    const int nt = K / 64;

    auto stageT = [&](int buf, int k0) {
        bf16* Ad = arena + buf * BUFE;
        bf16* Bd = Ad + ABUF;
#pragma unroll
        for (int j = 0; j < 4; j++)
            stage16(A + (size_t)(m0 + j * 32 + srow) * K + k0 + scol, &Ad[ldsOff + j * 2048]);
#pragma unroll
        for (int j = 0; j < NF; j++)
            stage16(Bt + (size_t)(n0 + j * 32 + srow) * K + k0 + scol, &Bd[ldsOff + j * 2048]);
    };

    f32x4 acc[4][NF] = {};
    stageT(0, 0);
    __syncthreads();
    int cur = 0;
    for (int t = 0; t < nt; t++) {
        if (t + 1 < nt) stageT(cur ^ 1, (t + 1) * 64);
        const bf16* As = arena + cur * BUFE;
        const bf16* Bs = As + ABUF;
#pragma unroll
        for (int ks = 0; ks < 2; ks++) {
            s16x8 a[4], b[NF];
#pragma unroll
            for (int mf = 0; mf < 4; mf++) {
                int ar = wm + mf * 16 + (l & 15);
                int ch = (ks * 4 + (l >> 4)) ^ (ar & 7);
                a[mf] = *(const s16x8*)&As[ar * 64 + ch * 8];
            }
#pragma unroll
            for (int nf = 0; nf < NF; nf++) {
                int br = wn + nf * 16 + (l & 15);
                int ch = (ks * 4 + (l >> 4)) ^ (br & 7);
                b[nf] = *(const s16x8*)&Bs[br * 64 + ch * 8];
            }
            __builtin_amdgcn_s_setprio(1);
#pragma unroll
            for (int mf = 0; mf < 4; mf++)
#pragma unroll
                for (int nf = 0; nf < NF; nf++)
                    acc[mf][nf] = __builtin_amdgcn_mfma_f32_16x16x32_bf16(a[mf], b[nf], acc[mf][nf], 0, 0, 0);
            __builtin_amdgcn_s_setprio(0);
        }
        __syncthreads();
        cur ^= 1;
    }
    bf16* Es = arena;
#pragma unroll
    for (int mf = 0; mf < 4; mf++)
#pragma unroll
        for (int nf = 0; nf < NF; nf++)
#pragma unroll
            for (int r = 0; r < 4; r++) {
                int row = wm + mf * 16 + (l >> 4) * 4 + r;
                int col = wn + nf * 16 + (l & 15);
                float v = acc[mf][nf][r] + bias[n0 + col];
                if (MODE == 2) v = fmaxf(v, 0.f);
                Es[row * EC + col] = __float2bfloat16(v);
            }
    __syncthreads();
    constexpr int RPC = BN / 8;
    constexpr int CPT = (128 * BN) / (256 * 8);
#pragma unroll
    for (int c = 0; c < CPT; c++) {
        int lin = c * 256 + tid;
        int row = lin / RPC, cc = lin - row * RPC;
        s16x8 v = *(const s16x8*)&Es[row * EC + cc * 8];
        *(s16x8*)(C + (size_t)(m0 + row) * N + n0 + cc * 8) = v;
    }
}

// ---------------- local windowed attention (proven) ----------------
// QKV: [B*T][6144] (lQ | lK | lV). O: [B*T][2048]. grid (T/64, B*H).
__global__ __launch_bounds__(256) void local_attn(const bf16* __restrict__ QKV, bf16* __restrict__ O) {
    __shared__ bf16 U[256 * 72];
    __shared__ bf16 Ps[64][136];
    const int tid = threadIdx.x, l = tid & 63, w = tid >> 6;
    const int qt = blockIdx.x, bh = blockIdx.y;
    const int b = bh >> 3, h = bh & 7;
    const int qs = qt * 64;
    const int r0 = w * 16;
    const int lrow = tid >> 2, lc4 = (tid & 3) * 8;
    const size_t obase = (size_t)b * T_ * HK_ + h * KD_;

    s16x8 qa[8];
    {
        const bf16* qbase = QKV + (size_t)(b * T_ + qs + r0 + (l & 15)) * S6_ + h * KD_ + (l >> 4) * 8;
#pragma unroll
        for (int ks = 0; ks < 8; ks++) qa[ks] = *(const s16x8*)(qbase + ks * 32);
    }

    bf16(*Ks)[264] = (bf16(*)[264])U;
    {
        int tk = qs - 64 + lrow;
        const bf16* krow = QKV + (size_t)(b * T_ + tk) * S6_ + 2048 + h * KD_;
#pragma unroll
        for (int c = 0; c < 8; c++) {
            int col = lc4 + c * 32;
            uint4 val = {0, 0, 0, 0};
            if (tk >= 0) val = *(const uint4*)(krow + col);
            *(uint4*)&Ks[lrow][col] = val;
        }
    }
    __syncthreads();
    f32x4 sacc[8];
#pragma unroll
    for (int f = 0; f < 8; f++) sacc[f] = (f32x4){0.f, 0.f, 0.f, 0.f};
    __builtin_amdgcn_s_setprio(1);
#pragma unroll
    for (int nf = 0; nf < 4; nf++)
#pragma unroll
        for (int ks = 0; ks < 8; ks++) {
            s16x8 bb = *(const s16x8*)&Ks[nf * 16 + (l & 15)][ks * 32 + (l >> 4) * 8];
            sacc[nf] = __builtin_amdgcn_mfma_f32_16x16x32_bf16(qa[ks], bb, sacc[nf], 0, 0, 0);
        }
    __builtin_amdgcn_s_setprio(0);
    __syncthreads();
    {
        const bf16* krow = QKV + (size_t)(b * T_ + qs + lrow) * S6_ + 2048 + h * KD_;
#pragma unroll
        for (int c = 0; c < 8; c++) {
            int col = lc4 + c * 32;
            *(uint4*)&Ks[lrow][col] = *(const uint4*)(krow + col);
        }
    }
    __syncthreads();
    __builtin_amdgcn_s_setprio(1);
#pragma unroll
    for (int nf = 0; nf < 4; nf++)
#pragma unroll
        for (int ks = 0; ks < 8; ks++) {
            s16x8 bb = *(const s16x8*)&Ks[nf * 16 + (l & 15)][ks * 32 + (l >> 4) * 8];
            sacc[4 + nf] = __builtin_amdgcn_mfma_f32_16x16x32_bf16(qa[ks], bb, sacc[4 + nf], 0, 0, 0);
        }
    __builtin_amdgcn_s_setprio(0);

    uint4 vreg[8];
    {
        int tk = qs - 64 + lrow;
        const bf16* vrow = QKV + (size_t)(b * T_ + tk) * S6_ + 4096 + h * KD_;
#pragma unroll
        for (int c = 0; c < 8; c++) {
            uint4 v = {0, 0, 0, 0};
            if (tk >= 0) v = *(const uint4*)(vrow + lc4 + c * 32);
            vreg[c] = v;
        }
    }

#pragma unroll
    for (int r = 0; r < 4; r++) {
        int i = qs + r0 + (l >> 4) * 4 + r;
#pragma unroll
        for (int f = 0; f < 8; f++) {
            int j = qs - 64 + f * 16 + (l & 15);
            bool valid = (j >= 0) && (j <= i) && (j > i - WIN_);
            sacc[f][r] = valid ? sacc[f][r] * (1.f / 16.f) : -1e9f;
        }
        float mm = -1e30f;
#pragma unroll
        for (int f = 0; f < 8; f++) mm = fmaxf(mm, sacc[f][r]);
        mm = fmaxf(mm, __shfl_xor(mm, 1, 64));
        mm = fmaxf(mm, __shfl_xor(mm, 2, 64));
        mm = fmaxf(mm, __shfl_xor(mm, 4, 64));
        mm = fmaxf(mm, __shfl_xor(mm, 8, 64));
        float ss = 0.f;
#pragma unroll
        for (int f = 0; f < 8; f++) {
            float e = __expf(sacc[f][r] - mm);
            sacc[f][r] = e;
            ss += e;
        }
        ss += __shfl_xor(ss, 1, 64);
        ss += __shfl_xor(ss, 2, 64);
        ss += __shfl_xor(ss, 4, 64);
        ss += __shfl_xor(ss, 8, 64);
        float inv = 1.f / ss;
#pragma unroll
        for (int f = 0; f < 8; f++) sacc[f][r] *= inv;
    }
    __syncthreads();

    bf16(*VT)[72] = (bf16(*)[72])U;
#pragma unroll
    for (int f = 0; f < 8; f++)
#pragma unroll
        for (int r = 0; r < 4; r++)
            Ps[r0 + (l >> 4) * 4 + r][f * 16 + (l & 15)] = __float2bfloat16(sacc[f][r]);
#pragma unroll
    for (int c = 0; c < 8; c++) {
        int col = lc4 + c * 32;
        bf16 tmp[8];
        *(uint4*)tmp = vreg[c];
        for (int e = 0; e < 8; e++) VT[col + e][lrow] = tmp[e];
    }
    __syncthreads();
    {
        const bf16* vrow = QKV + (size_t)(b * T_ + qs + lrow) * S6_ + 4096 + h * KD_;
#pragma unroll
        for (int c = 0; c < 8; c++) vreg[c] = *(const uint4*)(vrow + lc4 + c * 32);
    }

    f32x4 oacc[16];
#pragma unroll
    for (int nf = 0; nf < 16; nf++) oacc[nf] = (f32x4){0.f, 0.f, 0.f, 0.f};
    for (int kb = 0; kb < 2; kb++) {
#pragma unroll
        for (int ks = 0; ks < 2; ks++) {
            s16x8 a = *(const s16x8*)&Ps[r0 + (l & 15)][kb * 64 + ks * 32 + (l >> 4) * 8];
            __builtin_amdgcn_s_setprio(1);
#pragma unroll
            for (int nf = 0; nf < 16; nf++) {
                s16x8 bb = *(const s16x8*)&VT[nf * 16 + (l & 15)][ks * 32 + (l >> 4) * 8];
                oacc[nf] = __builtin_amdgcn_mfma_f32_16x16x32_bf16(a, bb, oacc[nf], 0, 0, 0);
            }
            __builtin_amdgcn_s_setprio(0);
        }
        if (kb == 0) {
            __syncthreads();
#pragma unroll
            for (int c = 0; c < 8; c++) {
                int col = lc4 + c * 32;
                bf16 tmp[8];
                *(uint4*)tmp = vreg[c];
                for (int e = 0; e < 8; e++) VT[col + e][lrow] = tmp[e];
            }
            __syncthreads();
        }
    }
#pragma unroll
    for (int nf = 0; nf < 16; nf++)
#pragma unroll
        for (int r = 0; r < 4; r++) {
            int row = r0 + (l >> 4) * 4 + r;
            int col = nf * 16 + (l & 15);
            O[obase + (size_t)(qs + row) * HK_ + col] = __float2bfloat16(oacc[nf][r]);
        }
}

// ---------------- global path ----------------
__global__ __launch_bounds__(256) void qg_kernel(const float* __restrict__ x, const bf16* __restrict__ gwq_t,
                                                 const float* __restrict__ gbq, float* __restrict__ qg) {
    __shared__ float xs[256];
    int bi = blockIdx.x, ch = blockIdx.y, tid = threadIdx.x;
    int b = bi >> 1, i = bi & 1;
    xs[tid] = x[((size_t)b * T_ + (T_ - 2 + i)) * D_ + tid];
    __syncthreads();
    int hk = ch * 256 + tid;
    const bf16* wr = gwq_t + (size_t)hk * D_;
    float acc = gbq[hk];
    for (int c = 0; c < 32; c++) {
        s16x8 wv = *(const s16x8*)&wr[c * 8];
#pragma unroll
        for (int e = 0; e < 8; e++) acc += xs[c * 8 + e] * bs2f(wv[e]);
    }
    qg[(size_t)bi * HK_ + hk] = acc;
}

__global__ __launch_bounds__(256) void g2_scores(const float* __restrict__ qg, const bf16* __restrict__ KVg,
                                                 float* __restrict__ sc) {
    __shared__ float qf[2][256];
    int bh = blockIdx.x, ch = blockIdx.y;
    int b = bh >> 3, h = bh & 7;
    int tid = threadIdx.x;
    for (int i = 0; i < 2; i++)
        qf[i][tid] = qg[(size_t)(b * 2 + i) * HK_ + h * KD_ + tid];
    __syncthreads();
    int t = ch * 256 + tid;
    const bf16* kr = &KVg[((size_t)(b * T_ + t)) * S4_ + h * KD_];
    float a0 = 0.f, a1 = 0.f;
    for (int c = 0; c < 32; c++) {
        s16x8 kv = *(const s16x8*)&kr[c * 8];
#pragma unroll
        for (int e = 0; e < 8; e++) {
            float kf = bs2f(kv[e]);
            a0 += kf * qf[0][c * 8 + e];
            a1 += kf * qf[1][c * 8 + e];
        }
    }
    sc[((size_t)bh * 2 + 0) * T_ + t] = a0 * (1.f / 16.f);
    sc[((size_t)bh * 2 + 1) * T_ + t] = a1 * (1.f / 16.f);
}

__global__ __launch_bounds__(256) void g2_softmax(float* __restrict__ sc) {
    __shared__ float red[4];
    int bh = blockIdx.x, tid = threadIdx.x;
    int w = tid >> 6;
    for (int i = 0; i < 2; i++) {
        float* row = &sc[((size_t)bh * 2 + i) * T_];
        float vals[4];
        float m = -1e30f;
        for (int c = 0; c < 4; c++) {
            vals[c] = row[tid + 256 * c];
            m = fmaxf(m, vals[c]);
        }
        for (int s = 32; s >= 1; s >>= 1) m = fmaxf(m, __shfl_xor(m, s, 64));
        if ((tid & 63) == 0) red[w] = m;
        __syncthreads();
        m = fmaxf(fmaxf(red[0], red[1]), fmaxf(red[2], red[3]));
        __syncthreads();
        float s = 0.f;
        for (int c = 0; c < 4; c++) {
            vals[c] = __expf(vals[c] - m);
            s += vals[c];
        }
        for (int d = 32; d >= 1; d >>= 1) s += __shfl_xor(s, d, 64);
        if ((tid & 63) == 0) red[w] = s;
        __syncthreads();
        s = red[0] + red[1] + red[2] + red[3];
        float inv = 1.f / s;
        for (int c = 0; c < 4; c++) row[tid + 256 * c] = vals[c] * inv;
        __syncthreads();
    }
}

__global__ __launch_bounds__(256) void g2_pv(const float* __restrict__ sc, const bf16* __restrict__ KVg,
                                             float* __restrict__ og_part) {
    __shared__ float p2[2][256];
    int bh = blockIdx.x, ch = blockIdx.y;
    int b = bh >> 3, h = bh & 7;
    int tid = threadIdx.x;
    for (int i = 0; i < 2; i++) p2[i][tid] = sc[((size_t)bh * 2 + i) * T_ + ch * 256 + tid];
    __syncthreads();
    const bf16* vb = &KVg[((size_t)(b * T_ + ch * 256)) * S4_ + 2048 + h * KD_ + tid];
    float a0 = 0.f, a1 = 0.f;
    for (int t = 0; t < 256; t++) {
        float vv = b2f(vb[(size_t)t * S4_]);
        a0 += p2[0][t] * vv;
        a1 += p2[1][t] * vv;
    }
    og_part[((size_t)(bh * 4 + ch) * 2 + 0) * KD_ + tid] = a0;
    og_part[((size_t)(bh * 4 + ch) * 2 + 1) * KD_ + tid] = a1;
}

__global__ __launch_bounds__(256) void g2_red(const float* __restrict__ og_part, float* __restrict__ og2) {
    int idx = blockIdx.x * 256 + threadIdx.x;
    int kd = idx & 255, i = (idx >> 8) & 1, h = (idx >> 9) & 7, b = idx >> 12;
    int bh = b * 8 + h;
    float s = 0.f;
    for (int ch = 0; ch < 4; ch++) s += og_part[((size_t)(bh * 4 + ch) * 2 + i) * KD_ + kd];
    og2[(size_t)(b * 2 + i) * 2048 + h * 256 + kd] = s;
}

__global__ __launch_bounds__(256) void g2_lin(const float* __restrict__ og2, const bf16* __restrict__ gwoT,
                                              const float* __restrict__ gbo, float* __restrict__ g2buf) {
    int bi = blockIdx.x, tid = threadIdx.x;
    int d = blockIdx.y * 16 + (tid >> 4);
    int s16i = tid & 15;
    const float* ogr = og2 + (size_t)bi * 2048 + s16i * 128;
    const bf16* wr = gwoT + (size_t)d * HK_ + s16i * 128;
    float acc = 0.f;
    for (int c = 0; c < 16; c++) {
        s16x8 wv = *(const s16x8*)&wr[c * 8];
#pragma unroll
        for (int e = 0; e < 8; e++) acc += ogr[c * 8 + e] * bs2f(wv[e]);
    }
    acc += __shfl_xor(acc, 1, 64);
    acc += __shfl_xor(acc, 2, 64);
    acc += __shfl_xor(acc, 4, 64);
    acc += __shfl_xor(acc, 8, 64);
    if (s16i == 0) g2buf[(size_t)bi * 256 + d] = acc + gbo[d];
}

__global__ __launch_bounds__(256) void g2_kv(const float* __restrict__ g2buf, const bf16* __restrict__ gwk_t,
                                             const float* __restrict__ gbk, const bf16* __restrict__ gwv_t,
                                             const float* __restrict__ gbv, bf16* __restrict__ K2,
                                             bf16* __restrict__ V2) {
    __shared__ float g2s[256];
    int bi = blockIdx.x, ch = blockIdx.y;
    int tid = threadIdx.x;
    g2s[tid] = g2buf[(size_t)bi * 256 + tid];
    __syncthreads();
    int hk = ch * 256 + tid;
    const bf16* rk = &gwk_t[(size_t)hk * D_];
    const bf16* rv = &gwv_t[(size_t)hk * D_];
    float ak = gbk[hk], av = gbv[hk];
    for (int c = 0; c < 32; c++) {
        s16x8 kw = *(const s16x8*)&rk[c * 8];
        s16x8 vw = *(const s16x8*)&rv[c * 8];
#pragma unroll
        for (int e = 0; e < 8; e++) {
            float g = g2s[c * 8 + e];
            ak += g * bs2f(kw[e]);
            av += g * bs2f(vw[e]);
        }
    }
    K2[(size_t)bi * HK_ + hk] = __float2bfloat16(ak);
    V2[(size_t)bi * HK_ + hk] = __float2bfloat16(av);
}

__global__ __launch_bounds__(256) void a2w2_kernel(const bf16* __restrict__ K2, const bf16* __restrict__ V2,
                                                   const bf16* __restrict__ gwq_t, const bf16* __restrict__ gwoT,
                                                   const float* __restrict__ gbq, float* __restrict__ A2,
                                                   float* __restrict__ W2, float* __restrict__ c2) {
    __shared__ float k2s[256], v2s[256];
    __shared__ float red[4];
    int bi = blockIdx.x, h = blockIdx.y, tid = threadIdx.x;
    k2s[tid] = b2f(K2[(size_t)bi * HK_ + h * 256 + tid]);
    v2s[tid] = b2f(V2[(size_t)bi * HK_ + h * 256 + tid]);
    __syncthreads();
    float accA = 0.f;
    const bf16* wq = gwq_t + (size_t)(h * 256) * D_ + tid;
    for (int kd = 0; kd < 256; kd++)
        accA += k2s[kd] * b2f(wq[(size_t)kd * D_]);
    float accW = 0.f;
    const bf16* wo = gwoT + (size_t)tid * HK_ + h * 256;
    for (int c = 0; c < 32; c++) {
        s16x8 wv = *(const s16x8*)&wo[c * 8];
#pragma unroll
        for (int e = 0; e < 8; e++) accW += v2s[c * 8 + e] * bs2f(wv[e]);
    }
    int o = (bi * 8 + h) * 256 + tid;
    A2[o] = accA;
    W2[o] = accW;
    float pc = gbq[h * 256 + tid] * k2s[tid];
#pragma unroll
    for (int m = 32; m >= 1; m >>= 1) pc += __shfl_xor(pc, m, 64);
    if ((tid & 63) == 0) red[tid >> 6] = pc;
    __syncthreads();
    if (tid == 0) c2[bi * 8 + h] = red[0] + red[1] + red[2] + red[3];
}

__global__ __launch_bounds__(256) void gx_fused(const float* __restrict__ x, const float* __restrict__ A2,
                                                const float* __restrict__ W2, const float* __restrict__ c2,
                                                const float* __restrict__ gbo, bf16* __restrict__ attnG) {
    int w = threadIdx.x >> 6, l = threadIdx.x & 63;
    int t = blockIdx.x * 4 + w;
    int b = t >> 10;
    float4 x4 = *(const float4*)(x + (size_t)t * D_ + l * 4);
    float p[8][2];
#pragma unroll
    for (int h = 0; h < 8; h++)
#pragma unroll
        for (int i = 0; i < 2; i++) {
            const float* a = A2 + ((size_t)((b * 2 + i) * 8 + h)) * 256 + l * 4;
            float4 a4 = *(const float4*)a;
            float dt = x4.x * a4.x + x4.y * a4.y + x4.z * a4.z + x4.w * a4.w;
#pragma unroll
            for (int m = 32; m >= 1; m >>= 1) dt += __shfl_xor(dt, m, 64);
            p[h][i] = dt;
        }
    float4 gb = *(const float4*)(gbo + l * 4);
    float o0 = gb.x, o1 = gb.y, o2 = gb.z, o3 = gb.w;
#pragma unroll
    for (int h = 0; h < 8; h++) {
        float s0 = (p[h][0] + c2[(b * 2 + 0) * 8 + h]) * (1.f / 16.f);
        float s1 = (p[h][1] + c2[(b * 2 + 1) * 8 + h]) * (1.f / 16.f);
        float mx = fmaxf(s0, s1);
        float e0 = __expf(s0 - mx), e1 = __expf(s1 - mx);
        float inv = 1.f / (e0 + e1);
        float p0 = e0 * inv, p1 = e1 * inv;
        float4 w0 = *(const float4*)(W2 + ((size_t)((b * 2 + 0) * 8 + h)) * 256 + l * 4);
        float4 w1 = *(const float4*)(W2 + ((size_t)((b * 2 + 1) * 8 + h)) * 256 + l * 4);
        o0 += p0 * w0.x + p1 * w1.x;
        o1 += p0 * w0.y + p1 * w1.y;
        o2 += p0 * w0.z + p1 * w1.z;
        o3 += p0 * w0.w + p1 * w1.w;
    }
    ushort4 ou;
    ou.x = fbits(o0); ou.y = fbits(o1); ou.z = fbits(o2); ou.w = fbits(o3);
    *(ushort4*)(attnG + (size_t)t * D_ + l * 4) = ou;
}

// ---------------- LayerNorm over D=256: wave per row ----------------
// TA = float or bf16 for input a; optional c (bf16); outputs f32 and/or bf16.
template <typename TA, bool HASC>
__global__ __launch_bounds__(256) void ln_kernel(const TA* __restrict__ a, const bf16* __restrict__ b2,
                                                 const bf16* __restrict__ c, const float* __restrict__ g,
                                                 const float* __restrict__ bia, float* __restrict__ outf,
                                                 bf16* __restrict__ outb) {
    int w = threadIdx.x >> 6, l = threadIdx.x & 63;
    int row = blockIdx.x * 4 + w;
    size_t base = (size_t)row * D_ + l * 4;
    float vv[4];
    if constexpr (sizeof(TA) == 4) {
        float4 av = *(const float4*)((const float*)a + base);
        vv[0] = av.x; vv[1] = av.y; vv[2] = av.z; vv[3] = av.w;
    } else {
        ushort4 av = *(const ushort4*)((const unsigned short*)a + base);
        vv[0] = us2f(av.x); vv[1] = us2f(av.y); vv[2] = us2f(av.z); vv[3] = us2f(av.w);
    }
    ushort4 bv = *(const ushort4*)((const unsigned short*)b2 + base);
    vv[0] += us2f(bv.x); vv[1] += us2f(bv.y); vv[2] += us2f(bv.z); vv[3] += us2f(bv.w);
    if constexpr (HASC) {
        ushort4 cv = *(const ushort4*)((const unsigned short*)c + base);
        vv[0] += us2f(cv.x); vv[1] += us2f(cv.y); vv[2] += us2f(cv.z); vv[3] += us2f(cv.w);
    }
    float s = vv[0] + vv[1] + vv[2] + vv[3];
#pragma unroll
    for (int m = 32; m >= 1; m >>= 1) s += __shfl_xor(s, m, 64);
    float mean = s * (1.f / 256.f);
    float q = 0.f;
#pragma unroll
    for (int e = 0; e < 4; e++) {
        float d = vv[e] - mean;
        q += d * d;
    }
#pragma unroll
    for (int m = 32; m >= 1; m >>= 1) q += __shfl_xor(q, m, 64);
    float rs = rsqrtf(q * (1.f / 256.f) + 1e-6f);
    float4 gv = *(const float4*)(g + l * 4);
    float4 biv = *(const float4*)(bia + l * 4);
    float o0 = (vv[0] - mean) * rs * gv.x + biv.x;
    float o1 = (vv[1] - mean) * rs * gv.y + biv.y;
    float o2 = (vv[2] - mean) * rs * gv.z + biv.z;
    float o3 = (vv[3] - mean) * rs * gv.w + biv.w;
    if (outf) *(float4*)(outf + base) = (float4){o0, o1, o2, o3};
    if (outb) {
        ushort4 ou;
        ou.x = fbits(o0); ou.y = fbits(o1); ou.z = fbits(o2); ou.w = fbits(o3);
        *(ushort4*)(outb + base) = ou;
    }
}

extern "C" void kernel_launch(void* const* d_in, const int* in_sizes, int n_in, void* d_out, int out_size,
                              void* d_ws, size_t ws_size, hipStream_t stream) {
    const float* x = (const float*)d_in[0];
    const float* lWq = (const float*)d_in[1];  const float* lbq = (const float*)d_in[2];
    const float* lWk = (const float*)d_in[3];  const float* lbk = (const float*)d_in[4];
    const float* lWv = (const float*)d_in[5];  const float* lbv = (const float*)d_in[6];
    const float* lWo = (const float*)d_in[7];  const float* lbo = (const float*)d_in[8];
    const float* gWq = (const float*)d_in[9];  const float* gbq = (const float*)d_in[10];
    const float* gWk = (const float*)d_in[11]; const float* gbk = (const float*)d_in[12];
    const float* gWv = (const float*)d_in[13]; const float* gbv = (const float*)d_in[14];
    const float* gWo = (const float*)d_in[15]; const float* gbo = (const float*)d_in[16];
    const float* fW1 = (const float*)d_in[17]; const float* fb1 = (const float*)d_in[18];
    const float* fW2 = (const float*)d_in[19]; const float* fb2 = (const float*)d_in[20];
    const float* ln1g = (const float*)d_in[21]; const float* ln1b = (const float*)d_in[22];
    const float* ln2g = (const float*)d_in[23]; const float* ln2b = (const float*)d_in[24];

    char* ws = (char*)d_ws;
    size_t off = 0;
    auto alloc = [&](size_t bytes) -> char* {
        char* p = ws + off;
        off = (off + bytes + 255) & ~(size_t)255;
        return p;
    };
    bf16* xb = (bf16*)alloc((size_t)BT_ * D_ * 2);
    bf16* WcatL = (bf16*)alloc((size_t)S6_ * D_ * 2);   // [lWq|lWk|lWv]^T
    bf16* WcatG = (bf16*)alloc((size_t)S4_ * D_ * 2);   // [gWk|gWv]^T
    bf16* gwq_t = (bf16*)alloc((size_t)HK_ * D_ * 2);   // gWq^T [2048][256]
    bf16* woL = (bf16*)alloc((size_t)D_ * HK_ * 2);     // lWo^T [256][2048]
    bf16* gwoT = (bf16*)alloc((size_t)D_ * HK_ * 2);    // gWo^T [256][2048]
    bf16* fw1_t = (bf16*)alloc((size_t)FF_ * D_ * 2);
    bf16* fw2_t = (bf16*)alloc((size_t)D_ * FF_ * 2);
    float* bcatL = (float*)alloc((size_t)S6_ * 4);
    float* bcatG = (float*)alloc((size_t)S4_ * 4);
    bf16* QKV = (bf16*)alloc((size_t)BT_ * S6_ * 2);    // 96 MB; local QKV, then KVg + FFN aliases
    bf16* Ob = (bf16*)alloc((size_t)BT_ * HK_ * 2);     // 32 MB local attn out
    bf16* attnL = (bf16*)alloc((size_t)BT_ * D_ * 2);
    bf16* attnG = (bf16*)alloc((size_t)BT_ * D_ * 2);
    float* sc = (float*)alloc((size_t)B_ * H_ * 2 * T_ * 4);
    float* og_part = (float*)alloc((size_t)B_ * H_ * 4 * 2 * KD_ * 4);
    float* og2 = (float*)alloc((size_t)B_ * 2 * HK_ * 4);
    float* g2buf = (float*)alloc((size_t)B_ * 2 * D_ * 4);
    float* qg = (float*)alloc((size_t)B_ * 2 * HK_ * 4);
    bf16* K2 = (bf16*)alloc((size_t)B_ * 2 * HK_ * 2);
    bf16* V2 = (bf16*)alloc((size_t)B_ * 2 * HK_ * 2);
    float* A2 = (float*)alloc((size_t)16 * 8 * 256 * 4);
    float* W2 = (float*)alloc((size_t)16 * 8 * 256 * 4);
    float* c2 = (float*)alloc((size_t)16 * 8 * 4);
    // aliases into QKV:
    bf16* KVg = QKV;                                    // [8192][4096] = 64 MB (after local_attn)
    bf16* hid = QKV;                                    // 16 MB @ 0 (after g2_pv)
    bf16* ffn = (bf16*)((char*)QKV + (32u << 20));      // 4 MB @ 32M
    bf16* out1b = (bf16*)((char*)QKV + (48u << 20));    // 4 MB @ 48M

    // 0. convert + transposes + biases + qg
    f32_to_bf16_vec<<<(BT_ * D_) / 1024, 256, 0, stream>>>(x, xb, BT_ * D_);
    {
        TJobs js;
        int t = 0;
        auto add = [&](int i, const float* in, bf16* out, int R, int C, int os) {
            js.j[i] = {in, out, R, C, os, t};
            t += (R / 32) * (C / 32);
        };
        add(0, lWq, WcatL, D_, HK_, D_);
        add(1, lWk, WcatL + (size_t)2048 * D_, D_, HK_, D_);
        add(2, lWv, WcatL + (size_t)4096 * D_, D_, HK_, D_);
        add(3, gWk, WcatG, D_, HK_, D_);
        add(4, gWv, WcatG + (size_t)2048 * D_, D_, HK_, D_);
        add(5, gWq, gwq_t, D_, HK_, D_);
        add(6, lWo, woL, HK_, D_, HK_);
        add(7, gWo, gwoT, HK_, D_, HK_);
        add(8, fW1, fw1_t, D_, FF_, D_);
        add(9, fW2, fw2_t, FF_, D_, FF_);
        js.total = t;
        transpose_all<<<t, dim3(32, 8), 0, stream>>>(js);
    }
    concat_bias<<<S6_ / 256, 256, 0, stream>>>(lbq, lbk, lbv, gbk, gbv, bcatL, bcatG);
    qg_kernel<<<dim3(16, 8), 256, 0, stream>>>(x, gwq_t, gbq, qg);

    // 1. local path
    gemm128<1, 128><<<dim3(S6_ / 128, BT_ / 128), 256, 0, stream>>>(xb, WcatL, bcatL, QKV, BT_, S6_, D_);
    local_attn<<<dim3(T_ / 64, B_ * H_), 256, 0, stream>>>(QKV, Ob);
    gemm128<1, 64><<<dim3(D_ / 64, BT_ / 128), 256, 0, stream>>>(Ob, woL, lbo, attnL, BT_, D_, HK_);

    // 2. global path (QKV region reused as KVg after local_attn)
    gemm128<1, 128><<<dim3(S4_ / 128, BT_ / 128), 256, 0, stream>>>(xb, WcatG, bcatG, KVg, BT_, S4_, D_);
    g2_scores<<<dim3(B_ * H_, T_ / 256), 256, 0, stream>>>(qg, KVg, sc);
    g2_softmax<<<B_ * H_, 256, 0, stream>>>(sc);
    g2_pv<<<dim3(B_ * H_, 4), 256, 0, stream>>>(sc, KVg, og_part);
    g2_red<<<128, 256, 0, stream>>>(og_part, og2);
    g2_lin<<<dim3(B_ * 2, 16), 256, 0, stream>>>(og2, gwoT, gbo, g2buf);
    g2_kv<<<dim3(B_ * 2, HK_ / 256), 256, 0, stream>>>(g2buf, WcatG, gbk, WcatG + (size_t)2048 * D_, gbv, K2, V2);
    a2w2_kernel<<<dim3(16, 8), 256, 0, stream>>>(K2, V2, gwq_t, gwoT, gbq, A2, W2, c2);
    gx_fused<<<BT_ / 4, 256, 0, stream>>>(x, A2, W2, c2, gbo, attnG);

    // 3. LN1 + FFN + LN2
    ln_kernel<float, true><<<BT_ / 4, 256, 0, stream>>>(x, attnL, attnG, ln1g, ln1b, nullptr, out1b);
    gemm128<2, 128><<<dim3(FF_ / 128, BT_ / 128), 256, 0, stream>>>(out1b, fw1_t, fb1, hid, BT_, FF_, D_);
    gemm128<1, 64><<<dim3(D_ / 64, BT_ / 128), 256, 0, stream>>>(hid, fw2_t, fb2, ffn, BT_, D_, FF_);
    ln_kernel<bf16, false><<<BT_ / 4, 256, 0, stream>>>(out1b, ffn, nullptr, ln2g, ln2b, (float*)d_out, nullptr);
}